// Round 1
// baseline (342.140 us; speedup 1.0000x reference)
//
#include <hip/hip_runtime.h>
#include <math.h>
#include <stdint.h>

#define B_ 8
#define C_ 256
#define HW_ 4096
#define NPIX 32768
#define NELEM (B_*C_*HW_)   // 8388608

typedef __attribute__((ext_vector_type(8))) short short8;
typedef __attribute__((ext_vector_type(4))) float f32x4;

__device__ __forceinline__ unsigned short f2bf(float f) {
    union { float f; uint32_t u; } v; v.f = f;
    uint32_t r = v.u + 0x7FFFu + ((v.u >> 16) & 1u);
    return (unsigned short)(r >> 16);
}
__device__ __forceinline__ float b2f(unsigned short h) {
    union { uint32_t u; float f; } v; v.u = ((uint32_t)h) << 16; return v.f;
}
__device__ __forceinline__ float silu_f(float v) { return v / (1.f + __expf(-v)); }

// async global->LDS, 16B per lane; LDS dest is wave-uniform base + lane*16
__device__ __forceinline__ void gl2lds16(const void* g, void* l) {
    __builtin_amdgcn_global_load_lds(
        (const __attribute__((address_space(1))) void*)g,
        (__attribute__((address_space(3))) void*)l,
        16, 0, 0);
}
// raw barrier with explicit drain (T3 2-phase template: one per K-step)
__device__ __forceinline__ void pipeline_barrier() {
    asm volatile("s_waitcnt vmcnt(0) lgkmcnt(0)" ::: "memory");
    __builtin_amdgcn_s_barrier();
    asm volatile("" ::: "memory");
}

// ---------------- K0: weight conversion + p_w transpose ---------------------
__global__ __launch_bounds__(256) void prep_kernel(
    const float* __restrict__ akw, const float* __restrict__ l1w,
    const float* __restrict__ cvw, const float* __restrict__ pw,
    unsigned short* __restrict__ wak, unsigned short* __restrict__ wl1,
    unsigned short* __restrict__ wcv, float* __restrict__ pwt)
{
    int gid = blockIdx.x * 256 + threadIdx.x;      // grid=1352
    if (gid < 196608) {
        unsigned co = (unsigned)gid / 768u;
        unsigned kp = (unsigned)gid - co * 768u;   // k'' = n*256+ci
        unsigned n = kp >> 8, ci = kp & 255;
        wak[gid] = f2bf(akw[co * 768 + ci * 3 + n]);
    }
    else if (gid < 262144) { int g = gid - 196608; wl1[g] = f2bf(l1w[g]); }
    else if (gid < 327680) { int g = gid - 262144; wcv[g] = f2bf(cvw[g]); }
    else if (gid < 346112) {
        int idx = gid - 327680;
        int ci = idx / 72, r = idx - ci * 72;
        int tt = r / 12, t9 = r - tt * 12;
        pwt[idx] = (t9 < 9) ? pw[tt * 2304 + ci * 9 + t9] : 0.f;
    }
}

// ---------------- K0b: x CHW -> HWC transpose (XCD-swizzled) ----------------
__global__ __launch_bounds__(256) void transpose_kernel(
    const float* __restrict__ x, float* __restrict__ xt)
{
    int blk = blockIdx.x;            // 1024
    int b = blk & 7;
    int rest = blk >> 3;             // 0..127
    int half = rest & 1, i = rest >> 1;
    int bi = b * 64 + i;
    int tid = threadIdx.x;
    __shared__ float tile[64 * 132];

    {
        int ci_l = tid >> 6, jj = tid & 63;
        const float* ip = x + ((size_t)b * C_ + half * 128 + ci_l) * HW_ + i * 64 + jj;
        #pragma unroll 4
        for (int it = 0; it < 32; ++it)
            tile[jj * 132 + ci_l + it * 4] = ip[(size_t)it * 4 * HW_];
    }
    __syncthreads();
    {
        int j = tid >> 2, q = tid & 3;
        float* op = xt + ((size_t)(bi * 64 + j)) * 256 + half * 128 + q * 32;
        #pragma unroll
        for (int f = 0; f < 8; ++f)
            *(float4*)(op + f * 4) = *(const float4*)&tile[j * 132 + q * 32 + f * 4];
    }
}

// ---------------- K1a: offset conv stage 1 (v5: register acc, small tree) ---
__global__ __launch_bounds__(256) void offset_s1_kernel(
    const float* __restrict__ x, const float* __restrict__ pwt,
    float* __restrict__ part)          // [bi*8+g][6][64]
{
    int blk = blockIdx.x;              // 4096
    int b = blk & 7;
    int rest = blk >> 3;               // 0..511
    int g = rest & 7, i = rest >> 3;
    int bi = b * 64 + i;
    int tid = threadIdx.x;

    __shared__ float tile[6600];       // x tile [(row*66+col)*33+ci]; aliased as s2[16][387]

    // ---- stage x tile (transposed, halo-padded) ----
    {
        int cs = tid >> 3, r8 = tid & 7;
        const float* xp = x + ((size_t)b * C_ + g * 32 + cs) * HW_;
        #pragma unroll
        for (int t = 0; t < 6; ++t) {
            int idx = r8 * 6 + t;
            int r = idx >> 4, v4 = idx & 15;
            int ii = i + r - 1;
            float4 val = make_float4(0.f, 0.f, 0.f, 0.f);
            if (ii >= 0 && ii < 64)
                val = *(const float4*)(xp + ii * 64 + v4 * 4);
            int base = (r * 66 + 1 + v4 * 4) * 33 + cs;
            tile[base]      = val.x;  tile[base + 33]  = val.y;
            tile[base + 66] = val.z;  tile[base + 99]  = val.w;
        }
        if (tid < 192) {
            int ci = tid / 6, rem = tid - ci * 6;
            int ki = rem >> 1, side = rem & 1;
            tile[(ki * 66 + side * 65) * 33 + ci] = 0.f;
        }
    }
    __syncthreads();

    int sub = tid >> 4;                // 0..15
    int jq  = tid & 15;                // 0..15: pixels jq*4 .. jq*4+3

    float acc[6][4];
    #pragma unroll
    for (int tt = 0; tt < 6; ++tt)
        #pragma unroll
        for (int p = 0; p < 4; ++p) acc[tt][p] = 0.f;

    #pragma unroll
    for (int t = 0; t < 2; ++t) {
        int ci = sub + 16 * t;
        float xv[3][6];                // tile cols jq*4 .. jq*4+5
        #pragma unroll
        for (int ki = 0; ki < 3; ++ki)
            #pragma unroll
            for (int cc = 0; cc < 6; ++cc)
                xv[ki][cc] = tile[(ki * 66 + jq * 4 + cc) * 33 + ci];
        const float* wp = pwt + (g * 32 + ci) * 72;
        #pragma unroll
        for (int tt = 0; tt < 6; ++tt) {
            float w[9];
            *(float4*)&w[0] = *(const float4*)(wp + tt * 12);
            *(float4*)&w[4] = *(const float4*)(wp + tt * 12 + 4);
            w[8] = wp[tt * 12 + 8];
            #pragma unroll
            for (int ki = 0; ki < 3; ++ki)
                #pragma unroll
                for (int kj = 0; kj < 3; ++kj) {
                    float wgt = w[ki * 3 + kj];
                    #pragma unroll
                    for (int p = 0; p < 4; ++p)
                        acc[tt][p] += wgt * xv[ki][kj + p];
                }
        }
    }

    // ---- 16-sub reduction via LDS tree (alias tile as s2, stride 387) ----
    __syncthreads();
    {
        float* s2 = tile + sub * 387;
        #pragma unroll
        for (int tt = 0; tt < 6; ++tt)
            #pragma unroll
            for (int p = 0; p < 4; ++p)
                s2[tt * 64 + jq * 4 + p] = acc[tt][p];
    }
    __syncthreads();
    size_t pslot = (size_t)bi * 8 + g;
    for (int idx = tid; idx < 384; idx += 256) {
        float s = 0.f;
        #pragma unroll
        for (int sb = 0; sb < 16; ++sb)
            s += tile[sb * 387 + idx];
        part[pslot * 384 + idx] = s;
    }
}

// ---------------- K1b: offset stage 2 -> paired gather tables ---------------
__global__ __launch_bounds__(256) void offset_s2_kernel(
    const float* __restrict__ part, const float* __restrict__ pb,
    int2* __restrict__ tbl_off, float4* __restrict__ tbl_w)
{
    int pix = blockIdx.x * 256 + threadIdx.x;   // grid=128
    int b = pix >> 12, rem = pix & 4095, i = rem >> 6, j = rem & 63;
    int bi = b * 64 + i;
    float v[6];
    #pragma unroll
    for (int tt = 0; tt < 6; ++tt) v[tt] = pb[tt];
    for (int g = 0; g < 8; ++g) {
        const float* pp = part + ((size_t)bi * 8 + g) * 384;
        #pragma unroll
        for (int tt = 0; tt < 6; ++tt) v[tt] += pp[tt * 64 + j];
    }
    const float pnx[3] = {0.f, 0.f, 1.f};
    const float pny[3] = {0.f, 1.f, 0.f};
    #pragma unroll
    for (int n = 0; n < 3; ++n) {
        float px_ = (float)i + pnx[n] + v[n];
        float py_ = (float)j + pny[n] + v[n + 3];
        float qx = floorf(px_), qy = floorf(py_);
        float qlx = fminf(fmaxf(qx,       0.f), 63.f);
        float qly = fminf(fmaxf(qy,       0.f), 63.f);
        float qrx = fminf(fmaxf(qx + 1.f, 0.f), 63.f);
        float qry = fminf(fmaxf(qy + 1.f, 0.f), 63.f);
        float pxc = fminf(fmaxf(px_,      0.f), 63.f);
        float pyc = fminf(fmaxf(py_,      0.f), 63.f);
        float glt = (1.f + (qlx - pxc)) * (1.f + (qly - pyc));
        float grb = (1.f - (qrx - pxc)) * (1.f - (qry - pyc));
        float glb = (1.f + (qlx - pxc)) * (1.f - (qry - pyc));
        float grt = (1.f - (qrx - pxc)) * (1.f + (qly - pyc));
        int ilx = (int)qlx, irx = (int)qrx;
        int ily = (int)qly, iry = (int)qry;
        int c0; float a0, a1, b0, b1;
        if (ily == iry) {
            if (ily == 0) { c0 = 0;  a0 = glt + glb; a1 = 0.f; b0 = grt + grb; b1 = 0.f; }
            else          { c0 = 62; a0 = 0.f; a1 = glt + glb; b0 = 0.f; b1 = grt + grb; }
        } else { c0 = ily; a0 = glt; a1 = glb; b0 = grt; b1 = grb; }
        int oi = (b * 3 + n) * HW_ + i * 64 + j;
        tbl_off[oi] = make_int2(ilx * 64 + c0, irx * 64 + c0);
        tbl_w[oi]   = make_float4(a0, a1, b0, b1);
    }
}

// ---------------- K2a: gather — HWC input, coalesced, XCD-swizzled ----------
__global__ __launch_bounds__(256) void gather_kernel(
    const float* __restrict__ xt, const int2* __restrict__ tbl_off,
    const float4* __restrict__ tbl_w, unsigned short* __restrict__ v)
{
    int blk = blockIdx.x;          // 1536
    int b = blk & 7;
    int rest = blk >> 3;           // 0..191
    int n = rest >> 6, i = rest & 63;
    int bi = b * 64 + i;
    int tid = threadIdx.x;
    int lane = tid & 63, wv = tid >> 6;
    int ci4 = lane * 4;
    const float* xb = xt + (size_t)b * 1048576;

    for (int it0 = 0; it0 < 16; it0 += 4) {
        float4 A[4], Bv[4], Cv[4], Dv[4], w4[4];
        #pragma unroll
        for (int u = 0; u < 4; ++u) {
            int j = wv * 16 + it0 + u;
            int oi = (b * 3 + n) * HW_ + i * 64 + j;
            int2 off = tbl_off[oi];
            w4[u] = tbl_w[oi];
            const float* p0 = xb + (size_t)off.x * 256 + ci4;
            const float* p1 = xb + (size_t)off.y * 256 + ci4;
            A[u]  = *(const float4*)p0;
            Bv[u] = *(const float4*)(p0 + 256);
            Cv[u] = *(const float4*)p1;
            Dv[u] = *(const float4*)(p1 + 256);
        }
        #pragma unroll
        for (int u = 0; u < 4; ++u) {
            int j = wv * 16 + it0 + u;
            int pix = bi * 64 + j;
            union { unsigned short h[4]; uint2 q; } pk;
            pk.h[0] = f2bf(w4[u].x*A[u].x + w4[u].y*Bv[u].x + w4[u].z*Cv[u].x + w4[u].w*Dv[u].x);
            pk.h[1] = f2bf(w4[u].x*A[u].y + w4[u].y*Bv[u].y + w4[u].z*Cv[u].y + w4[u].w*Dv[u].y);
            pk.h[2] = f2bf(w4[u].x*A[u].z + w4[u].y*Bv[u].z + w4[u].z*Cv[u].z + w4[u].w*Dv[u].z);
            pk.h[3] = f2bf(w4[u].x*A[u].w + w4[u].y*Bv[u].w + w4[u].z*Cv[u].w + w4[u].w*Dv[u].w);
            *(uint2*)&v[(size_t)pix * 768 + n * 256 + ci4] = pk.q;
        }
    }
}

// ---------------- K2b: AK GEMM (bf16 MFMA, 2-phase pipelined) ---------------
// T3 minimum template: double-buffered LDS, global_load_lds(16B) staging,
// next-tile stage issued BEFORE current MFMAs, one vmcnt(0)+raw-barrier/K-step.
__global__ __launch_bounds__(256) void ak_mfma_kernel(
    const unsigned short* __restrict__ v, const unsigned short* __restrict__ W,
    unsigned short* __restrict__ yh, float* __restrict__ p1, float* __restrict__ p2)
{
    int blk = blockIdx.x;              // 512
    int b = blk & 7, i = blk >> 3;
    int tid = threadIdx.x;
    int wv = tid >> 6, lane = tid & 63;
    int quad = lane >> 4, l15 = lane & 15;
    __shared__ __align__(16) unsigned short sA[2][8192];   // 2 x 256co x 32k
    __shared__ __align__(16) unsigned short sB[2][2048];   // 2 x 64pix x 32k
    int pix0 = (b * 64 + i) * 64;

    // per-lane global srcs; LDS dest = wave-uniform base + lane*16 (HW rule)
    const unsigned short* wp = W + (size_t)(wv * 64 + lane) * 768;
    const unsigned short* vp = v + (size_t)(pix0 + lane) * 768;

    f32x4 acc[4][4];
    #pragma unroll
    for (int mt = 0; mt < 4; ++mt)
        #pragma unroll
        for (int nt = 0; nt < 4; ++nt) acc[mt][nt] = (f32x4){0.f, 0.f, 0.f, 0.f};

    auto stage = [&](int bb, int k0) {
        #pragma unroll
        for (int s = 0; s < 4; ++s)
            gl2lds16(wp + k0 + s * 8, &sA[bb][(s * 256 + wv * 64) * 8]);
        gl2lds16(vp + k0 + wv * 8, &sB[bb][(wv * 64) * 8]);
    };

    stage(0, 0);
    pipeline_barrier();
    int cur = 0;
    #pragma unroll 2
    for (int t = 0; t < 24; ++t) {
        if (t < 23) stage(cur ^ 1, (t + 1) * 32);   // prefetch next K-tile
        short8 af[4], bf[4];
        #pragma unroll
        for (int mt = 0; mt < 4; ++mt)
            af[mt] = *(const short8*)&sA[cur][(quad * 256 + wv * 64 + mt * 16 + l15) * 8];
        #pragma unroll
        for (int nt = 0; nt < 4; ++nt)
            bf[nt] = *(const short8*)&sB[cur][(quad * 64 + nt * 16 + l15) * 8];
        #pragma unroll
        for (int mt = 0; mt < 4; ++mt)
            #pragma unroll
            for (int nt = 0; nt < 4; ++nt)
                acc[mt][nt] = __builtin_amdgcn_mfma_f32_16x16x32_bf16(
                    af[mt], bf[nt], acc[mt][nt], 0, 0, 0);
        pipeline_barrier();                          // drains next-tile loads
        cur ^= 1;
    }
    #pragma unroll
    for (int mt = 0; mt < 4; ++mt) {
        #pragma unroll
        for (int r = 0; r < 4; ++r) {
            int co = wv * 64 + mt * 16 + quad * 4 + r;
            size_t base = ((size_t)b * C_ + co) * HW_ + i * 64;
            float s1 = 0.f, s2 = 0.f;
            #pragma unroll
            for (int nt = 0; nt < 4; ++nt) {
                float val = acc[mt][nt][r];
                s1 += val; s2 += val * val;
                yh[base + nt * 16 + l15] = f2bf(val);
            }
            #pragma unroll
            for (int m = 1; m < 16; m <<= 1) {
                s1 += __shfl_xor(s1, m); s2 += __shfl_xor(s2, m);
            }
            if (l15 == 0) { p1[co * 512 + blk] = s1; p2[co * 512 + blk] = s2; }
        }
    }
}

// ---------------- K3: BN stats from partials --------------------------------
__global__ __launch_bounds__(256) void bn_stats_kernel(
    const float* __restrict__ p1, const float* __restrict__ p2,
    const float* __restrict__ gamma, const float* __restrict__ beta,
    float* __restrict__ ss)
{
    int co = blockIdx.x, tid = threadIdx.x;     // grid=256
    float a = p1[co * 512 + tid] + p1[co * 512 + 256 + tid];
    float q = p2[co * 512 + tid] + p2[co * 512 + 256 + tid];
    __shared__ float r1[256], r2[256];
    r1[tid] = a; r2[tid] = q; __syncthreads();
    for (int st = 128; st > 0; st >>= 1) {
        if (tid < st) { r1[tid] += r1[tid + st]; r2[tid] += r2[tid + st]; }
        __syncthreads();
    }
    if (tid == 0) {
        const float inv_n = 1.f / (float)NPIX;
        float m = r1[0] * inv_n;
        float var = r2[0] * inv_n - m * m;
        float sc = gamma[co] * rsqrtf(var + 1e-5f);
        ss[co] = sc; ss[256 + co] = beta[co] - m * sc;
    }
}

// ---------------- K4: fused BN+SiLU + 5x5 depthwise (XCD-swizzled) ----------
__global__ __launch_bounds__(256) void dw5_fused_kernel(
    const unsigned short* __restrict__ in, const float* __restrict__ ss,
    const float* __restrict__ w, const float* __restrict__ bias,
    unsigned short* __restrict__ out)
{
    int blkI = blockIdx.x;         // 2048
    int b = blkI & 7, c = blkI >> 3;
    int bc = b * 256 + c;
    int tid = threadIdx.x;
    __shared__ float tile[68 * 68];
    float sc = ss[c], sh = ss[256 + c];
    const unsigned short* ip = in + (size_t)bc * HW_;
    for (int s = tid; s < 68 * 68; s += 256) {
        int r = s / 68, cc = s - r * 68;
        int ii = r - 2, jj = cc - 2;
        float vv = 0.f;
        if (ii >= 0 && ii < 64 && jj >= 0 && jj < 64) {
            float t = b2f(ip[ii * 64 + jj]) * sc + sh;
            vv = silu_f(t);
        }
        tile[s] = vv;
    }
    float wr[25];
    #pragma unroll
    for (int t = 0; t < 25; ++t) wr[t] = w[c * 25 + t];
    float bv = bias[c];
    __syncthreads();
    int j0 = (tid & 15) * 4, ig = tid >> 4;
    unsigned short* op = out + (size_t)bc * HW_;
    for (int r = 0; r < 4; ++r) {
        int i = r * 16 + ig;
        float o0 = bv, o1 = bv, o2 = bv, o3 = bv;
        #pragma unroll
        for (int di = 0; di < 5; ++di) {
            const float* tp = &tile[(i + di) * 68 + j0];
            float4 a = *(const float4*)tp;
            float4 bq = *(const float4*)(tp + 4);
            float vv[8] = {a.x, a.y, a.z, a.w, bq.x, bq.y, bq.z, bq.w};
            #pragma unroll
            for (int dj = 0; dj < 5; ++dj) {
                float wv = wr[di * 5 + dj];
                o0 += wv * vv[dj];     o1 += wv * vv[dj + 1];
                o2 += wv * vv[dj + 2]; o3 += wv * vv[dj + 3];
            }
        }
        union { unsigned short h[4]; uint2 u; } pk;
        pk.h[0] = f2bf(o0); pk.h[1] = f2bf(o1);
        pk.h[2] = f2bf(o2); pk.h[3] = f2bf(o3);
        *(uint2*)&op[i * 64 + j0] = pk.u;
    }
}

// ---------------- K5: 7x7 dilated(3) depthwise (XCD-swizzled) ---------------
__global__ __launch_bounds__(256) void dw7d3_kernel(
    const unsigned short* __restrict__ in, const float* __restrict__ w,
    const float* __restrict__ bias, unsigned short* __restrict__ out)
{
    int blkI = blockIdx.x;         // 2048
    int b = blkI & 7, c = blkI >> 3;
    int bc = b * 256 + c;
    int tid = threadIdx.x;
    __shared__ float tile[82 * 84];
    const unsigned short* ip = in + (size_t)bc * HW_;
    for (int s = tid; s < 82 * 84; s += 256) {
        int r = s / 84, cc = s - r * 84;
        int ii = r - 9, jj = cc - 9;
        float vv = 0.f;
        if (ii >= 0 && ii < 64 && jj >= 0 && jj < 64) vv = b2f(ip[ii * 64 + jj]);
        tile[s] = vv;
    }
    float wr[49];
    #pragma unroll
    for (int t = 0; t < 49; ++t) wr[t] = w[c * 49 + t];
    float bv = bias[c];
    __syncthreads();
    int j0 = (tid & 15) * 4, ig = tid >> 4;
    unsigned short* op = out + (size_t)bc * HW_;
    for (int r = 0; r < 4; ++r) {
        int i = r * 16 + ig;
        float o0 = bv, o1 = bv, o2 = bv, o3 = bv;
        #pragma unroll
        for (int di = 0; di < 7; ++di) {
            const float* tp = &tile[(i + 3 * di) * 84 + j0];
            float vv[24];
            #pragma unroll
            for (int q = 0; q < 6; ++q)
                *(float4*)&vv[q * 4] = *(const float4*)(tp + q * 4);
            #pragma unroll
            for (int dj = 0; dj < 7; ++dj) {
                float wv = wr[di * 7 + dj];
                o0 += wv * vv[3 * dj];     o1 += wv * vv[3 * dj + 1];
                o2 += wv * vv[3 * dj + 2]; o3 += wv * vv[3 * dj + 3];
            }
        }
        union { unsigned short h[4]; uint2 u; } pk;
        pk.h[0] = f2bf(o0); pk.h[1] = f2bf(o1);
        pk.h[2] = f2bf(o2); pk.h[3] = f2bf(o3);
        *(uint2*)&op[i * 64 + j0] = pk.u;
    }
}

// ---------------- K6/K7: 1x1 conv bf16 MFMA GEMM (2-phase pipelined) --------
// sA via global_load_lds double-buffer; sB (strided CHW source) via T14 split:
// issue next-tile loads to regs before MFMAs, ds_write after vmcnt(0).
template<int MODE>
__global__ __launch_bounds__(256) void gemm1x1_mfma(
    const unsigned short* __restrict__ in, const unsigned short* __restrict__ W,
    const float* __restrict__ bias,
    const unsigned short* __restrict__ auxh, const float* __restrict__ auxf,
    const float* __restrict__ ss,
    unsigned short* __restrict__ out_bf, float* __restrict__ out_f)
{
    int blk = blockIdx.x;              // 512
    int b = blk & 7, i = blk >> 3;
    int tid = threadIdx.x;
    int wv = tid >> 6, lane = tid & 63;
    int quad = lane >> 4, l15 = lane & 15;
    __shared__ __align__(16) unsigned short sA[2][8192];
    __shared__ __align__(16) unsigned short sB[2][2048];
    int pixS = tid & 63, kqS = tid >> 6;

    const unsigned short* wp = W + (size_t)(wv * 64 + lane) * 256;
    const unsigned short* bp = in + ((size_t)b * C_) * HW_ + i * 64 + pixS;

    f32x4 acc[4][4];
    #pragma unroll
    for (int mt = 0; mt < 4; ++mt)
        #pragma unroll
        for (int nt = 0; nt < 4; ++nt) acc[mt][nt] = (f32x4){0.f, 0.f, 0.f, 0.f};

    auto stageA = [&](int bb, int k0) {
        #pragma unroll
        for (int s = 0; s < 4; ++s)
            gl2lds16(wp + k0 + s * 8, &sA[bb][(s * 256 + wv * 64) * 8]);
    };
    union U8 { unsigned short h[8]; uint4 u; };
    auto loadB = [&](U8& hb, int k0) {
        const unsigned short* p = bp + (size_t)(k0 + kqS * 8) * HW_;
        #pragma unroll
        for (int jj = 0; jj < 8; ++jj) hb.h[jj] = p[(size_t)jj * HW_];
    };

    U8 hb;
    stageA(0, 0);
    loadB(hb, 0);
    asm volatile("s_waitcnt vmcnt(0)" ::: "memory");
    *(uint4*)&sB[0][(kqS * 64 + pixS) * 8] = hb.u;
    pipeline_barrier();

    int cur = 0;
    #pragma unroll 2
    for (int t = 0; t < 8; ++t) {
        if (t < 7) { stageA(cur ^ 1, (t + 1) * 32); loadB(hb, (t + 1) * 32); }
        short8 af[4], bf[4];
        #pragma unroll
        for (int mt = 0; mt < 4; ++mt)
            af[mt] = *(const short8*)&sA[cur][(quad * 256 + wv * 64 + mt * 16 + l15) * 8];
        #pragma unroll
        for (int nt = 0; nt < 4; ++nt)
            bf[nt] = *(const short8*)&sB[cur][(quad * 64 + nt * 16 + l15) * 8];
        #pragma unroll
        for (int mt = 0; mt < 4; ++mt)
            #pragma unroll
            for (int nt = 0; nt < 4; ++nt)
                acc[mt][nt] = __builtin_amdgcn_mfma_f32_16x16x32_bf16(
                    af[mt], bf[nt], acc[mt][nt], 0, 0, 0);
        if (t < 7) {
            asm volatile("s_waitcnt vmcnt(0)" ::: "memory");
            *(uint4*)&sB[cur ^ 1][(kqS * 64 + pixS) * 8] = hb.u;
        }
        pipeline_barrier();
        cur ^= 1;
    }
    #pragma unroll
    for (int mt = 0; mt < 4; ++mt) {
        #pragma unroll
        for (int r = 0; r < 4; ++r) {
            int co = wv * 64 + mt * 16 + quad * 4 + r;
            float bco = bias[co];
            size_t base = ((size_t)b * C_ + co) * HW_ + i * 64;
            if (MODE == 0) {
                float sc = ss[co], sh = ss[256 + co];
                #pragma unroll
                for (int nt = 0; nt < 4; ++nt) {
                    int col = nt * 16 + l15;
                    float o = acc[mt][nt][r] + bco;
                    float u = silu_f(b2f(auxh[base + col]) * sc + sh);
                    out_bf[base + col] = f2bf(o * u);
                }
            } else {
                #pragma unroll
                for (int nt = 0; nt < 4; ++nt) {
                    int col = nt * 16 + l15;
                    out_f[base + col] = acc[mt][nt][r] + bco + auxf[base + col];
                }
            }
        }
    }
}

// ---------------- launch ----------------------------------------------------
extern "C" void kernel_launch(void* const* d_in, const int* in_sizes, int n_in,
                              void* d_out, int out_size, void* d_ws, size_t ws_size,
                              hipStream_t stream) {
    const float* x     = (const float*)d_in[0];
    const float* p_w   = (const float*)d_in[1];
    const float* p_b   = (const float*)d_in[2];
    const float* ak_w  = (const float*)d_in[3];
    const float* ak_g  = (const float*)d_in[4];
    const float* ak_b  = (const float*)d_in[5];
    const float* l0_w  = (const float*)d_in[6];
    const float* l0_b  = (const float*)d_in[7];
    const float* ls_w  = (const float*)d_in[8];
    const float* ls_b  = (const float*)d_in[9];
    const float* l1_w  = (const float*)d_in[10];
    const float* l1_b  = (const float*)d_in[11];
    const float* cv_w  = (const float*)d_in[12];
    const float* cv_b  = (const float*)d_in[13];
    float* out = (float*)d_out;

    char* w = (char*)d_ws;
    int2*   tbl_off = (int2*)w;                              // 786 KB
    float4* tbl_w   = (float4*)(w + 786432);                 // 1.5 MB
    unsigned short* wak = (unsigned short*)(w + 2359296);    // 384 KB
    unsigned short* wl1 = (unsigned short*)(w + 2752512);    // 128 KB
    unsigned short* wcv = (unsigned short*)(w + 2883584);    // 128 KB
    float* p1 = (float*)(w + 3014656);                       // 512 KB
    float* p2 = (float*)(w + 3538944);                       // 512 KB
    float* ss = (float*)(w + 4063232);                       // 2 KB
    float* pwt = (float*)(w + 4065280);                      // 72 KB
    // time-multiplexed regions:
    float* xt   = (float*)(w + 4194304);                     // 32 MB (dead after gather)
    unsigned short* ybh    = (unsigned short*)(w + 4194304); // 16 MB (ak writes, after gather)
    unsigned short* dw5out = (unsigned short*)(w + 20971520);// 16 MB
    float* part = (float*)(w + 37748736);                    // 6.3 MB (dead after s2)
    unsigned short* attn   = (unsigned short*)(w + 37748736);// 16 MB (dw7 out)
    unsigned short* v      = (unsigned short*)(w + 44040192);// 48 MB (dead after ak)
    unsigned short* g0out  = (unsigned short*)(w + 54525952);// 16 MB (after gemm0)

    prep_kernel<<<1352, 256, 0, stream>>>(ak_w, l1_w, cv_w, p_w, wak, wl1, wcv, pwt);
    offset_s1_kernel<<<4096, 256, 0, stream>>>(x, pwt, part);
    offset_s2_kernel<<<128, 256, 0, stream>>>(part, p_b, tbl_off, tbl_w);
    transpose_kernel<<<1024, 256, 0, stream>>>(x, xt);
    gather_kernel<<<1536, 256, 0, stream>>>(xt, tbl_off, tbl_w, v);
    ak_mfma_kernel<<<512, 256, 0, stream>>>(v, wak, ybh, p1, p2);
    bn_stats_kernel<<<256, 256, 0, stream>>>(p1, p2, ak_g, ak_b, ss);
    dw5_fused_kernel<<<2048, 256, 0, stream>>>(ybh, ss, l0_w, l0_b, dw5out);
    dw7d3_kernel<<<2048, 256, 0, stream>>>(dw5out, ls_w, ls_b, attn);
    gemm1x1_mfma<0><<<512, 256, 0, stream>>>(attn, wl1, l1_b, ybh, nullptr, ss, g0out, nullptr);
    gemm1x1_mfma<1><<<512, 256, 0, stream>>>(g0out, wcv, cv_b, nullptr, x, nullptr, nullptr, out);
}

// Round 2
// 326.068 us; speedup vs baseline: 1.0493x; 1.0493x over previous
//
#include <hip/hip_runtime.h>
#include <math.h>
#include <stdint.h>

#define B_ 8
#define C_ 256
#define HW_ 4096
#define NPIX 32768
#define NELEM (B_*C_*HW_)   // 8388608

typedef __attribute__((ext_vector_type(8))) short short8;
typedef __attribute__((ext_vector_type(4))) float f32x4;

__device__ __forceinline__ unsigned short f2bf(float f) {
    union { float f; uint32_t u; } v; v.f = f;
    uint32_t r = v.u + 0x7FFFu + ((v.u >> 16) & 1u);
    return (unsigned short)(r >> 16);
}
__device__ __forceinline__ float b2f(unsigned short h) {
    union { uint32_t u; float f; } v; v.u = ((uint32_t)h) << 16; return v.f;
}
__device__ __forceinline__ float silu_f(float v) { return v / (1.f + __expf(-v)); }

// async global->LDS, 16B per lane; LDS dest is wave-uniform base + lane*16
__device__ __forceinline__ void gl2lds16(const void* g, void* l) {
    __builtin_amdgcn_global_load_lds(
        (const __attribute__((address_space(1))) void*)g,
        (__attribute__((address_space(3))) void*)l,
        16, 0, 0);
}

// ---------------- K0: weight conversion + p_w transpose ---------------------
__global__ __launch_bounds__(256) void prep_kernel(
    const float* __restrict__ akw, const float* __restrict__ l1w,
    const float* __restrict__ cvw, const float* __restrict__ pw,
    unsigned short* __restrict__ wak, unsigned short* __restrict__ wl1,
    unsigned short* __restrict__ wcv, float* __restrict__ pwt)
{
    int gid = blockIdx.x * 256 + threadIdx.x;      // grid=1352
    if (gid < 196608) {
        unsigned co = (unsigned)gid / 768u;
        unsigned kp = (unsigned)gid - co * 768u;   // k'' = n*256+ci
        unsigned n = kp >> 8, ci = kp & 255;
        wak[gid] = f2bf(akw[co * 768 + ci * 3 + n]);
    }
    else if (gid < 262144) { int g = gid - 196608; wl1[g] = f2bf(l1w[g]); }
    else if (gid < 327680) { int g = gid - 262144; wcv[g] = f2bf(cvw[g]); }
    else if (gid < 346112) {
        int idx = gid - 327680;
        int ci = idx / 72, r = idx - ci * 72;
        int tt = r / 12, t9 = r - tt * 12;
        pwt[idx] = (t9 < 9) ? pw[tt * 2304 + ci * 9 + t9] : 0.f;
    }
}

// ---------------- K0b: x CHW -> HWC transpose (XCD-swizzled) ----------------
__global__ __launch_bounds__(256) void transpose_kernel(
    const float* __restrict__ x, float* __restrict__ xt)
{
    int blk = blockIdx.x;            // 1024
    int b = blk & 7;
    int rest = blk >> 3;             // 0..127
    int half = rest & 1, i = rest >> 1;
    int bi = b * 64 + i;
    int tid = threadIdx.x;
    __shared__ float tile[64 * 132];

    {
        int ci_l = tid >> 6, jj = tid & 63;
        const float* ip = x + ((size_t)b * C_ + half * 128 + ci_l) * HW_ + i * 64 + jj;
        #pragma unroll 4
        for (int it = 0; it < 32; ++it)
            tile[jj * 132 + ci_l + it * 4] = ip[(size_t)it * 4 * HW_];
    }
    __syncthreads();
    {
        int j = tid >> 2, q = tid & 3;
        float* op = xt + ((size_t)(bi * 64 + j)) * 256 + half * 128 + q * 32;
        #pragma unroll
        for (int f = 0; f < 8; ++f)
            *(float4*)(op + f * 4) = *(const float4*)&tile[j * 132 + q * 32 + f * 4];
    }
}

// ---------------- K1a: offset conv stage 1 (v5: register acc, small tree) ---
__global__ __launch_bounds__(256) void offset_s1_kernel(
    const float* __restrict__ x, const float* __restrict__ pwt,
    float* __restrict__ part)          // [bi*8+g][6][64]
{
    int blk = blockIdx.x;              // 4096
    int b = blk & 7;
    int rest = blk >> 3;               // 0..511
    int g = rest & 7, i = rest >> 3;
    int bi = b * 64 + i;
    int tid = threadIdx.x;

    __shared__ float tile[6600];       // x tile [(row*66+col)*33+ci]; aliased as s2[16][387]

    // ---- stage x tile (transposed, halo-padded) ----
    {
        int cs = tid >> 3, r8 = tid & 7;
        const float* xp = x + ((size_t)b * C_ + g * 32 + cs) * HW_;
        #pragma unroll
        for (int t = 0; t < 6; ++t) {
            int idx = r8 * 6 + t;
            int r = idx >> 4, v4 = idx & 15;
            int ii = i + r - 1;
            float4 val = make_float4(0.f, 0.f, 0.f, 0.f);
            if (ii >= 0 && ii < 64)
                val = *(const float4*)(xp + ii * 64 + v4 * 4);
            int base = (r * 66 + 1 + v4 * 4) * 33 + cs;
            tile[base]      = val.x;  tile[base + 33]  = val.y;
            tile[base + 66] = val.z;  tile[base + 99]  = val.w;
        }
        if (tid < 192) {
            int ci = tid / 6, rem = tid - ci * 6;
            int ki = rem >> 1, side = rem & 1;
            tile[(ki * 66 + side * 65) * 33 + ci] = 0.f;
        }
    }
    __syncthreads();

    int sub = tid >> 4;                // 0..15
    int jq  = tid & 15;                // 0..15: pixels jq*4 .. jq*4+3

    float acc[6][4];
    #pragma unroll
    for (int tt = 0; tt < 6; ++tt)
        #pragma unroll
        for (int p = 0; p < 4; ++p) acc[tt][p] = 0.f;

    #pragma unroll
    for (int t = 0; t < 2; ++t) {
        int ci = sub + 16 * t;
        float xv[3][6];                // tile cols jq*4 .. jq*4+5
        #pragma unroll
        for (int ki = 0; ki < 3; ++ki)
            #pragma unroll
            for (int cc = 0; cc < 6; ++cc)
                xv[ki][cc] = tile[(ki * 66 + jq * 4 + cc) * 33 + ci];
        const float* wp = pwt + (g * 32 + ci) * 72;
        #pragma unroll
        for (int tt = 0; tt < 6; ++tt) {
            float w[9];
            *(float4*)&w[0] = *(const float4*)(wp + tt * 12);
            *(float4*)&w[4] = *(const float4*)(wp + tt * 12 + 4);
            w[8] = wp[tt * 12 + 8];
            #pragma unroll
            for (int ki = 0; ki < 3; ++ki)
                #pragma unroll
                for (int kj = 0; kj < 3; ++kj) {
                    float wgt = w[ki * 3 + kj];
                    #pragma unroll
                    for (int p = 0; p < 4; ++p)
                        acc[tt][p] += wgt * xv[ki][kj + p];
                }
        }
    }

    // ---- 16-sub reduction via LDS tree (alias tile as s2, stride 387) ----
    __syncthreads();
    {
        float* s2 = tile + sub * 387;
        #pragma unroll
        for (int tt = 0; tt < 6; ++tt)
            #pragma unroll
            for (int p = 0; p < 4; ++p)
                s2[tt * 64 + jq * 4 + p] = acc[tt][p];
    }
    __syncthreads();
    size_t pslot = (size_t)bi * 8 + g;
    for (int idx = tid; idx < 384; idx += 256) {
        float s = 0.f;
        #pragma unroll
        for (int sb = 0; sb < 16; ++sb)
            s += tile[sb * 387 + idx];
        part[pslot * 384 + idx] = s;
    }
}

// ---------------- K1b: offset stage 2 -> paired gather tables ---------------
__global__ __launch_bounds__(256) void offset_s2_kernel(
    const float* __restrict__ part, const float* __restrict__ pb,
    int2* __restrict__ tbl_off, float4* __restrict__ tbl_w)
{
    int pix = blockIdx.x * 256 + threadIdx.x;   // grid=128
    int b = pix >> 12, rem = pix & 4095, i = rem >> 6, j = rem & 63;
    int bi = b * 64 + i;
    float v[6];
    #pragma unroll
    for (int tt = 0; tt < 6; ++tt) v[tt] = pb[tt];
    for (int g = 0; g < 8; ++g) {
        const float* pp = part + ((size_t)bi * 8 + g) * 384;
        #pragma unroll
        for (int tt = 0; tt < 6; ++tt) v[tt] += pp[tt * 64 + j];
    }
    const float pnx[3] = {0.f, 0.f, 1.f};
    const float pny[3] = {0.f, 1.f, 0.f};
    #pragma unroll
    for (int n = 0; n < 3; ++n) {
        float px_ = (float)i + pnx[n] + v[n];
        float py_ = (float)j + pny[n] + v[n + 3];
        float qx = floorf(px_), qy = floorf(py_);
        float qlx = fminf(fmaxf(qx,       0.f), 63.f);
        float qly = fminf(fmaxf(qy,       0.f), 63.f);
        float qrx = fminf(fmaxf(qx + 1.f, 0.f), 63.f);
        float qry = fminf(fmaxf(qy + 1.f, 0.f), 63.f);
        float pxc = fminf(fmaxf(px_,      0.f), 63.f);
        float pyc = fminf(fmaxf(py_,      0.f), 63.f);
        float glt = (1.f + (qlx - pxc)) * (1.f + (qly - pyc));
        float grb = (1.f - (qrx - pxc)) * (1.f - (qry - pyc));
        float glb = (1.f + (qlx - pxc)) * (1.f - (qry - pyc));
        float grt = (1.f - (qrx - pxc)) * (1.f + (qly - pyc));
        int ilx = (int)qlx, irx = (int)qrx;
        int ily = (int)qly, iry = (int)qry;
        int c0; float a0, a1, b0, b1;
        if (ily == iry) {
            if (ily == 0) { c0 = 0;  a0 = glt + glb; a1 = 0.f; b0 = grt + grb; b1 = 0.f; }
            else          { c0 = 62; a0 = 0.f; a1 = glt + glb; b0 = 0.f; b1 = grt + grb; }
        } else { c0 = ily; a0 = glt; a1 = glb; b0 = grt; b1 = grb; }
        int oi = (b * 3 + n) * HW_ + i * 64 + j;
        tbl_off[oi] = make_int2(ilx * 64 + c0, irx * 64 + c0);
        tbl_w[oi]   = make_float4(a0, a1, b0, b1);
    }
}

// ---------------- K2a: gather — HWC input, coalesced, XCD-swizzled ----------
__global__ __launch_bounds__(256) void gather_kernel(
    const float* __restrict__ xt, const int2* __restrict__ tbl_off,
    const float4* __restrict__ tbl_w, unsigned short* __restrict__ v)
{
    int blk = blockIdx.x;          // 1536
    int b = blk & 7;
    int rest = blk >> 3;           // 0..191
    int n = rest >> 6, i = rest & 63;
    int bi = b * 64 + i;
    int tid = threadIdx.x;
    int lane = tid & 63, wv = tid >> 6;
    int ci4 = lane * 4;
    const float* xb = xt + (size_t)b * 1048576;

    for (int it0 = 0; it0 < 16; it0 += 4) {
        float4 A[4], Bv[4], Cv[4], Dv[4], w4[4];
        #pragma unroll
        for (int u = 0; u < 4; ++u) {
            int j = wv * 16 + it0 + u;
            int oi = (b * 3 + n) * HW_ + i * 64 + j;
            int2 off = tbl_off[oi];
            w4[u] = tbl_w[oi];
            const float* p0 = xb + (size_t)off.x * 256 + ci4;
            const float* p1 = xb + (size_t)off.y * 256 + ci4;
            A[u]  = *(const float4*)p0;
            Bv[u] = *(const float4*)(p0 + 256);
            Cv[u] = *(const float4*)p1;
            Dv[u] = *(const float4*)(p1 + 256);
        }
        #pragma unroll
        for (int u = 0; u < 4; ++u) {
            int j = wv * 16 + it0 + u;
            int pix = bi * 64 + j;
            union { unsigned short h[4]; uint2 q; } pk;
            pk.h[0] = f2bf(w4[u].x*A[u].x + w4[u].y*Bv[u].x + w4[u].z*Cv[u].x + w4[u].w*Dv[u].x);
            pk.h[1] = f2bf(w4[u].x*A[u].y + w4[u].y*Bv[u].y + w4[u].z*Cv[u].y + w4[u].w*Dv[u].y);
            pk.h[2] = f2bf(w4[u].x*A[u].z + w4[u].y*Bv[u].z + w4[u].z*Cv[u].z + w4[u].w*Dv[u].z);
            pk.h[3] = f2bf(w4[u].x*A[u].w + w4[u].y*Bv[u].w + w4[u].z*Cv[u].w + w4[u].w*Dv[u].w);
            *(uint2*)&v[(size_t)pix * 768 + n * 256 + ci4] = pk.q;
        }
    }
}

// ---------------- K2b: AK GEMM (bf16 MFMA, 128co x 64pix tiles) -------------
// Round-0 proven 2-barrier structure + global_load_lds staging (m97 pattern).
// M split in half -> grid 1024 -> 4 blocks/CU (2x warps for latency hiding).
__global__ __launch_bounds__(256) void ak_mfma_kernel(
    const unsigned short* __restrict__ v, const unsigned short* __restrict__ W,
    unsigned short* __restrict__ yh, float* __restrict__ p1, float* __restrict__ p2)
{
    int blk = blockIdx.x;              // 1024
    int mt2 = blk & 1;                 // co half (anti-correlated with XCD id)
    int rest = blk >> 1;               // 0..511 = pixel-block id (partial slot)
    int b = rest & 7, i = rest >> 3;
    int tid = threadIdx.x;
    int wv = tid >> 6, lane = tid & 63;
    int quad = lane >> 4, l15 = lane & 15;
    __shared__ __align__(16) unsigned short sA[4096];   // [kq4][co128] x8
    __shared__ __align__(16) unsigned short sB[2048];   // [kq4][pix64] x8
    int pix0 = (b * 64 + i) * 64;
    int co0 = mt2 * 128;

    // staging decomposition (wave-uniform LDS dest + lane*16)
    int coS = tid & 127, shS = tid >> 7;    // A: co + k-subhalf
    int pixS = tid & 63, kqS = tid >> 6;    // B: pix + k-quad
    const unsigned short* wpA = W + (size_t)(co0 + coS) * 768;
    const unsigned short* vpB = v + (size_t)(pix0 + pixS) * 768;

    f32x4 acc[2][4];
    #pragma unroll
    for (int mt = 0; mt < 2; ++mt)
        #pragma unroll
        for (int nt = 0; nt < 4; ++nt) acc[mt][nt] = (f32x4){0.f, 0.f, 0.f, 0.f};

    for (int k0 = 0; k0 < 768; k0 += 32) {
        #pragma unroll
        for (int q = 0; q < 2; ++q) {
            int s = shS * 2 + q;
            gl2lds16(wpA + k0 + s * 8, &sA[(s * 128 + coS) * 8]);
        }
        gl2lds16(vpB + k0 + kqS * 8, &sB[(kqS * 64 + pixS) * 8]);
        __syncthreads();
        short8 af[2], bf[4];
        #pragma unroll
        for (int mt = 0; mt < 2; ++mt)
            af[mt] = *(const short8*)&sA[(quad * 128 + wv * 32 + mt * 16 + l15) * 8];
        #pragma unroll
        for (int nt = 0; nt < 4; ++nt)
            bf[nt] = *(const short8*)&sB[(quad * 64 + nt * 16 + l15) * 8];
        #pragma unroll
        for (int mt = 0; mt < 2; ++mt)
            #pragma unroll
            for (int nt = 0; nt < 4; ++nt)
                acc[mt][nt] = __builtin_amdgcn_mfma_f32_16x16x32_bf16(
                    af[mt], bf[nt], acc[mt][nt], 0, 0, 0);
        __syncthreads();
    }
    #pragma unroll
    for (int mt = 0; mt < 2; ++mt) {
        #pragma unroll
        for (int r = 0; r < 4; ++r) {
            int co = co0 + wv * 32 + mt * 16 + quad * 4 + r;
            size_t base = ((size_t)b * C_ + co) * HW_ + i * 64;
            float s1 = 0.f, s2 = 0.f;
            #pragma unroll
            for (int nt = 0; nt < 4; ++nt) {
                float val = acc[mt][nt][r];
                s1 += val; s2 += val * val;
                yh[base + nt * 16 + l15] = f2bf(val);
            }
            #pragma unroll
            for (int m = 1; m < 16; m <<= 1) {
                s1 += __shfl_xor(s1, m); s2 += __shfl_xor(s2, m);
            }
            if (l15 == 0) { p1[co * 512 + rest] = s1; p2[co * 512 + rest] = s2; }
        }
    }
}

// ---------------- K3: BN stats from partials --------------------------------
__global__ __launch_bounds__(256) void bn_stats_kernel(
    const float* __restrict__ p1, const float* __restrict__ p2,
    const float* __restrict__ gamma, const float* __restrict__ beta,
    float* __restrict__ ss)
{
    int co = blockIdx.x, tid = threadIdx.x;     // grid=256
    float a = p1[co * 512 + tid] + p1[co * 512 + 256 + tid];
    float q = p2[co * 512 + tid] + p2[co * 512 + 256 + tid];
    __shared__ float r1[256], r2[256];
    r1[tid] = a; r2[tid] = q; __syncthreads();
    for (int st = 128; st > 0; st >>= 1) {
        if (tid < st) { r1[tid] += r1[tid + st]; r2[tid] += r2[tid + st]; }
        __syncthreads();
    }
    if (tid == 0) {
        const float inv_n = 1.f / (float)NPIX;
        float m = r1[0] * inv_n;
        float var = r2[0] * inv_n - m * m;
        float sc = gamma[co] * rsqrtf(var + 1e-5f);
        ss[co] = sc; ss[256 + co] = beta[co] - m * sc;
    }
}

// ---------------- K4: fused BN+SiLU + 5x5 depthwise (XCD-swizzled) ----------
__global__ __launch_bounds__(256) void dw5_fused_kernel(
    const unsigned short* __restrict__ in, const float* __restrict__ ss,
    const float* __restrict__ w, const float* __restrict__ bias,
    unsigned short* __restrict__ out)
{
    int blkI = blockIdx.x;         // 2048
    int b = blkI & 7, c = blkI >> 3;
    int bc = b * 256 + c;
    int tid = threadIdx.x;
    __shared__ float tile[68 * 68];
    float sc = ss[c], sh = ss[256 + c];
    const unsigned short* ip = in + (size_t)bc * HW_;
    for (int s = tid; s < 68 * 68; s += 256) {
        int r = s / 68, cc = s - r * 68;
        int ii = r - 2, jj = cc - 2;
        float vv = 0.f;
        if (ii >= 0 && ii < 64 && jj >= 0 && jj < 64) {
            float t = b2f(ip[ii * 64 + jj]) * sc + sh;
            vv = silu_f(t);
        }
        tile[s] = vv;
    }
    float wr[25];
    #pragma unroll
    for (int t = 0; t < 25; ++t) wr[t] = w[c * 25 + t];
    float bv = bias[c];
    __syncthreads();
    int j0 = (tid & 15) * 4, ig = tid >> 4;
    unsigned short* op = out + (size_t)bc * HW_;
    for (int r = 0; r < 4; ++r) {
        int i = r * 16 + ig;
        float o0 = bv, o1 = bv, o2 = bv, o3 = bv;
        #pragma unroll
        for (int di = 0; di < 5; ++di) {
            const float* tp = &tile[(i + di) * 68 + j0];
            float4 a = *(const float4*)tp;
            float4 bq = *(const float4*)(tp + 4);
            float vv[8] = {a.x, a.y, a.z, a.w, bq.x, bq.y, bq.z, bq.w};
            #pragma unroll
            for (int dj = 0; dj < 5; ++dj) {
                float wv = wr[di * 5 + dj];
                o0 += wv * vv[dj];     o1 += wv * vv[dj + 1];
                o2 += wv * vv[dj + 2]; o3 += wv * vv[dj + 3];
            }
        }
        union { unsigned short h[4]; uint2 u; } pk;
        pk.h[0] = f2bf(o0); pk.h[1] = f2bf(o1);
        pk.h[2] = f2bf(o2); pk.h[3] = f2bf(o3);
        *(uint2*)&op[i * 64 + j0] = pk.u;
    }
}

// ---------------- K5: 7x7 dilated(3) depthwise (XCD-swizzled) ---------------
__global__ __launch_bounds__(256) void dw7d3_kernel(
    const unsigned short* __restrict__ in, const float* __restrict__ w,
    const float* __restrict__ bias, unsigned short* __restrict__ out)
{
    int blkI = blockIdx.x;         // 2048
    int b = blkI & 7, c = blkI >> 3;
    int bc = b * 256 + c;
    int tid = threadIdx.x;
    __shared__ float tile[82 * 84];
    const unsigned short* ip = in + (size_t)bc * HW_;
    for (int s = tid; s < 82 * 84; s += 256) {
        int r = s / 84, cc = s - r * 84;
        int ii = r - 9, jj = cc - 9;
        float vv = 0.f;
        if (ii >= 0 && ii < 64 && jj >= 0 && jj < 64) vv = b2f(ip[ii * 64 + jj]);
        tile[s] = vv;
    }
    float wr[49];
    #pragma unroll
    for (int t = 0; t < 49; ++t) wr[t] = w[c * 49 + t];
    float bv = bias[c];
    __syncthreads();
    int j0 = (tid & 15) * 4, ig = tid >> 4;
    unsigned short* op = out + (size_t)bc * HW_;
    for (int r = 0; r < 4; ++r) {
        int i = r * 16 + ig;
        float o0 = bv, o1 = bv, o2 = bv, o3 = bv;
        #pragma unroll
        for (int di = 0; di < 7; ++di) {
            const float* tp = &tile[(i + 3 * di) * 84 + j0];
            float vv[24];
            #pragma unroll
            for (int q = 0; q < 6; ++q)
                *(float4*)&vv[q * 4] = *(const float4*)(tp + q * 4);
            #pragma unroll
            for (int dj = 0; dj < 7; ++dj) {
                float wv = wr[di * 7 + dj];
                o0 += wv * vv[3 * dj];     o1 += wv * vv[3 * dj + 1];
                o2 += wv * vv[3 * dj + 2]; o3 += wv * vv[3 * dj + 3];
            }
        }
        union { unsigned short h[4]; uint2 u; } pk;
        pk.h[0] = f2bf(o0); pk.h[1] = f2bf(o1);
        pk.h[2] = f2bf(o2); pk.h[3] = f2bf(o3);
        *(uint2*)&op[i * 64 + j0] = pk.u;
    }
}

// ---------------- K6/K7: 1x1 conv bf16 MFMA GEMM (128co tiles) --------------
// Round-0 structure; A via global_load_lds, B (strided CHW) via registers.
template<int MODE>
__global__ __launch_bounds__(256) void gemm1x1_mfma(
    const unsigned short* __restrict__ in, const unsigned short* __restrict__ W,
    const float* __restrict__ bias,
    const unsigned short* __restrict__ auxh, const float* __restrict__ auxf,
    const float* __restrict__ ss,
    unsigned short* __restrict__ out_bf, float* __restrict__ out_f)
{
    int blk = blockIdx.x;              // 1024
    int mt2 = blk & 1;
    int rest = blk >> 1;               // 0..511
    int b = rest & 7, i = rest >> 3;
    int tid = threadIdx.x;
    int wv = tid >> 6, lane = tid & 63;
    int quad = lane >> 4, l15 = lane & 15;
    __shared__ __align__(16) unsigned short sA[4096];
    __shared__ __align__(16) unsigned short sB[2048];
    int co0 = mt2 * 128;

    int coS = tid & 127, shS = tid >> 7;
    int pixS = tid & 63, kqS = tid >> 6;
    const unsigned short* wpA = W + (size_t)(co0 + coS) * 256;
    const unsigned short* bp = in + ((size_t)b * C_) * HW_ + i * 64 + pixS;

    f32x4 acc[2][4];
    #pragma unroll
    for (int mt = 0; mt < 2; ++mt)
        #pragma unroll
        for (int nt = 0; nt < 4; ++nt) acc[mt][nt] = (f32x4){0.f, 0.f, 0.f, 0.f};

    for (int k0 = 0; k0 < 256; k0 += 32) {
        #pragma unroll
        for (int q = 0; q < 2; ++q) {
            int s = shS * 2 + q;
            gl2lds16(wpA + k0 + s * 8, &sA[(s * 128 + coS) * 8]);
        }
        {
            const unsigned short* p = bp + (size_t)(k0 + kqS * 8) * HW_;
            union { unsigned short h[8]; uint4 u; } hb;
            #pragma unroll
            for (int jj = 0; jj < 8; ++jj) hb.h[jj] = p[(size_t)jj * HW_];
            *(uint4*)&sB[(kqS * 64 + pixS) * 8] = hb.u;
        }
        __syncthreads();
        short8 af[2], bf[4];
        #pragma unroll
        for (int mt = 0; mt < 2; ++mt)
            af[mt] = *(const short8*)&sA[(quad * 128 + wv * 32 + mt * 16 + l15) * 8];
        #pragma unroll
        for (int nt = 0; nt < 4; ++nt)
            bf[nt] = *(const short8*)&sB[(quad * 64 + nt * 16 + l15) * 8];
        #pragma unroll
        for (int mt = 0; mt < 2; ++mt)
            #pragma unroll
            for (int nt = 0; nt < 4; ++nt)
                acc[mt][nt] = __builtin_amdgcn_mfma_f32_16x16x32_bf16(
                    af[mt], bf[nt], acc[mt][nt], 0, 0, 0);
        __syncthreads();
    }
    #pragma unroll
    for (int mt = 0; mt < 2; ++mt) {
        #pragma unroll
        for (int r = 0; r < 4; ++r) {
            int co = co0 + wv * 32 + mt * 16 + quad * 4 + r;
            float bco = bias[co];
            size_t base = ((size_t)b * C_ + co) * HW_ + i * 64;
            if (MODE == 0) {
                float sc = ss[co], sh = ss[256 + co];
                #pragma unroll
                for (int nt = 0; nt < 4; ++nt) {
                    int col = nt * 16 + l15;
                    float o = acc[mt][nt][r] + bco;
                    float u = silu_f(b2f(auxh[base + col]) * sc + sh);
                    out_bf[base + col] = f2bf(o * u);
                }
            } else {
                #pragma unroll
                for (int nt = 0; nt < 4; ++nt) {
                    int col = nt * 16 + l15;
                    out_f[base + col] = acc[mt][nt][r] + bco + auxf[base + col];
                }
            }
        }
    }
}

// ---------------- launch ----------------------------------------------------
extern "C" void kernel_launch(void* const* d_in, const int* in_sizes, int n_in,
                              void* d_out, int out_size, void* d_ws, size_t ws_size,
                              hipStream_t stream) {
    const float* x     = (const float*)d_in[0];
    const float* p_w   = (const float*)d_in[1];
    const float* p_b   = (const float*)d_in[2];
    const float* ak_w  = (const float*)d_in[3];
    const float* ak_g  = (const float*)d_in[4];
    const float* ak_b  = (const float*)d_in[5];
    const float* l0_w  = (const float*)d_in[6];
    const float* l0_b  = (const float*)d_in[7];
    const float* ls_w  = (const float*)d_in[8];
    const float* ls_b  = (const float*)d_in[9];
    const float* l1_w  = (const float*)d_in[10];
    const float* l1_b  = (const float*)d_in[11];
    const float* cv_w  = (const float*)d_in[12];
    const float* cv_b  = (const float*)d_in[13];
    float* out = (float*)d_out;

    char* w = (char*)d_ws;
    int2*   tbl_off = (int2*)w;                              // 786 KB
    float4* tbl_w   = (float4*)(w + 786432);                 // 1.5 MB
    unsigned short* wak = (unsigned short*)(w + 2359296);    // 384 KB
    unsigned short* wl1 = (unsigned short*)(w + 2752512);    // 128 KB
    unsigned short* wcv = (unsigned short*)(w + 2883584);    // 128 KB
    float* p1 = (float*)(w + 3014656);                       // 512 KB
    float* p2 = (float*)(w + 3538944);                       // 512 KB
    float* ss = (float*)(w + 4063232);                       // 2 KB
    float* pwt = (float*)(w + 4065280);                      // 72 KB
    // time-multiplexed regions:
    float* xt   = (float*)(w + 4194304);                     // 32 MB (dead after gather)
    unsigned short* ybh    = (unsigned short*)(w + 4194304); // 16 MB (ak writes, after gather)
    unsigned short* dw5out = (unsigned short*)(w + 20971520);// 16 MB
    float* part = (float*)(w + 37748736);                    // 6.3 MB (dead after s2)
    unsigned short* attn   = (unsigned short*)(w + 37748736);// 16 MB (dw7 out)
    unsigned short* v      = (unsigned short*)(w + 44040192);// 48 MB (dead after ak)
    unsigned short* g0out  = (unsigned short*)(w + 54525952);// 16 MB (after gemm0)

    prep_kernel<<<1352, 256, 0, stream>>>(ak_w, l1_w, cv_w, p_w, wak, wl1, wcv, pwt);
    offset_s1_kernel<<<4096, 256, 0, stream>>>(x, pwt, part);
    offset_s2_kernel<<<128, 256, 0, stream>>>(part, p_b, tbl_off, tbl_w);
    transpose_kernel<<<1024, 256, 0, stream>>>(x, xt);
    gather_kernel<<<1536, 256, 0, stream>>>(xt, tbl_off, tbl_w, v);
    ak_mfma_kernel<<<1024, 256, 0, stream>>>(v, wak, ybh, p1, p2);
    bn_stats_kernel<<<256, 256, 0, stream>>>(p1, p2, ak_g, ak_b, ss);
    dw5_fused_kernel<<<2048, 256, 0, stream>>>(ybh, ss, l0_w, l0_b, dw5out);
    dw7d3_kernel<<<2048, 256, 0, stream>>>(dw5out, ls_w, ls_b, attn);
    gemm1x1_mfma<0><<<1024, 256, 0, stream>>>(attn, wl1, l1_b, ybh, nullptr, ss, g0out, nullptr);
    gemm1x1_mfma<1><<<1024, 256, 0, stream>>>(g0out, wcv, cv_b, nullptr, x, nullptr, nullptr, out);
}

// Round 3
// 320.620 us; speedup vs baseline: 1.0671x; 1.0170x over previous
//
#include <hip/hip_runtime.h>
#include <math.h>
#include <stdint.h>

#define B_ 8
#define C_ 256
#define HW_ 4096
#define NPIX 32768
#define NELEM (B_*C_*HW_)   // 8388608

typedef __attribute__((ext_vector_type(8))) short short8;
typedef __attribute__((ext_vector_type(4))) float f32x4;

__device__ __forceinline__ unsigned short f2bf(float f) {
    union { float f; uint32_t u; } v; v.f = f;
    uint32_t r = v.u + 0x7FFFu + ((v.u >> 16) & 1u);
    return (unsigned short)(r >> 16);
}
__device__ __forceinline__ float b2f(unsigned short h) {
    union { uint32_t u; float f; } v; v.u = ((uint32_t)h) << 16; return v.f;
}
__device__ __forceinline__ float silu_f(float v) { return v / (1.f + __expf(-v)); }

// barrier that does NOT drain vmcnt: ds_writes visible (lgkmcnt0) + rendezvous.
// Prefetched global->reg loads stay in flight across it (compiler inserts the
// vmcnt wait at the ds_write that consumes them).
__device__ __forceinline__ void lds_barrier() {
    asm volatile("s_waitcnt lgkmcnt(0)" ::: "memory");
    __builtin_amdgcn_s_barrier();
}

// ---------------- K0: weight conversion + p_w transpose ---------------------
__global__ __launch_bounds__(256) void prep_kernel(
    const float* __restrict__ akw, const float* __restrict__ l1w,
    const float* __restrict__ cvw, const float* __restrict__ pw,
    unsigned short* __restrict__ wak, unsigned short* __restrict__ wl1,
    unsigned short* __restrict__ wcv, float* __restrict__ pwt)
{
    int gid = blockIdx.x * 256 + threadIdx.x;      // grid=1352
    if (gid < 196608) {
        unsigned co = (unsigned)gid / 768u;
        unsigned kp = (unsigned)gid - co * 768u;   // k'' = n*256+ci
        unsigned n = kp >> 8, ci = kp & 255;
        wak[gid] = f2bf(akw[co * 768 + ci * 3 + n]);
    }
    else if (gid < 262144) { int g = gid - 196608; wl1[g] = f2bf(l1w[g]); }
    else if (gid < 327680) { int g = gid - 262144; wcv[g] = f2bf(cvw[g]); }
    else if (gid < 346112) {
        int idx = gid - 327680;
        int ci = idx / 72, r = idx - ci * 72;
        int tt = r / 12, t9 = r - tt * 12;
        pwt[idx] = (t9 < 9) ? pw[tt * 2304 + ci * 9 + t9] : 0.f;
    }
}

// ---------------- K0b: x CHW -> HWC transpose (XCD-swizzled) ----------------
__global__ __launch_bounds__(256) void transpose_kernel(
    const float* __restrict__ x, float* __restrict__ xt)
{
    int blk = blockIdx.x;            // 1024
    int b = blk & 7;
    int rest = blk >> 3;             // 0..127
    int half = rest & 1, i = rest >> 1;
    int bi = b * 64 + i;
    int tid = threadIdx.x;
    __shared__ float tile[64 * 132];

    {
        int ci_l = tid >> 6, jj = tid & 63;
        const float* ip = x + ((size_t)b * C_ + half * 128 + ci_l) * HW_ + i * 64 + jj;
        #pragma unroll 4
        for (int it = 0; it < 32; ++it)
            tile[jj * 132 + ci_l + it * 4] = ip[(size_t)it * 4 * HW_];
    }
    __syncthreads();
    {
        int j = tid >> 2, q = tid & 3;
        float* op = xt + ((size_t)(bi * 64 + j)) * 256 + half * 128 + q * 32;
        #pragma unroll
        for (int f = 0; f < 8; ++f)
            *(float4*)(op + f * 4) = *(const float4*)&tile[j * 132 + q * 32 + f * 4];
    }
}

// ---------------- K1a: offset conv stage 1 (v5: register acc, small tree) ---
__global__ __launch_bounds__(256) void offset_s1_kernel(
    const float* __restrict__ x, const float* __restrict__ pwt,
    float* __restrict__ part)          // [bi*8+g][6][64]
{
    int blk = blockIdx.x;              // 4096
    int b = blk & 7;
    int rest = blk >> 3;               // 0..511
    int g = rest & 7, i = rest >> 3;
    int bi = b * 64 + i;
    int tid = threadIdx.x;

    __shared__ float tile[6600];       // x tile [(row*66+col)*33+ci]; aliased as s2[16][387]

    // ---- stage x tile (transposed, halo-padded) ----
    {
        int cs = tid >> 3, r8 = tid & 7;
        const float* xp = x + ((size_t)b * C_ + g * 32 + cs) * HW_;
        #pragma unroll
        for (int t = 0; t < 6; ++t) {
            int idx = r8 * 6 + t;
            int r = idx >> 4, v4 = idx & 15;
            int ii = i + r - 1;
            float4 val = make_float4(0.f, 0.f, 0.f, 0.f);
            if (ii >= 0 && ii < 64)
                val = *(const float4*)(xp + ii * 64 + v4 * 4);
            int base = (r * 66 + 1 + v4 * 4) * 33 + cs;
            tile[base]      = val.x;  tile[base + 33]  = val.y;
            tile[base + 66] = val.z;  tile[base + 99]  = val.w;
        }
        if (tid < 192) {
            int ci = tid / 6, rem = tid - ci * 6;
            int ki = rem >> 1, side = rem & 1;
            tile[(ki * 66 + side * 65) * 33 + ci] = 0.f;
        }
    }
    __syncthreads();

    int sub = tid >> 4;                // 0..15
    int jq  = tid & 15;                // 0..15: pixels jq*4 .. jq*4+3

    float acc[6][4];
    #pragma unroll
    for (int tt = 0; tt < 6; ++tt)
        #pragma unroll
        for (int p = 0; p < 4; ++p) acc[tt][p] = 0.f;

    #pragma unroll
    for (int t = 0; t < 2; ++t) {
        int ci = sub + 16 * t;
        float xv[3][6];                // tile cols jq*4 .. jq*4+5
        #pragma unroll
        for (int ki = 0; ki < 3; ++ki)
            #pragma unroll
            for (int cc = 0; cc < 6; ++cc)
                xv[ki][cc] = tile[(ki * 66 + jq * 4 + cc) * 33 + ci];
        const float* wp = pwt + (g * 32 + ci) * 72;
        #pragma unroll
        for (int tt = 0; tt < 6; ++tt) {
            float w[9];
            *(float4*)&w[0] = *(const float4*)(wp + tt * 12);
            *(float4*)&w[4] = *(const float4*)(wp + tt * 12 + 4);
            w[8] = wp[tt * 12 + 8];
            #pragma unroll
            for (int ki = 0; ki < 3; ++ki)
                #pragma unroll
                for (int kj = 0; kj < 3; ++kj) {
                    float wgt = w[ki * 3 + kj];
                    #pragma unroll
                    for (int p = 0; p < 4; ++p)
                        acc[tt][p] += wgt * xv[ki][kj + p];
                }
        }
    }

    // ---- 16-sub reduction via LDS tree (alias tile as s2, stride 387) ----
    __syncthreads();
    {
        float* s2 = tile + sub * 387;
        #pragma unroll
        for (int tt = 0; tt < 6; ++tt)
            #pragma unroll
            for (int p = 0; p < 4; ++p)
                s2[tt * 64 + jq * 4 + p] = acc[tt][p];
    }
    __syncthreads();
    size_t pslot = (size_t)bi * 8 + g;
    for (int idx = tid; idx < 384; idx += 256) {
        float s = 0.f;
        #pragma unroll
        for (int sb = 0; sb < 16; ++sb)
            s += tile[sb * 387 + idx];
        part[pslot * 384 + idx] = s;
    }
}

// ---------------- K1b: offset stage 2 -> paired gather tables ---------------
__global__ __launch_bounds__(256) void offset_s2_kernel(
    const float* __restrict__ part, const float* __restrict__ pb,
    int2* __restrict__ tbl_off, float4* __restrict__ tbl_w)
{
    int pix = blockIdx.x * 256 + threadIdx.x;   // grid=128
    int b = pix >> 12, rem = pix & 4095, i = rem >> 6, j = rem & 63;
    int bi = b * 64 + i;
    float v[6];
    #pragma unroll
    for (int tt = 0; tt < 6; ++tt) v[tt] = pb[tt];
    for (int g = 0; g < 8; ++g) {
        const float* pp = part + ((size_t)bi * 8 + g) * 384;
        #pragma unroll
        for (int tt = 0; tt < 6; ++tt) v[tt] += pp[tt * 64 + j];
    }
    const float pnx[3] = {0.f, 0.f, 1.f};
    const float pny[3] = {0.f, 1.f, 0.f};
    #pragma unroll
    for (int n = 0; n < 3; ++n) {
        float px_ = (float)i + pnx[n] + v[n];
        float py_ = (float)j + pny[n] + v[n + 3];
        float qx = floorf(px_), qy = floorf(py_);
        float qlx = fminf(fmaxf(qx,       0.f), 63.f);
        float qly = fminf(fmaxf(qy,       0.f), 63.f);
        float qrx = fminf(fmaxf(qx + 1.f, 0.f), 63.f);
        float qry = fminf(fmaxf(qy + 1.f, 0.f), 63.f);
        float pxc = fminf(fmaxf(px_,      0.f), 63.f);
        float pyc = fminf(fmaxf(py_,      0.f), 63.f);
        float glt = (1.f + (qlx - pxc)) * (1.f + (qly - pyc));
        float grb = (1.f - (qrx - pxc)) * (1.f - (qry - pyc));
        float glb = (1.f + (qlx - pxc)) * (1.f - (qry - pyc));
        float grt = (1.f - (qrx - pxc)) * (1.f + (qly - pyc));
        int ilx = (int)qlx, irx = (int)qrx;
        int ily = (int)qly, iry = (int)qry;
        int c0; float a0, a1, b0, b1;
        if (ily == iry) {
            if (ily == 0) { c0 = 0;  a0 = glt + glb; a1 = 0.f; b0 = grt + grb; b1 = 0.f; }
            else          { c0 = 62; a0 = 0.f; a1 = glt + glb; b0 = 0.f; b1 = grt + grb; }
        } else { c0 = ily; a0 = glt; a1 = glb; b0 = grt; b1 = grb; }
        int oi = (b * 3 + n) * HW_ + i * 64 + j;
        tbl_off[oi] = make_int2(ilx * 64 + c0, irx * 64 + c0);
        tbl_w[oi]   = make_float4(a0, a1, b0, b1);
    }
}

// ---------------- K2a: gather — HWC input, coalesced, XCD-swizzled ----------
__global__ __launch_bounds__(256) void gather_kernel(
    const float* __restrict__ xt, const int2* __restrict__ tbl_off,
    const float4* __restrict__ tbl_w, unsigned short* __restrict__ v)
{
    int blk = blockIdx.x;          // 1536
    int b = blk & 7;
    int rest = blk >> 3;           // 0..191
    int n = rest >> 6, i = rest & 63;
    int bi = b * 64 + i;
    int tid = threadIdx.x;
    int lane = tid & 63, wv = tid >> 6;
    int ci4 = lane * 4;
    const float* xb = xt + (size_t)b * 1048576;

    for (int it0 = 0; it0 < 16; it0 += 4) {
        float4 A[4], Bv[4], Cv[4], Dv[4], w4[4];
        #pragma unroll
        for (int u = 0; u < 4; ++u) {
            int j = wv * 16 + it0 + u;
            int oi = (b * 3 + n) * HW_ + i * 64 + j;
            int2 off = tbl_off[oi];
            w4[u] = tbl_w[oi];
            const float* p0 = xb + (size_t)off.x * 256 + ci4;
            const float* p1 = xb + (size_t)off.y * 256 + ci4;
            A[u]  = *(const float4*)p0;
            Bv[u] = *(const float4*)(p0 + 256);
            Cv[u] = *(const float4*)p1;
            Dv[u] = *(const float4*)(p1 + 256);
        }
        #pragma unroll
        for (int u = 0; u < 4; ++u) {
            int j = wv * 16 + it0 + u;
            int pix = bi * 64 + j;
            union { unsigned short h[4]; uint2 q; } pk;
            pk.h[0] = f2bf(w4[u].x*A[u].x + w4[u].y*Bv[u].x + w4[u].z*Cv[u].x + w4[u].w*Dv[u].x);
            pk.h[1] = f2bf(w4[u].x*A[u].y + w4[u].y*Bv[u].y + w4[u].z*Cv[u].y + w4[u].w*Dv[u].y);
            pk.h[2] = f2bf(w4[u].x*A[u].z + w4[u].y*Bv[u].z + w4[u].z*Cv[u].z + w4[u].w*Dv[u].z);
            pk.h[3] = f2bf(w4[u].x*A[u].w + w4[u].y*Bv[u].w + w4[u].z*Cv[u].w + w4[u].w*Dv[u].w);
            *(uint2*)&v[(size_t)pix * 768 + n * 256 + ci4] = pk.q;
        }
    }
}

// ---------------- K2b: AK GEMM (bf16 MFMA, 128co x 64pix tiles) -------------
// Single-barrier double-buffer, distance-2 register prefetch, raw s_barrier
// (no vmcnt drain -> prefetch stays in flight across barriers).
// XCD pairing: co-halves of the same pixel block land on the same XCD.
__global__ __launch_bounds__(256) void ak_mfma_kernel(
    const unsigned short* __restrict__ v, const unsigned short* __restrict__ W,
    unsigned short* __restrict__ yh, float* __restrict__ p1, float* __restrict__ p2)
{
    int pid = blockIdx.x;              // 1024
    int mt2 = (pid >> 3) & 1;          // co half; pid and pid+8 share XCD (%8)
    int rest = (pid & 7) | ((pid >> 4) << 3);   // pixel block 0..511
    int b = rest & 7, i = rest >> 3;
    int tid = threadIdx.x;
    int wv = tid >> 6, lane = tid & 63;
    int quad = lane >> 4, l15 = lane & 15;
    __shared__ __align__(16) unsigned short sA[2][4096];   // [kq4][co128] x8
    __shared__ __align__(16) unsigned short sB[2][2048];   // [kq4][pix64] x8
    int pix0 = (b * 64 + i) * 64;
    int co0 = mt2 * 128;

    int coS = tid & 127, shS = tid >> 7;    // A: 2 x 16B per thread
    int pixS = tid & 63, kqS = tid >> 6;    // B: 1 x 16B per thread
    const unsigned short* wpA = W + (size_t)(co0 + coS) * 768;
    const unsigned short* vpB = v + (size_t)(pix0 + pixS) * 768;

    f32x4 acc[2][4];
    #pragma unroll
    for (int mt = 0; mt < 2; ++mt)
        #pragma unroll
        for (int nt = 0; nt < 4; ++nt) acc[mt][nt] = (f32x4){0.f, 0.f, 0.f, 0.f};

    uint4 a0A, a1A, bA;                     // prefetch set A (even tiles)
    uint4 a0B, a1B, bB;                     // prefetch set B (odd tiles)

    auto loadSetA = [&](int k0) {
        a0A = *(const uint4*)(wpA + k0 + (shS * 2 + 0) * 8);
        a1A = *(const uint4*)(wpA + k0 + (shS * 2 + 1) * 8);
        bA  = *(const uint4*)(vpB + k0 + kqS * 8);
    };
    auto loadSetB = [&](int k0) {
        a0B = *(const uint4*)(wpA + k0 + (shS * 2 + 0) * 8);
        a1B = *(const uint4*)(wpA + k0 + (shS * 2 + 1) * 8);
        bB  = *(const uint4*)(vpB + k0 + kqS * 8);
    };
    auto compute = [&](const unsigned short* cA, const unsigned short* cB) {
        short8 af[2], bf[4];
        #pragma unroll
        for (int mt = 0; mt < 2; ++mt)
            af[mt] = *(const short8*)&cA[(quad * 128 + wv * 32 + mt * 16 + l15) * 8];
        #pragma unroll
        for (int nt = 0; nt < 4; ++nt)
            bf[nt] = *(const short8*)&cB[(quad * 64 + nt * 16 + l15) * 8];
        #pragma unroll
        for (int mt = 0; mt < 2; ++mt)
            #pragma unroll
            for (int nt = 0; nt < 4; ++nt)
                acc[mt][nt] = __builtin_amdgcn_mfma_f32_16x16x32_bf16(
                    af[mt], bf[nt], acc[mt][nt], 0, 0, 0);
    };

    loadSetA(0);
    loadSetB(32);
    for (int t2 = 0; t2 < 12; ++t2) {
        // even step: buffer 0, set A
        *(uint4*)&sA[0][((shS * 2 + 0) * 128 + coS) * 8] = a0A;
        *(uint4*)&sA[0][((shS * 2 + 1) * 128 + coS) * 8] = a1A;
        *(uint4*)&sB[0][(kqS * 64 + pixS) * 8] = bA;
        if (t2 < 11) loadSetA((t2 * 2 + 2) * 32);
        lds_barrier();
        compute(sA[0], sB[0]);
        // odd step: buffer 1, set B
        *(uint4*)&sA[1][((shS * 2 + 0) * 128 + coS) * 8] = a0B;
        *(uint4*)&sA[1][((shS * 2 + 1) * 128 + coS) * 8] = a1B;
        *(uint4*)&sB[1][(kqS * 64 + pixS) * 8] = bB;
        if (t2 < 11) loadSetB((t2 * 2 + 3) * 32);
        lds_barrier();
        compute(sA[1], sB[1]);
    }
    #pragma unroll
    for (int mt = 0; mt < 2; ++mt) {
        #pragma unroll
        for (int r = 0; r < 4; ++r) {
            int co = co0 + wv * 32 + mt * 16 + quad * 4 + r;
            size_t base = ((size_t)b * C_ + co) * HW_ + i * 64;
            float s1 = 0.f, s2 = 0.f;
            #pragma unroll
            for (int nt = 0; nt < 4; ++nt) {
                float val = acc[mt][nt][r];
                s1 += val; s2 += val * val;
                yh[base + nt * 16 + l15] = f2bf(val);
            }
            #pragma unroll
            for (int m = 1; m < 16; m <<= 1) {
                s1 += __shfl_xor(s1, m); s2 += __shfl_xor(s2, m);
            }
            if (l15 == 0) { p1[co * 512 + rest] = s1; p2[co * 512 + rest] = s2; }
        }
    }
}

// ---------------- K3: BN stats from partials --------------------------------
__global__ __launch_bounds__(256) void bn_stats_kernel(
    const float* __restrict__ p1, const float* __restrict__ p2,
    const float* __restrict__ gamma, const float* __restrict__ beta,
    float* __restrict__ ss)
{
    int co = blockIdx.x, tid = threadIdx.x;     // grid=256
    float a = p1[co * 512 + tid] + p1[co * 512 + 256 + tid];
    float q = p2[co * 512 + tid] + p2[co * 512 + 256 + tid];
    __shared__ float r1[256], r2[256];
    r1[tid] = a; r2[tid] = q; __syncthreads();
    for (int st = 128; st > 0; st >>= 1) {
        if (tid < st) { r1[tid] += r1[tid + st]; r2[tid] += r2[tid + st]; }
        __syncthreads();
    }
    if (tid == 0) {
        const float inv_n = 1.f / (float)NPIX;
        float m = r1[0] * inv_n;
        float var = r2[0] * inv_n - m * m;
        float sc = gamma[co] * rsqrtf(var + 1e-5f);
        ss[co] = sc; ss[256 + co] = beta[co] - m * sc;
    }
}

// ---------------- K4: fused BN+SiLU + 5x5 depthwise (XCD-swizzled) ----------
__global__ __launch_bounds__(256) void dw5_fused_kernel(
    const unsigned short* __restrict__ in, const float* __restrict__ ss,
    const float* __restrict__ w, const float* __restrict__ bias,
    unsigned short* __restrict__ out)
{
    int blkI = blockIdx.x;         // 2048
    int b = blkI & 7, c = blkI >> 3;
    int bc = b * 256 + c;
    int tid = threadIdx.x;
    __shared__ float tile[68 * 68];
    float sc = ss[c], sh = ss[256 + c];
    const unsigned short* ip = in + (size_t)bc * HW_;
    for (int s = tid; s < 68 * 68; s += 256) {
        int r = s / 68, cc = s - r * 68;
        int ii = r - 2, jj = cc - 2;
        float vv = 0.f;
        if (ii >= 0 && ii < 64 && jj >= 0 && jj < 64) {
            float t = b2f(ip[ii * 64 + jj]) * sc + sh;
            vv = silu_f(t);
        }
        tile[s] = vv;
    }
    float wr[25];
    #pragma unroll
    for (int t = 0; t < 25; ++t) wr[t] = w[c * 25 + t];
    float bv = bias[c];
    __syncthreads();
    int j0 = (tid & 15) * 4, ig = tid >> 4;
    unsigned short* op = out + (size_t)bc * HW_;
    for (int r = 0; r < 4; ++r) {
        int i = r * 16 + ig;
        float o0 = bv, o1 = bv, o2 = bv, o3 = bv;
        #pragma unroll
        for (int di = 0; di < 5; ++di) {
            const float* tp = &tile[(i + di) * 68 + j0];
            float4 a = *(const float4*)tp;
            float4 bq = *(const float4*)(tp + 4);
            float vv[8] = {a.x, a.y, a.z, a.w, bq.x, bq.y, bq.z, bq.w};
            #pragma unroll
            for (int dj = 0; dj < 5; ++dj) {
                float wv = wr[di * 5 + dj];
                o0 += wv * vv[dj];     o1 += wv * vv[dj + 1];
                o2 += wv * vv[dj + 2]; o3 += wv * vv[dj + 3];
            }
        }
        union { unsigned short h[4]; uint2 u; } pk;
        pk.h[0] = f2bf(o0); pk.h[1] = f2bf(o1);
        pk.h[2] = f2bf(o2); pk.h[3] = f2bf(o3);
        *(uint2*)&op[i * 64 + j0] = pk.u;
    }
}

// ---------------- K5: 7x7 dilated(3) depthwise (XCD-swizzled) ---------------
__global__ __launch_bounds__(256) void dw7d3_kernel(
    const unsigned short* __restrict__ in, const float* __restrict__ w,
    const float* __restrict__ bias, unsigned short* __restrict__ out)
{
    int blkI = blockIdx.x;         // 2048
    int b = blkI & 7, c = blkI >> 3;
    int bc = b * 256 + c;
    int tid = threadIdx.x;
    __shared__ float tile[82 * 84];
    const unsigned short* ip = in + (size_t)bc * HW_;
    for (int s = tid; s < 82 * 84; s += 256) {
        int r = s / 84, cc = s - r * 84;
        int ii = r - 9, jj = cc - 9;
        float vv = 0.f;
        if (ii >= 0 && ii < 64 && jj >= 0 && jj < 64) vv = b2f(ip[ii * 64 + jj]);
        tile[s] = vv;
    }
    float wr[49];
    #pragma unroll
    for (int t = 0; t < 49; ++t) wr[t] = w[c * 49 + t];
    float bv = bias[c];
    __syncthreads();
    int j0 = (tid & 15) * 4, ig = tid >> 4;
    unsigned short* op = out + (size_t)bc * HW_;
    for (int r = 0; r < 4; ++r) {
        int i = r * 16 + ig;
        float o0 = bv, o1 = bv, o2 = bv, o3 = bv;
        #pragma unroll
        for (int di = 0; di < 7; ++di) {
            const float* tp = &tile[(i + 3 * di) * 84 + j0];
            float vv[24];
            #pragma unroll
            for (int q = 0; q < 6; ++q)
                *(float4*)&vv[q * 4] = *(const float4*)(tp + q * 4);
            #pragma unroll
            for (int dj = 0; dj < 7; ++dj) {
                float wv = wr[di * 7 + dj];
                o0 += wv * vv[3 * dj];     o1 += wv * vv[3 * dj + 1];
                o2 += wv * vv[3 * dj + 2]; o3 += wv * vv[3 * dj + 3];
            }
        }
        union { unsigned short h[4]; uint2 u; } pk;
        pk.h[0] = f2bf(o0); pk.h[1] = f2bf(o1);
        pk.h[2] = f2bf(o2); pk.h[3] = f2bf(o3);
        *(uint2*)&op[i * 64 + j0] = pk.u;
    }
}

// ---------------- K6/K7: 1x1 conv bf16 MFMA GEMM (pipelined, 128co) ---------
// Same single-barrier double-buffer + distance-2 prefetch structure.
template<int MODE>
__global__ __launch_bounds__(256) void gemm1x1_mfma(
    const unsigned short* __restrict__ in, const unsigned short* __restrict__ W,
    const float* __restrict__ bias,
    const unsigned short* __restrict__ auxh, const float* __restrict__ auxf,
    const float* __restrict__ ss,
    unsigned short* __restrict__ out_bf, float* __restrict__ out_f)
{
    int pid = blockIdx.x;              // 1024
    int mt2 = (pid >> 3) & 1;          // co half; pairs share XCD
    int rest = (pid & 7) | ((pid >> 4) << 3);   // pixel block 0..511
    int b = rest & 7, i = rest >> 3;
    int tid = threadIdx.x;
    int wv = tid >> 6, lane = tid & 63;
    int quad = lane >> 4, l15 = lane & 15;
    __shared__ __align__(16) unsigned short sA[2][4096];
    __shared__ __align__(16) unsigned short sB[2][2048];
    int co0 = mt2 * 128;

    int coS = tid & 127, shS = tid >> 7;
    int pixS = tid & 63, kqS = tid >> 6;
    const unsigned short* wpA = W + (size_t)(co0 + coS) * 256;
    const unsigned short* bp = in + ((size_t)b * C_) * HW_ + i * 64 + pixS;

    f32x4 acc[2][4];
    #pragma unroll
    for (int mt = 0; mt < 2; ++mt)
        #pragma unroll
        for (int nt = 0; nt < 4; ++nt) acc[mt][nt] = (f32x4){0.f, 0.f, 0.f, 0.f};

    uint4 a0A, a1A, a0B, a1B;
    union U8 { unsigned short h[8]; uint4 u; };
    U8 hbA, hbB;

    auto loadSetA = [&](int k0) {
        a0A = *(const uint4*)(wpA + k0 + (shS * 2 + 0) * 8);
        a1A = *(const uint4*)(wpA + k0 + (shS * 2 + 1) * 8);
        const unsigned short* p = bp + (size_t)(k0 + kqS * 8) * HW_;
        #pragma unroll
        for (int jj = 0; jj < 8; ++jj) hbA.h[jj] = p[(size_t)jj * HW_];
    };
    auto loadSetB = [&](int k0) {
        a0B = *(const uint4*)(wpA + k0 + (shS * 2 + 0) * 8);
        a1B = *(const uint4*)(wpA + k0 + (shS * 2 + 1) * 8);
        const unsigned short* p = bp + (size_t)(k0 + kqS * 8) * HW_;
        #pragma unroll
        for (int jj = 0; jj < 8; ++jj) hbB.h[jj] = p[(size_t)jj * HW_];
    };
    auto compute = [&](const unsigned short* cA, const unsigned short* cB) {
        short8 af[2], bf[4];
        #pragma unroll
        for (int mt = 0; mt < 2; ++mt)
            af[mt] = *(const short8*)&cA[(quad * 128 + wv * 32 + mt * 16 + l15) * 8];
        #pragma unroll
        for (int nt = 0; nt < 4; ++nt)
            bf[nt] = *(const short8*)&cB[(quad * 64 + nt * 16 + l15) * 8];
        #pragma unroll
        for (int mt = 0; mt < 2; ++mt)
            #pragma unroll
            for (int nt = 0; nt < 4; ++nt)
                acc[mt][nt] = __builtin_amdgcn_mfma_f32_16x16x32_bf16(
                    af[mt], bf[nt], acc[mt][nt], 0, 0, 0);
    };

    loadSetA(0);
    loadSetB(32);
    for (int t2 = 0; t2 < 4; ++t2) {
        *(uint4*)&sA[0][((shS * 2 + 0) * 128 + coS) * 8] = a0A;
        *(uint4*)&sA[0][((shS * 2 + 1) * 128 + coS) * 8] = a1A;
        *(uint4*)&sB[0][(kqS * 64 + pixS) * 8] = hbA.u;
        if (t2 < 3) loadSetA((t2 * 2 + 2) * 32);
        lds_barrier();
        compute(sA[0], sB[0]);
        *(uint4*)&sA[1][((shS * 2 + 0) * 128 + coS) * 8] = a0B;
        *(uint4*)&sA[1][((shS * 2 + 1) * 128 + coS) * 8] = a1B;
        *(uint4*)&sB[1][(kqS * 64 + pixS) * 8] = hbB.u;
        if (t2 < 3) loadSetB((t2 * 2 + 3) * 32);
        lds_barrier();
        compute(sA[1], sB[1]);
    }
    #pragma unroll
    for (int mt = 0; mt < 2; ++mt) {
        #pragma unroll
        for (int r = 0; r < 4; ++r) {
            int co = co0 + wv * 32 + mt * 16 + quad * 4 + r;
            float bco = bias[co];
            size_t base = ((size_t)b * C_ + co) * HW_ + i * 64;
            if (MODE == 0) {
                float sc = ss[co], sh = ss[256 + co];
                #pragma unroll
                for (int nt = 0; nt < 4; ++nt) {
                    int col = nt * 16 + l15;
                    float o = acc[mt][nt][r] + bco;
                    float u = silu_f(b2f(auxh[base + col]) * sc + sh);
                    out_bf[base + col] = f2bf(o * u);
                }
            } else {
                #pragma unroll
                for (int nt = 0; nt < 4; ++nt) {
                    int col = nt * 16 + l15;
                    out_f[base + col] = acc[mt][nt][r] + bco + auxf[base + col];
                }
            }
        }
    }
}

// ---------------- launch ----------------------------------------------------
extern "C" void kernel_launch(void* const* d_in, const int* in_sizes, int n_in,
                              void* d_out, int out_size, void* d_ws, size_t ws_size,
                              hipStream_t stream) {
    const float* x     = (const float*)d_in[0];
    const float* p_w   = (const float*)d_in[1];
    const float* p_b   = (const float*)d_in[2];
    const float* ak_w  = (const float*)d_in[3];
    const float* ak_g  = (const float*)d_in[4];
    const float* ak_b  = (const float*)d_in[5];
    const float* l0_w  = (const float*)d_in[6];
    const float* l0_b  = (const float*)d_in[7];
    const float* ls_w  = (const float*)d_in[8];
    const float* ls_b  = (const float*)d_in[9];
    const float* l1_w  = (const float*)d_in[10];
    const float* l1_b  = (const float*)d_in[11];
    const float* cv_w  = (const float*)d_in[12];
    const float* cv_b  = (const float*)d_in[13];
    float* out = (float*)d_out;

    char* w = (char*)d_ws;
    int2*   tbl_off = (int2*)w;                              // 786 KB
    float4* tbl_w   = (float4*)(w + 786432);                 // 1.5 MB
    unsigned short* wak = (unsigned short*)(w + 2359296);    // 384 KB
    unsigned short* wl1 = (unsigned short*)(w + 2752512);    // 128 KB
    unsigned short* wcv = (unsigned short*)(w + 2883584);    // 128 KB
    float* p1 = (float*)(w + 3014656);                       // 512 KB
    float* p2 = (float*)(w + 3538944);                       // 512 KB
    float* ss = (float*)(w + 4063232);                       // 2 KB
    float* pwt = (float*)(w + 4065280);                      // 72 KB
    // time-multiplexed regions:
    float* xt   = (float*)(w + 4194304);                     // 32 MB (dead after gather)
    unsigned short* ybh    = (unsigned short*)(w + 4194304); // 16 MB (ak writes, after gather)
    unsigned short* dw5out = (unsigned short*)(w + 20971520);// 16 MB
    float* part = (float*)(w + 37748736);                    // 6.3 MB (dead after s2)
    unsigned short* attn   = (unsigned short*)(w + 37748736);// 16 MB (dw7 out)
    unsigned short* v      = (unsigned short*)(w + 44040192);// 48 MB (dead after ak)
    unsigned short* g0out  = (unsigned short*)(w + 54525952);// 16 MB (after gemm0)

    prep_kernel<<<1352, 256, 0, stream>>>(ak_w, l1_w, cv_w, p_w, wak, wl1, wcv, pwt);
    offset_s1_kernel<<<4096, 256, 0, stream>>>(x, pwt, part);
    offset_s2_kernel<<<128, 256, 0, stream>>>(part, p_b, tbl_off, tbl_w);
    transpose_kernel<<<1024, 256, 0, stream>>>(x, xt);
    gather_kernel<<<1536, 256, 0, stream>>>(xt, tbl_off, tbl_w, v);
    ak_mfma_kernel<<<1024, 256, 0, stream>>>(v, wak, ybh, p1, p2);
    bn_stats_kernel<<<256, 256, 0, stream>>>(p1, p2, ak_g, ak_b, ss);
    dw5_fused_kernel<<<2048, 256, 0, stream>>>(ybh, ss, l0_w, l0_b, dw5out);
    dw7d3_kernel<<<2048, 256, 0, stream>>>(dw5out, ls_w, ls_b, attn);
    gemm1x1_mfma<0><<<1024, 256, 0, stream>>>(attn, wl1, l1_b, ybh, nullptr, ss, g0out, nullptr);
    gemm1x1_mfma<1><<<1024, 256, 0, stream>>>(g0out, wcv, cv_b, nullptr, x, nullptr, nullptr, out);
}

// Round 4
// 305.116 us; speedup vs baseline: 1.1213x; 1.0508x over previous
//
#include <hip/hip_runtime.h>
#include <math.h>
#include <stdint.h>

#define B_ 8
#define C_ 256
#define HW_ 4096
#define NPIX 32768
#define NELEM (B_*C_*HW_)   // 8388608

typedef __attribute__((ext_vector_type(8))) short short8;
typedef __attribute__((ext_vector_type(4))) float f32x4;

__device__ __forceinline__ unsigned short f2bf(float f) {
    union { float f; uint32_t u; } v; v.f = f;
    uint32_t r = v.u + 0x7FFFu + ((v.u >> 16) & 1u);
    return (unsigned short)(r >> 16);
}
__device__ __forceinline__ float b2f(unsigned short h) {
    union { uint32_t u; float f; } v; v.u = ((uint32_t)h) << 16; return v.f;
}
__device__ __forceinline__ float silu_f(float v) { return v / (1.f + __expf(-v)); }

// async global->LDS, 16B per lane; LDS dest = wave-uniform base + lane*16.
// Src MUST be lane-contiguous for TA-friendly request counts (the point of
// this round's layout changes).
__device__ __forceinline__ void gl2lds16(const void* g, void* l) {
    __builtin_amdgcn_global_load_lds(
        (const __attribute__((address_space(1))) void*)g,
        (__attribute__((address_space(3))) void*)l,
        16, 0, 0);
}

// ---------------- K0: weight conversion (K-TILED layouts) + p_w transpose ---
// Tiled weight layout: Wt[((q)*256 + co)*8 + e] = W[co][k''] with k'' = q*8+e.
// A K-step (32 k) = 4 consecutive q blocks = one contiguous 16 KB chunk.
__global__ __launch_bounds__(256) void prep_kernel(
    const float* __restrict__ akw, const float* __restrict__ l1w,
    const float* __restrict__ cvw, const float* __restrict__ pw,
    unsigned short* __restrict__ wak, unsigned short* __restrict__ wl1,
    unsigned short* __restrict__ wcv, float* __restrict__ pwt)
{
    int gid = blockIdx.x * 256 + threadIdx.x;      // grid=1352
    if (gid < 196608) {
        int e = gid & 7;
        int co = (gid >> 3) & 255;
        int q = gid >> 11;            // 0..95
        int kpp = q * 8 + e;          // k'' = n*256+ci
        int n = kpp >> 8, ci = kpp & 255;
        wak[gid] = f2bf(akw[co * 768 + ci * 3 + n]);
    }
    else if (gid < 262144) {
        int g = gid - 196608;
        int e = g & 7, co = (g >> 3) & 255, q = g >> 11;   // q 0..31
        wl1[g] = f2bf(l1w[co * 256 + q * 8 + e]);
    }
    else if (gid < 327680) {
        int g = gid - 262144;
        int e = g & 7, co = (g >> 3) & 255, q = g >> 11;
        wcv[g] = f2bf(cvw[co * 256 + q * 8 + e]);
    }
    else if (gid < 346112) {
        int idx = gid - 327680;
        int ci = idx / 72, r = idx - ci * 72;
        int tt = r / 12, t9 = r - tt * 12;
        pwt[idx] = (t9 < 9) ? pw[tt * 2304 + ci * 9 + t9] : 0.f;
    }
}

// ---------------- K0b: x CHW -> HWC transpose (XCD-swizzled) ----------------
__global__ __launch_bounds__(256) void transpose_kernel(
    const float* __restrict__ x, float* __restrict__ xt)
{
    int blk = blockIdx.x;            // 1024
    int b = blk & 7;
    int rest = blk >> 3;             // 0..127
    int half = rest & 1, i = rest >> 1;
    int bi = b * 64 + i;
    int tid = threadIdx.x;
    __shared__ float tile[64 * 132];

    {
        int ci_l = tid >> 6, jj = tid & 63;
        const float* ip = x + ((size_t)b * C_ + half * 128 + ci_l) * HW_ + i * 64 + jj;
        #pragma unroll 4
        for (int it = 0; it < 32; ++it)
            tile[jj * 132 + ci_l + it * 4] = ip[(size_t)it * 4 * HW_];
    }
    __syncthreads();
    {
        int j = tid >> 2, q = tid & 3;
        float* op = xt + ((size_t)(bi * 64 + j)) * 256 + half * 128 + q * 32;
        #pragma unroll
        for (int f = 0; f < 8; ++f)
            *(float4*)(op + f * 4) = *(const float4*)&tile[j * 132 + q * 32 + f * 4];
    }
}

// ---------------- K1a: offset conv stage 1 (v5: register acc, small tree) ---
__global__ __launch_bounds__(256) void offset_s1_kernel(
    const float* __restrict__ x, const float* __restrict__ pwt,
    float* __restrict__ part)          // [bi*8+g][6][64]
{
    int blk = blockIdx.x;              // 4096
    int b = blk & 7;
    int rest = blk >> 3;               // 0..511
    int g = rest & 7, i = rest >> 3;
    int bi = b * 64 + i;
    int tid = threadIdx.x;

    __shared__ float tile[6600];       // x tile [(row*66+col)*33+ci]; aliased as s2[16][387]

    // ---- stage x tile (transposed, halo-padded) ----
    {
        int cs = tid >> 3, r8 = tid & 7;
        const float* xp = x + ((size_t)b * C_ + g * 32 + cs) * HW_;
        #pragma unroll
        for (int t = 0; t < 6; ++t) {
            int idx = r8 * 6 + t;
            int r = idx >> 4, v4 = idx & 15;
            int ii = i + r - 1;
            float4 val = make_float4(0.f, 0.f, 0.f, 0.f);
            if (ii >= 0 && ii < 64)
                val = *(const float4*)(xp + ii * 64 + v4 * 4);
            int base = (r * 66 + 1 + v4 * 4) * 33 + cs;
            tile[base]      = val.x;  tile[base + 33]  = val.y;
            tile[base + 66] = val.z;  tile[base + 99]  = val.w;
        }
        if (tid < 192) {
            int ci = tid / 6, rem = tid - ci * 6;
            int ki = rem >> 1, side = rem & 1;
            tile[(ki * 66 + side * 65) * 33 + ci] = 0.f;
        }
    }
    __syncthreads();

    int sub = tid >> 4;                // 0..15
    int jq  = tid & 15;                // 0..15: pixels jq*4 .. jq*4+3

    float acc[6][4];
    #pragma unroll
    for (int tt = 0; tt < 6; ++tt)
        #pragma unroll
        for (int p = 0; p < 4; ++p) acc[tt][p] = 0.f;

    #pragma unroll
    for (int t = 0; t < 2; ++t) {
        int ci = sub + 16 * t;
        float xv[3][6];                // tile cols jq*4 .. jq*4+5
        #pragma unroll
        for (int ki = 0; ki < 3; ++ki)
            #pragma unroll
            for (int cc = 0; cc < 6; ++cc)
                xv[ki][cc] = tile[(ki * 66 + jq * 4 + cc) * 33 + ci];
        const float* wp = pwt + (g * 32 + ci) * 72;
        #pragma unroll
        for (int tt = 0; tt < 6; ++tt) {
            float w[9];
            *(float4*)&w[0] = *(const float4*)(wp + tt * 12);
            *(float4*)&w[4] = *(const float4*)(wp + tt * 12 + 4);
            w[8] = wp[tt * 12 + 8];
            #pragma unroll
            for (int ki = 0; ki < 3; ++ki)
                #pragma unroll
                for (int kj = 0; kj < 3; ++kj) {
                    float wgt = w[ki * 3 + kj];
                    #pragma unroll
                    for (int p = 0; p < 4; ++p)
                        acc[tt][p] += wgt * xv[ki][kj + p];
                }
        }
    }

    // ---- 16-sub reduction via LDS tree (alias tile as s2, stride 387) ----
    __syncthreads();
    {
        float* s2 = tile + sub * 387;
        #pragma unroll
        for (int tt = 0; tt < 6; ++tt)
            #pragma unroll
            for (int p = 0; p < 4; ++p)
                s2[tt * 64 + jq * 4 + p] = acc[tt][p];
    }
    __syncthreads();
    size_t pslot = (size_t)bi * 8 + g;
    for (int idx = tid; idx < 384; idx += 256) {
        float s = 0.f;
        #pragma unroll
        for (int sb = 0; sb < 16; ++sb)
            s += tile[sb * 387 + idx];
        part[pslot * 384 + idx] = s;
    }
}

// ---------------- K1b: offset stage 2 -> paired gather tables ---------------
__global__ __launch_bounds__(256) void offset_s2_kernel(
    const float* __restrict__ part, const float* __restrict__ pb,
    int2* __restrict__ tbl_off, float4* __restrict__ tbl_w)
{
    int pix = blockIdx.x * 256 + threadIdx.x;   // grid=128
    int b = pix >> 12, rem = pix & 4095, i = rem >> 6, j = rem & 63;
    int bi = b * 64 + i;
    float v[6];
    #pragma unroll
    for (int tt = 0; tt < 6; ++tt) v[tt] = pb[tt];
    for (int g = 0; g < 8; ++g) {
        const float* pp = part + ((size_t)bi * 8 + g) * 384;
        #pragma unroll
        for (int tt = 0; tt < 6; ++tt) v[tt] += pp[tt * 64 + j];
    }
    const float pnx[3] = {0.f, 0.f, 1.f};
    const float pny[3] = {0.f, 1.f, 0.f};
    #pragma unroll
    for (int n = 0; n < 3; ++n) {
        float px_ = (float)i + pnx[n] + v[n];
        float py_ = (float)j + pny[n] + v[n + 3];
        float qx = floorf(px_), qy = floorf(py_);
        float qlx = fminf(fmaxf(qx,       0.f), 63.f);
        float qly = fminf(fmaxf(qy,       0.f), 63.f);
        float qrx = fminf(fmaxf(qx + 1.f, 0.f), 63.f);
        float qry = fminf(fmaxf(qy + 1.f, 0.f), 63.f);
        float pxc = fminf(fmaxf(px_,      0.f), 63.f);
        float pyc = fminf(fmaxf(py_,      0.f), 63.f);
        float glt = (1.f + (qlx - pxc)) * (1.f + (qly - pyc));
        float grb = (1.f - (qrx - pxc)) * (1.f - (qry - pyc));
        float glb = (1.f + (qlx - pxc)) * (1.f - (qry - pyc));
        float grt = (1.f - (qrx - pxc)) * (1.f + (qly - pyc));
        int ilx = (int)qlx, irx = (int)qrx;
        int ily = (int)qly, iry = (int)qry;
        int c0; float a0, a1, b0, b1;
        if (ily == iry) {
            if (ily == 0) { c0 = 0;  a0 = glt + glb; a1 = 0.f; b0 = grt + grb; b1 = 0.f; }
            else          { c0 = 62; a0 = 0.f; a1 = glt + glb; b0 = 0.f; b1 = grt + grb; }
        } else { c0 = ily; a0 = glt; a1 = glb; b0 = grt; b1 = grb; }
        int oi = (b * 3 + n) * HW_ + i * 64 + j;
        tbl_off[oi] = make_int2(ilx * 64 + c0, irx * 64 + c0);
        tbl_w[oi]   = make_float4(a0, a1, b0, b1);
    }
}

// ---------------- K2a: gather — writes v in K-TILED layout ------------------
// v2[((P*24 + t)*2048) + (kq*64 + pixl)*8 + e]  (shorts), P=pix-block, t=k-chunk.
// Each ak K-step then reads one contiguous 4 KB block.
__global__ __launch_bounds__(256) void gather_kernel(
    const float* __restrict__ xt, const int2* __restrict__ tbl_off,
    const float4* __restrict__ tbl_w, unsigned short* __restrict__ v)
{
    int blk = blockIdx.x;          // 1536
    int b = blk & 7;
    int rest = blk >> 3;           // 0..191
    int n = rest >> 6, i = rest & 63;
    int bi = b * 64 + i;           // = pixel-block P
    int tid = threadIdx.x;
    int lane = tid & 63, wv = tid >> 6;
    int ci4 = lane * 4;
    const float* xb = xt + (size_t)b * 1048576;

    int tC = (n << 3) + (ci4 >> 5);        // k-chunk (32k) index
    int kq = (ci4 >> 3) & 3;
    int e  = ci4 & 7;
    unsigned short* vb = v + ((size_t)bi * 24 + tC) * 2048 + kq * 512 + e;

    for (int it0 = 0; it0 < 16; it0 += 4) {
        float4 A[4], Bv[4], Cv[4], Dv[4], w4[4];
        #pragma unroll
        for (int u = 0; u < 4; ++u) {
            int j = wv * 16 + it0 + u;
            int oi = (b * 3 + n) * HW_ + i * 64 + j;
            int2 off = tbl_off[oi];
            w4[u] = tbl_w[oi];
            const float* p0 = xb + (size_t)off.x * 256 + ci4;
            const float* p1 = xb + (size_t)off.y * 256 + ci4;
            A[u]  = *(const float4*)p0;
            Bv[u] = *(const float4*)(p0 + 256);
            Cv[u] = *(const float4*)p1;
            Dv[u] = *(const float4*)(p1 + 256);
        }
        #pragma unroll
        for (int u = 0; u < 4; ++u) {
            int j = wv * 16 + it0 + u;
            union { unsigned short h[4]; uint2 q; } pk;
            pk.h[0] = f2bf(w4[u].x*A[u].x + w4[u].y*Bv[u].x + w4[u].z*Cv[u].x + w4[u].w*Dv[u].x);
            pk.h[1] = f2bf(w4[u].x*A[u].y + w4[u].y*Bv[u].y + w4[u].z*Cv[u].y + w4[u].w*Dv[u].y);
            pk.h[2] = f2bf(w4[u].x*A[u].z + w4[u].y*Bv[u].z + w4[u].z*Cv[u].z + w4[u].w*Dv[u].z);
            pk.h[3] = f2bf(w4[u].x*A[u].w + w4[u].y*Bv[u].w + w4[u].z*Cv[u].w + w4[u].w*Dv[u].w);
            *(uint2*)&vb[j * 8] = pk.q;
        }
    }
}

// ---------------- K2b: AK GEMM (bf16 MFMA, round-0 structure) ---------------
// Single-buffer 2-barrier loop; ALL staging via global_load_lds(16B) from
// K-tiled (lane-contiguous) W and v. Per-instruction TA requests: 16 vs 64.
__global__ __launch_bounds__(256) void ak_mfma_kernel(
    const unsigned short* __restrict__ v, const unsigned short* __restrict__ W,
    unsigned short* __restrict__ yh, float* __restrict__ p1, float* __restrict__ p2)
{
    int blk = blockIdx.x;              // 512
    int b = blk & 7, i = blk >> 3;
    int P = b * 64 + i;                // pixel-block id in v layout
    int tid = threadIdx.x;
    int wv = tid >> 6, lane = tid & 63;
    int quad = lane >> 4, l15 = lane & 15;
    __shared__ __align__(16) unsigned short sA[8192];
    __shared__ __align__(16) unsigned short sB[2048];

    const unsigned short* vP = v + (size_t)P * 24 * 2048;

    f32x4 acc[4][4];
    #pragma unroll
    for (int mt = 0; mt < 4; ++mt)
        #pragma unroll
        for (int nt = 0; nt < 4; ++nt) acc[mt][nt] = (f32x4){0.f, 0.f, 0.f, 0.f};

    for (int t = 0; t < 24; ++t) {
        #pragma unroll
        for (int s = 0; s < 4; ++s)
            gl2lds16(W + ((size_t)(t * 4 + s) * 256 + tid) * 8, &sA[(s * 256 + tid) * 8]);
        gl2lds16(vP + (size_t)t * 2048 + tid * 8, &sB[tid * 8]);
        __syncthreads();
        short8 af[4], bf[4];
        #pragma unroll
        for (int mt = 0; mt < 4; ++mt)
            af[mt] = *(const short8*)&sA[(quad * 256 + wv * 64 + mt * 16 + l15) * 8];
        #pragma unroll
        for (int nt = 0; nt < 4; ++nt)
            bf[nt] = *(const short8*)&sB[(quad * 64 + nt * 16 + l15) * 8];
        #pragma unroll
        for (int mt = 0; mt < 4; ++mt)
            #pragma unroll
            for (int nt = 0; nt < 4; ++nt)
                acc[mt][nt] = __builtin_amdgcn_mfma_f32_16x16x32_bf16(
                    af[mt], bf[nt], acc[mt][nt], 0, 0, 0);
        __syncthreads();
    }
    #pragma unroll
    for (int mt = 0; mt < 4; ++mt) {
        #pragma unroll
        for (int r = 0; r < 4; ++r) {
            int co = wv * 64 + mt * 16 + quad * 4 + r;
            size_t base = ((size_t)b * C_ + co) * HW_ + i * 64;
            float s1 = 0.f, s2 = 0.f;
            #pragma unroll
            for (int nt = 0; nt < 4; ++nt) {
                float val = acc[mt][nt][r];
                s1 += val; s2 += val * val;
                yh[base + nt * 16 + l15] = f2bf(val);
            }
            #pragma unroll
            for (int m = 1; m < 16; m <<= 1) {
                s1 += __shfl_xor(s1, m); s2 += __shfl_xor(s2, m);
            }
            if (l15 == 0) { p1[co * 512 + blk] = s1; p2[co * 512 + blk] = s2; }
        }
    }
}

// ---------------- K3: BN stats from partials --------------------------------
__global__ __launch_bounds__(256) void bn_stats_kernel(
    const float* __restrict__ p1, const float* __restrict__ p2,
    const float* __restrict__ gamma, const float* __restrict__ beta,
    float* __restrict__ ss)
{
    int co = blockIdx.x, tid = threadIdx.x;     // grid=256
    float a = p1[co * 512 + tid] + p1[co * 512 + 256 + tid];
    float q = p2[co * 512 + tid] + p2[co * 512 + 256 + tid];
    __shared__ float r1[256], r2[256];
    r1[tid] = a; r2[tid] = q; __syncthreads();
    for (int st = 128; st > 0; st >>= 1) {
        if (tid < st) { r1[tid] += r1[tid + st]; r2[tid] += r2[tid + st]; }
        __syncthreads();
    }
    if (tid == 0) {
        const float inv_n = 1.f / (float)NPIX;
        float m = r1[0] * inv_n;
        float var = r2[0] * inv_n - m * m;
        float sc = gamma[co] * rsqrtf(var + 1e-5f);
        ss[co] = sc; ss[256 + co] = beta[co] - m * sc;
    }
}

// ---------------- K4: fused BN+SiLU + 5x5 depthwise (XCD-swizzled) ----------
__global__ __launch_bounds__(256) void dw5_fused_kernel(
    const unsigned short* __restrict__ in, const float* __restrict__ ss,
    const float* __restrict__ w, const float* __restrict__ bias,
    unsigned short* __restrict__ out)
{
    int blkI = blockIdx.x;         // 2048
    int b = blkI & 7, c = blkI >> 3;
    int bc = b * 256 + c;
    int tid = threadIdx.x;
    __shared__ float tile[68 * 68];
    float sc = ss[c], sh = ss[256 + c];
    const unsigned short* ip = in + (size_t)bc * HW_;
    for (int s = tid; s < 68 * 68; s += 256) {
        int r = s / 68, cc = s - r * 68;
        int ii = r - 2, jj = cc - 2;
        float vv = 0.f;
        if (ii >= 0 && ii < 64 && jj >= 0 && jj < 64) {
            float t = b2f(ip[ii * 64 + jj]) * sc + sh;
            vv = silu_f(t);
        }
        tile[s] = vv;
    }
    float wr[25];
    #pragma unroll
    for (int t = 0; t < 25; ++t) wr[t] = w[c * 25 + t];
    float bv = bias[c];
    __syncthreads();
    int j0 = (tid & 15) * 4, ig = tid >> 4;
    unsigned short* op = out + (size_t)bc * HW_;
    for (int r = 0; r < 4; ++r) {
        int i = r * 16 + ig;
        float o0 = bv, o1 = bv, o2 = bv, o3 = bv;
        #pragma unroll
        for (int di = 0; di < 5; ++di) {
            const float* tp = &tile[(i + di) * 68 + j0];
            float4 a = *(const float4*)tp;
            float4 bq = *(const float4*)(tp + 4);
            float vv[8] = {a.x, a.y, a.z, a.w, bq.x, bq.y, bq.z, bq.w};
            #pragma unroll
            for (int dj = 0; dj < 5; ++dj) {
                float wv = wr[di * 5 + dj];
                o0 += wv * vv[dj];     o1 += wv * vv[dj + 1];
                o2 += wv * vv[dj + 2]; o3 += wv * vv[dj + 3];
            }
        }
        union { unsigned short h[4]; uint2 u; } pk;
        pk.h[0] = f2bf(o0); pk.h[1] = f2bf(o1);
        pk.h[2] = f2bf(o2); pk.h[3] = f2bf(o3);
        *(uint2*)&op[i * 64 + j0] = pk.u;
    }
}

// ---------------- K5: 7x7 dilated(3) depthwise (XCD-swizzled) ---------------
__global__ __launch_bounds__(256) void dw7d3_kernel(
    const unsigned short* __restrict__ in, const float* __restrict__ w,
    const float* __restrict__ bias, unsigned short* __restrict__ out)
{
    int blkI = blockIdx.x;         // 2048
    int b = blkI & 7, c = blkI >> 3;
    int bc = b * 256 + c;
    int tid = threadIdx.x;
    __shared__ float tile[82 * 84];
    const unsigned short* ip = in + (size_t)bc * HW_;
    for (int s = tid; s < 82 * 84; s += 256) {
        int r = s / 84, cc = s - r * 84;
        int ii = r - 9, jj = cc - 9;
        float vv = 0.f;
        if (ii >= 0 && ii < 64 && jj >= 0 && jj < 64) vv = b2f(ip[ii * 64 + jj]);
        tile[s] = vv;
    }
    float wr[49];
    #pragma unroll
    for (int t = 0; t < 49; ++t) wr[t] = w[c * 49 + t];
    float bv = bias[c];
    __syncthreads();
    int j0 = (tid & 15) * 4, ig = tid >> 4;
    unsigned short* op = out + (size_t)bc * HW_;
    for (int r = 0; r < 4; ++r) {
        int i = r * 16 + ig;
        float o0 = bv, o1 = bv, o2 = bv, o3 = bv;
        #pragma unroll
        for (int di = 0; di < 7; ++di) {
            const float* tp = &tile[(i + 3 * di) * 84 + j0];
            float vv[24];
            #pragma unroll
            for (int q = 0; q < 6; ++q)
                *(float4*)&vv[q * 4] = *(const float4*)(tp + q * 4);
            #pragma unroll
            for (int dj = 0; dj < 7; ++dj) {
                float wv = wr[di * 7 + dj];
                o0 += wv * vv[3 * dj];     o1 += wv * vv[3 * dj + 1];
                o2 += wv * vv[3 * dj + 2]; o3 += wv * vv[3 * dj + 3];
            }
        }
        union { unsigned short h[4]; uint2 u; } pk;
        pk.h[0] = f2bf(o0); pk.h[1] = f2bf(o1);
        pk.h[2] = f2bf(o2); pk.h[3] = f2bf(o3);
        *(uint2*)&op[i * 64 + j0] = pk.u;
    }
}

// ---------------- K6/K7: 1x1 conv bf16 MFMA GEMM (round-0 structure) --------
// A via global_load_lds from K-tiled W (lane-contiguous); B (CHW, already
// 128B-contiguous per instruction) via register staging.
template<int MODE>
__global__ __launch_bounds__(256) void gemm1x1_mfma(
    const unsigned short* __restrict__ in, const unsigned short* __restrict__ W,
    const float* __restrict__ bias,
    const unsigned short* __restrict__ auxh, const float* __restrict__ auxf,
    const float* __restrict__ ss,
    unsigned short* __restrict__ out_bf, float* __restrict__ out_f)
{
    int blk = blockIdx.x;              // 512
    int b = blk & 7, i = blk >> 3;
    int tid = threadIdx.x;
    int wv = tid >> 6, lane = tid & 63;
    int quad = lane >> 4, l15 = lane & 15;
    __shared__ __align__(16) unsigned short sA[8192];
    __shared__ __align__(16) unsigned short sB[2048];
    int pixS = tid & 63, kqS = tid >> 6;

    const unsigned short* bp = in + ((size_t)b * C_) * HW_ + i * 64 + pixS;

    f32x4 acc[4][4];
    #pragma unroll
    for (int mt = 0; mt < 4; ++mt)
        #pragma unroll
        for (int nt = 0; nt < 4; ++nt) acc[mt][nt] = (f32x4){0.f, 0.f, 0.f, 0.f};

    for (int t = 0; t < 8; ++t) {
        #pragma unroll
        for (int s = 0; s < 4; ++s)
            gl2lds16(W + ((size_t)(t * 4 + s) * 256 + tid) * 8, &sA[(s * 256 + tid) * 8]);
        {
            const unsigned short* p = bp + (size_t)(t * 32 + kqS * 8) * HW_;
            union { unsigned short h[8]; uint4 u; } hb;
            #pragma unroll
            for (int jj = 0; jj < 8; ++jj) hb.h[jj] = p[(size_t)jj * HW_];
            *(uint4*)&sB[(kqS * 64 + pixS) * 8] = hb.u;
        }
        __syncthreads();
        short8 af[4], bf[4];
        #pragma unroll
        for (int mt = 0; mt < 4; ++mt)
            af[mt] = *(const short8*)&sA[(quad * 256 + wv * 64 + mt * 16 + l15) * 8];
        #pragma unroll
        for (int nt = 0; nt < 4; ++nt)
            bf[nt] = *(const short8*)&sB[(quad * 64 + nt * 16 + l15) * 8];
        #pragma unroll
        for (int mt = 0; mt < 4; ++mt)
            #pragma unroll
            for (int nt = 0; nt < 4; ++nt)
                acc[mt][nt] = __builtin_amdgcn_mfma_f32_16x16x32_bf16(
                    af[mt], bf[nt], acc[mt][nt], 0, 0, 0);
        __syncthreads();
    }
    #pragma unroll
    for (int mt = 0; mt < 4; ++mt) {
        #pragma unroll
        for (int r = 0; r < 4; ++r) {
            int co = wv * 64 + mt * 16 + quad * 4 + r;
            float bco = bias[co];
            size_t base = ((size_t)b * C_ + co) * HW_ + i * 64;
            if (MODE == 0) {
                float sc = ss[co], sh = ss[256 + co];
                #pragma unroll
                for (int nt = 0; nt < 4; ++nt) {
                    int col = nt * 16 + l15;
                    float o = acc[mt][nt][r] + bco;
                    float u = silu_f(b2f(auxh[base + col]) * sc + sh);
                    out_bf[base + col] = f2bf(o * u);
                }
            } else {
                #pragma unroll
                for (int nt = 0; nt < 4; ++nt) {
                    int col = nt * 16 + l15;
                    out_f[base + col] = acc[mt][nt][r] + bco + auxf[base + col];
                }
            }
        }
    }
}

// ---------------- launch ----------------------------------------------------
extern "C" void kernel_launch(void* const* d_in, const int* in_sizes, int n_in,
                              void* d_out, int out_size, void* d_ws, size_t ws_size,
                              hipStream_t stream) {
    const float* x     = (const float*)d_in[0];
    const float* p_w   = (const float*)d_in[1];
    const float* p_b   = (const float*)d_in[2];
    const float* ak_w  = (const float*)d_in[3];
    const float* ak_g  = (const float*)d_in[4];
    const float* ak_b  = (const float*)d_in[5];
    const float* l0_w  = (const float*)d_in[6];
    const float* l0_b  = (const float*)d_in[7];
    const float* ls_w  = (const float*)d_in[8];
    const float* ls_b  = (const float*)d_in[9];
    const float* l1_w  = (const float*)d_in[10];
    const float* l1_b  = (const float*)d_in[11];
    const float* cv_w  = (const float*)d_in[12];
    const float* cv_b  = (const float*)d_in[13];
    float* out = (float*)d_out;

    char* w = (char*)d_ws;
    int2*   tbl_off = (int2*)w;                              // 786 KB
    float4* tbl_w   = (float4*)(w + 786432);                 // 1.5 MB
    unsigned short* wak = (unsigned short*)(w + 2359296);    // 384 KB
    unsigned short* wl1 = (unsigned short*)(w + 2752512);    // 128 KB
    unsigned short* wcv = (unsigned short*)(w + 2883584);    // 128 KB
    float* p1 = (float*)(w + 3014656);                       // 512 KB
    float* p2 = (float*)(w + 3538944);                       // 512 KB
    float* ss = (float*)(w + 4063232);                       // 2 KB
    float* pwt = (float*)(w + 4065280);                      // 72 KB
    // time-multiplexed regions:
    float* xt   = (float*)(w + 4194304);                     // 32 MB (dead after gather)
    unsigned short* ybh    = (unsigned short*)(w + 4194304); // 16 MB (ak writes, after gather)
    unsigned short* dw5out = (unsigned short*)(w + 20971520);// 16 MB
    float* part = (float*)(w + 37748736);                    // 6.3 MB (dead after s2)
    unsigned short* attn   = (unsigned short*)(w + 37748736);// 16 MB (dw7 out)
    unsigned short* v      = (unsigned short*)(w + 44040192);// 48 MB (dead after ak)
    unsigned short* g0out  = (unsigned short*)(w + 54525952);// 16 MB (after gemm0)

    prep_kernel<<<1352, 256, 0, stream>>>(ak_w, l1_w, cv_w, p_w, wak, wl1, wcv, pwt);
    offset_s1_kernel<<<4096, 256, 0, stream>>>(x, pwt, part);
    offset_s2_kernel<<<128, 256, 0, stream>>>(part, p_b, tbl_off, tbl_w);
    transpose_kernel<<<1024, 256, 0, stream>>>(x, xt);
    gather_kernel<<<1536, 256, 0, stream>>>(xt, tbl_off, tbl_w, v);
    ak_mfma_kernel<<<512, 256, 0, stream>>>(v, wak, ybh, p1, p2);
    bn_stats_kernel<<<256, 256, 0, stream>>>(p1, p2, ak_g, ak_b, ss);
    dw5_fused_kernel<<<2048, 256, 0, stream>>>(ybh, ss, l0_w, l0_b, dw5out);
    dw7d3_kernel<<<2048, 256, 0, stream>>>(dw5out, ls_w, ls_b, attn);
    gemm1x1_mfma<0><<<512, 256, 0, stream>>>(attn, wl1, l1_b, ybh, nullptr, ss, g0out, nullptr);
    gemm1x1_mfma<1><<<512, 256, 0, stream>>>(g0out, wcv, cv_b, nullptr, x, nullptr, nullptr, out);
}

// Round 5
// 297.645 us; speedup vs baseline: 1.1495x; 1.0251x over previous
//
#include <hip/hip_runtime.h>
#include <math.h>
#include <stdint.h>

#define B_ 8
#define C_ 256
#define HW_ 4096
#define NPIX 32768
#define NELEM (B_*C_*HW_)   // 8388608

typedef __attribute__((ext_vector_type(8))) short short8;
typedef __attribute__((ext_vector_type(4))) float f32x4;

__device__ __forceinline__ unsigned short f2bf(float f) {
    union { float f; uint32_t u; } v; v.f = f;
    uint32_t r = v.u + 0x7FFFu + ((v.u >> 16) & 1u);
    return (unsigned short)(r >> 16);
}
__device__ __forceinline__ float b2f(unsigned short h) {
    union { uint32_t u; float f; } v; v.u = ((uint32_t)h) << 16; return v.f;
}
__device__ __forceinline__ float silu_f(float v) { return v / (1.f + __expf(-v)); }

// async global->LDS, 16B per lane; LDS dest = wave-uniform base + lane*16.
// Src MUST be lane-contiguous (round-4 lesson: TA request count).
__device__ __forceinline__ void gl2lds16(const void* g, void* l) {
    __builtin_amdgcn_global_load_lds(
        (const __attribute__((address_space(1))) void*)g,
        (__attribute__((address_space(3))) void*)l,
        16, 0, 0);
}

// ---------------- K0: weight conversion (K-TILED layouts) + p_w transpose ---
// Tiled weight layout: Wt[((q)*256 + co)*8 + e] = W[co][k''] with k'' = q*8+e.
// A K-step (32 k) = 4 consecutive q blocks = one contiguous 16 KB chunk.
__global__ __launch_bounds__(256) void prep_kernel(
    const float* __restrict__ akw, const float* __restrict__ l1w,
    const float* __restrict__ cvw, const float* __restrict__ pw,
    unsigned short* __restrict__ wak, unsigned short* __restrict__ wl1,
    unsigned short* __restrict__ wcv, float* __restrict__ pwt)
{
    int gid = blockIdx.x * 256 + threadIdx.x;      // grid=1352
    if (gid < 196608) {
        int e = gid & 7;
        int co = (gid >> 3) & 255;
        int q = gid >> 11;            // 0..95
        int kpp = q * 8 + e;          // k'' = n*256+ci
        int n = kpp >> 8, ci = kpp & 255;
        wak[gid] = f2bf(akw[co * 768 + ci * 3 + n]);
    }
    else if (gid < 262144) {
        int g = gid - 196608;
        int e = g & 7, co = (g >> 3) & 255, q = g >> 11;   // q 0..31
        wl1[g] = f2bf(l1w[co * 256 + q * 8 + e]);
    }
    else if (gid < 327680) {
        int g = gid - 262144;
        int e = g & 7, co = (g >> 3) & 255, q = g >> 11;
        wcv[g] = f2bf(cvw[co * 256 + q * 8 + e]);
    }
    else if (gid < 346112) {
        int idx = gid - 327680;
        int ci = idx / 72, r = idx - ci * 72;
        int tt = r / 12, t9 = r - tt * 12;
        pwt[idx] = (t9 < 9) ? pw[tt * 2304 + ci * 9 + t9] : 0.f;
    }
}

// ---------------- K0b: x CHW -> HWC transpose (XCD-swizzled) ----------------
__global__ __launch_bounds__(256) void transpose_kernel(
    const float* __restrict__ x, float* __restrict__ xt)
{
    int blk = blockIdx.x;            // 1024
    int b = blk & 7;
    int rest = blk >> 3;             // 0..127
    int half = rest & 1, i = rest >> 1;
    int bi = b * 64 + i;
    int tid = threadIdx.x;
    __shared__ float tile[64 * 132];

    {
        int ci_l = tid >> 6, jj = tid & 63;
        const float* ip = x + ((size_t)b * C_ + half * 128 + ci_l) * HW_ + i * 64 + jj;
        #pragma unroll 4
        for (int it = 0; it < 32; ++it)
            tile[jj * 132 + ci_l + it * 4] = ip[(size_t)it * 4 * HW_];
    }
    __syncthreads();
    {
        int j = tid >> 2, q = tid & 3;
        float* op = xt + ((size_t)(bi * 64 + j)) * 256 + half * 128 + q * 32;
        #pragma unroll
        for (int f = 0; f < 8; ++f)
            *(float4*)(op + f * 4) = *(const float4*)&tile[j * 132 + q * 32 + f * 4];
    }
}

// ---------------- K1a: offset conv stage 1 (v5: register acc, small tree) ---
__global__ __launch_bounds__(256) void offset_s1_kernel(
    const float* __restrict__ x, const float* __restrict__ pwt,
    float* __restrict__ part)          // [bi*8+g][6][64]
{
    int blk = blockIdx.x;              // 4096
    int b = blk & 7;
    int rest = blk >> 3;               // 0..511
    int g = rest & 7, i = rest >> 3;
    int bi = b * 64 + i;
    int tid = threadIdx.x;

    __shared__ float tile[6600];       // x tile [(row*66+col)*33+ci]; aliased as s2[16][387]

    // ---- stage x tile (transposed, halo-padded) ----
    {
        int cs = tid >> 3, r8 = tid & 7;
        const float* xp = x + ((size_t)b * C_ + g * 32 + cs) * HW_;
        #pragma unroll
        for (int t = 0; t < 6; ++t) {
            int idx = r8 * 6 + t;
            int r = idx >> 4, v4 = idx & 15;
            int ii = i + r - 1;
            float4 val = make_float4(0.f, 0.f, 0.f, 0.f);
            if (ii >= 0 && ii < 64)
                val = *(const float4*)(xp + ii * 64 + v4 * 4);
            int base = (r * 66 + 1 + v4 * 4) * 33 + cs;
            tile[base]      = val.x;  tile[base + 33]  = val.y;
            tile[base + 66] = val.z;  tile[base + 99]  = val.w;
        }
        if (tid < 192) {
            int ci = tid / 6, rem = tid - ci * 6;
            int ki = rem >> 1, side = rem & 1;
            tile[(ki * 66 + side * 65) * 33 + ci] = 0.f;
        }
    }
    __syncthreads();

    int sub = tid >> 4;                // 0..15
    int jq  = tid & 15;                // 0..15: pixels jq*4 .. jq*4+3

    float acc[6][4];
    #pragma unroll
    for (int tt = 0; tt < 6; ++tt)
        #pragma unroll
        for (int p = 0; p < 4; ++p) acc[tt][p] = 0.f;

    #pragma unroll
    for (int t = 0; t < 2; ++t) {
        int ci = sub + 16 * t;
        float xv[3][6];                // tile cols jq*4 .. jq*4+5
        #pragma unroll
        for (int ki = 0; ki < 3; ++ki)
            #pragma unroll
            for (int cc = 0; cc < 6; ++cc)
                xv[ki][cc] = tile[(ki * 66 + jq * 4 + cc) * 33 + ci];
        const float* wp = pwt + (g * 32 + ci) * 72;
        #pragma unroll
        for (int tt = 0; tt < 6; ++tt) {
            float w[9];
            *(float4*)&w[0] = *(const float4*)(wp + tt * 12);
            *(float4*)&w[4] = *(const float4*)(wp + tt * 12 + 4);
            w[8] = wp[tt * 12 + 8];
            #pragma unroll
            for (int ki = 0; ki < 3; ++ki)
                #pragma unroll
                for (int kj = 0; kj < 3; ++kj) {
                    float wgt = w[ki * 3 + kj];
                    #pragma unroll
                    for (int p = 0; p < 4; ++p)
                        acc[tt][p] += wgt * xv[ki][kj + p];
                }
        }
    }

    // ---- 16-sub reduction via LDS tree (alias tile as s2, stride 387) ----
    __syncthreads();
    {
        float* s2 = tile + sub * 387;
        #pragma unroll
        for (int tt = 0; tt < 6; ++tt)
            #pragma unroll
            for (int p = 0; p < 4; ++p)
                s2[tt * 64 + jq * 4 + p] = acc[tt][p];
    }
    __syncthreads();
    size_t pslot = (size_t)bi * 8 + g;
    for (int idx = tid; idx < 384; idx += 256) {
        float s = 0.f;
        #pragma unroll
        for (int sb = 0; sb < 16; ++sb)
            s += tile[sb * 387 + idx];
        part[pslot * 384 + idx] = s;
    }
}

// ---------------- K1b: offset stage 2 -> paired gather tables ---------------
__global__ __launch_bounds__(256) void offset_s2_kernel(
    const float* __restrict__ part, const float* __restrict__ pb,
    int2* __restrict__ tbl_off, float4* __restrict__ tbl_w)
{
    int pix = blockIdx.x * 256 + threadIdx.x;   // grid=128
    int b = pix >> 12, rem = pix & 4095, i = rem >> 6, j = rem & 63;
    int bi = b * 64 + i;
    float v[6];
    #pragma unroll
    for (int tt = 0; tt < 6; ++tt) v[tt] = pb[tt];
    for (int g = 0; g < 8; ++g) {
        const float* pp = part + ((size_t)bi * 8 + g) * 384;
        #pragma unroll
        for (int tt = 0; tt < 6; ++tt) v[tt] += pp[tt * 64 + j];
    }
    const float pnx[3] = {0.f, 0.f, 1.f};
    const float pny[3] = {0.f, 1.f, 0.f};
    #pragma unroll
    for (int n = 0; n < 3; ++n) {
        float px_ = (float)i + pnx[n] + v[n];
        float py_ = (float)j + pny[n] + v[n + 3];
        float qx = floorf(px_), qy = floorf(py_);
        float qlx = fminf(fmaxf(qx,       0.f), 63.f);
        float qly = fminf(fmaxf(qy,       0.f), 63.f);
        float qrx = fminf(fmaxf(qx + 1.f, 0.f), 63.f);
        float qry = fminf(fmaxf(qy + 1.f, 0.f), 63.f);
        float pxc = fminf(fmaxf(px_,      0.f), 63.f);
        float pyc = fminf(fmaxf(py_,      0.f), 63.f);
        float glt = (1.f + (qlx - pxc)) * (1.f + (qly - pyc));
        float grb = (1.f - (qrx - pxc)) * (1.f - (qry - pyc));
        float glb = (1.f + (qlx - pxc)) * (1.f - (qry - pyc));
        float grt = (1.f - (qrx - pxc)) * (1.f + (qly - pyc));
        int ilx = (int)qlx, irx = (int)qrx;
        int ily = (int)qly, iry = (int)qry;
        int c0; float a0, a1, b0, b1;
        if (ily == iry) {
            if (ily == 0) { c0 = 0;  a0 = glt + glb; a1 = 0.f; b0 = grt + grb; b1 = 0.f; }
            else          { c0 = 62; a0 = 0.f; a1 = glt + glb; b0 = 0.f; b1 = grt + grb; }
        } else { c0 = ily; a0 = glt; a1 = glb; b0 = grt; b1 = grb; }
        int oi = (b * 3 + n) * HW_ + i * 64 + j;
        tbl_off[oi] = make_int2(ilx * 64 + c0, irx * 64 + c0);
        tbl_w[oi]   = make_float4(a0, a1, b0, b1);
    }
}

// ---------------- K2a: gather — writes v in K-TILED layout ------------------
// v2[((P*24 + t)*2048) + (kq*64 + pixl)*8 + e]  (shorts), P=pix-block, t=k-chunk.
// Each ak K-step then reads one contiguous 4 KB block.
__global__ __launch_bounds__(256) void gather_kernel(
    const float* __restrict__ xt, const int2* __restrict__ tbl_off,
    const float4* __restrict__ tbl_w, unsigned short* __restrict__ v)
{
    int blk = blockIdx.x;          // 1536
    int b = blk & 7;
    int rest = blk >> 3;           // 0..191
    int n = rest >> 6, i = rest & 63;
    int bi = b * 64 + i;           // = pixel-block P
    int tid = threadIdx.x;
    int lane = tid & 63, wv = tid >> 6;
    int ci4 = lane * 4;
    const float* xb = xt + (size_t)b * 1048576;

    int tC = (n << 3) + (ci4 >> 5);        // k-chunk (32k) index
    int kq = (ci4 >> 3) & 3;
    int e  = ci4 & 7;
    unsigned short* vb = v + ((size_t)bi * 24 + tC) * 2048 + kq * 512 + e;

    for (int it0 = 0; it0 < 16; it0 += 4) {
        float4 A[4], Bv[4], Cv[4], Dv[4], w4[4];
        #pragma unroll
        for (int u = 0; u < 4; ++u) {
            int j = wv * 16 + it0 + u;
            int oi = (b * 3 + n) * HW_ + i * 64 + j;
            int2 off = tbl_off[oi];
            w4[u] = tbl_w[oi];
            const float* p0 = xb + (size_t)off.x * 256 + ci4;
            const float* p1 = xb + (size_t)off.y * 256 + ci4;
            A[u]  = *(const float4*)p0;
            Bv[u] = *(const float4*)(p0 + 256);
            Cv[u] = *(const float4*)p1;
            Dv[u] = *(const float4*)(p1 + 256);
        }
        #pragma unroll
        for (int u = 0; u < 4; ++u) {
            int j = wv * 16 + it0 + u;
            union { unsigned short h[4]; uint2 q; } pk;
            pk.h[0] = f2bf(w4[u].x*A[u].x + w4[u].y*Bv[u].x + w4[u].z*Cv[u].x + w4[u].w*Dv[u].x);
            pk.h[1] = f2bf(w4[u].x*A[u].y + w4[u].y*Bv[u].y + w4[u].z*Cv[u].y + w4[u].w*Dv[u].y);
            pk.h[2] = f2bf(w4[u].x*A[u].z + w4[u].y*Bv[u].z + w4[u].z*Cv[u].z + w4[u].w*Dv[u].z);
            pk.h[3] = f2bf(w4[u].x*A[u].w + w4[u].y*Bv[u].w + w4[u].z*Cv[u].w + w4[u].w*Dv[u].w);
            *(uint2*)&vb[j * 8] = pk.q;
        }
    }
}

// ---------------- K2b: AK GEMM (bf16 MFMA, round-0 structure) ---------------
// Single-buffer 2-barrier loop; ALL staging via global_load_lds(16B) from
// K-tiled (lane-contiguous) W and v.
__global__ __launch_bounds__(256) void ak_mfma_kernel(
    const unsigned short* __restrict__ v, const unsigned short* __restrict__ W,
    unsigned short* __restrict__ yh, float* __restrict__ p1, float* __restrict__ p2)
{
    int blk = blockIdx.x;              // 512
    int b = blk & 7, i = blk >> 3;
    int P = b * 64 + i;                // pixel-block id in v layout
    int tid = threadIdx.x;
    int wv = tid >> 6, lane = tid & 63;
    int quad = lane >> 4, l15 = lane & 15;
    __shared__ __align__(16) unsigned short sA[8192];
    __shared__ __align__(16) unsigned short sB[2048];

    const unsigned short* vP = v + (size_t)P * 24 * 2048;

    f32x4 acc[4][4];
    #pragma unroll
    for (int mt = 0; mt < 4; ++mt)
        #pragma unroll
        for (int nt = 0; nt < 4; ++nt) acc[mt][nt] = (f32x4){0.f, 0.f, 0.f, 0.f};

    for (int t = 0; t < 24; ++t) {
        #pragma unroll
        for (int s = 0; s < 4; ++s)
            gl2lds16(W + ((size_t)(t * 4 + s) * 256 + tid) * 8, &sA[(s * 256 + tid) * 8]);
        gl2lds16(vP + (size_t)t * 2048 + tid * 8, &sB[tid * 8]);
        __syncthreads();
        short8 af[4], bf[4];
        #pragma unroll
        for (int mt = 0; mt < 4; ++mt)
            af[mt] = *(const short8*)&sA[(quad * 256 + wv * 64 + mt * 16 + l15) * 8];
        #pragma unroll
        for (int nt = 0; nt < 4; ++nt)
            bf[nt] = *(const short8*)&sB[(quad * 64 + nt * 16 + l15) * 8];
        #pragma unroll
        for (int mt = 0; mt < 4; ++mt)
            #pragma unroll
            for (int nt = 0; nt < 4; ++nt)
                acc[mt][nt] = __builtin_amdgcn_mfma_f32_16x16x32_bf16(
                    af[mt], bf[nt], acc[mt][nt], 0, 0, 0);
        __syncthreads();
    }
    #pragma unroll
    for (int mt = 0; mt < 4; ++mt) {
        #pragma unroll
        for (int r = 0; r < 4; ++r) {
            int co = wv * 64 + mt * 16 + quad * 4 + r;
            size_t base = ((size_t)b * C_ + co) * HW_ + i * 64;
            float s1 = 0.f, s2 = 0.f;
            #pragma unroll
            for (int nt = 0; nt < 4; ++nt) {
                float val = acc[mt][nt][r];
                s1 += val; s2 += val * val;
                yh[base + nt * 16 + l15] = f2bf(val);
            }
            #pragma unroll
            for (int m = 1; m < 16; m <<= 1) {
                s1 += __shfl_xor(s1, m); s2 += __shfl_xor(s2, m);
            }
            if (l15 == 0) { p1[co * 512 + blk] = s1; p2[co * 512 + blk] = s2; }
        }
    }
}

// ---------------- K3: BN stats from partials --------------------------------
__global__ __launch_bounds__(256) void bn_stats_kernel(
    const float* __restrict__ p1, const float* __restrict__ p2,
    const float* __restrict__ gamma, const float* __restrict__ beta,
    float* __restrict__ ss)
{
    int co = blockIdx.x, tid = threadIdx.x;     // grid=256
    float a = p1[co * 512 + tid] + p1[co * 512 + 256 + tid];
    float q = p2[co * 512 + tid] + p2[co * 512 + 256 + tid];
    __shared__ float r1[256], r2[256];
    r1[tid] = a; r2[tid] = q; __syncthreads();
    for (int st = 128; st > 0; st >>= 1) {
        if (tid < st) { r1[tid] += r1[tid + st]; r2[tid] += r2[tid + st]; }
        __syncthreads();
    }
    if (tid == 0) {
        const float inv_n = 1.f / (float)NPIX;
        float m = r1[0] * inv_n;
        float var = r2[0] * inv_n - m * m;
        float sc = gamma[co] * rsqrtf(var + 1e-5f);
        ss[co] = sc; ss[256 + co] = beta[co] - m * sc;
    }
}

// ---------------- K4: fused BN+SiLU + 5x5 depthwise (16-wide strips) --------
// Thread = 1 output row x 16 cols: 5 ds_read_b128 per tap-row (vs 2 per
// 4-wide strip) -> 25 reads/thread vs 40 for the same FMA count.
__global__ __launch_bounds__(256) void dw5_fused_kernel(
    const unsigned short* __restrict__ in, const float* __restrict__ ss,
    const float* __restrict__ w, const float* __restrict__ bias,
    unsigned short* __restrict__ out)
{
    int blkI = blockIdx.x;         // 2048
    int b = blkI & 7, c = blkI >> 3;
    int bc = b * 256 + c;
    int tid = threadIdx.x;
    __shared__ float tile[68 * 68];
    float sc = ss[c], sh = ss[256 + c];
    const unsigned short* ip = in + (size_t)bc * HW_;
    for (int s = tid; s < 68 * 68; s += 256) {
        int r = s / 68, cc = s - r * 68;
        int ii = r - 2, jj = cc - 2;
        float vv = 0.f;
        if (ii >= 0 && ii < 64 && jj >= 0 && jj < 64) {
            float t = b2f(ip[ii * 64 + jj]) * sc + sh;
            vv = silu_f(t);
        }
        tile[s] = vv;
    }
    float wr[25];
    #pragma unroll
    for (int t = 0; t < 25; ++t) wr[t] = w[c * 25 + t];
    float bv = bias[c];
    __syncthreads();

    int jb = tid & 3, row = tid >> 2;     // 16-col strip, one output row
    int j0 = jb * 16;
    float acc[16];
    #pragma unroll
    for (int j = 0; j < 16; ++j) acc[j] = bv;
    #pragma unroll
    for (int di = 0; di < 5; ++di) {
        const float* tp = &tile[(row + di) * 68 + j0];
        float vv[20];
        #pragma unroll
        for (int q = 0; q < 5; ++q)
            *(float4*)&vv[q * 4] = *(const float4*)(tp + q * 4);
        #pragma unroll
        for (int dj = 0; dj < 5; ++dj) {
            float wv = wr[di * 5 + dj];
            #pragma unroll
            for (int j = 0; j < 16; ++j)
                acc[j] += wv * vv[dj + j];
        }
    }
    unsigned short* op = out + (size_t)bc * HW_ + row * 64 + j0;
    union { unsigned short h[8]; uint4 u; } pk;
    #pragma unroll
    for (int half = 0; half < 2; ++half) {
        #pragma unroll
        for (int j = 0; j < 8; ++j) pk.h[j] = f2bf(acc[half * 8 + j]);
        *(uint4*)&op[half * 8] = pk.u;
    }
}

// ---------------- K5: 7x7 dilated(3) depthwise (16-wide strips) -------------
// Thread = 1 output row x 16 cols: 9 ds_read_b128 per tap-row -> 63
// reads/thread vs 168 for the 4-wide strip (same 784 FMAs).
__global__ __launch_bounds__(256) void dw7d3_kernel(
    const unsigned short* __restrict__ in, const float* __restrict__ w,
    const float* __restrict__ bias, unsigned short* __restrict__ out)
{
    int blkI = blockIdx.x;         // 2048
    int b = blkI & 7, c = blkI >> 3;
    int bc = b * 256 + c;
    int tid = threadIdx.x;
    __shared__ float tile[82 * 84];
    const unsigned short* ip = in + (size_t)bc * HW_;
    for (int s = tid; s < 82 * 84; s += 256) {
        int r = s / 84, cc = s - r * 84;
        int ii = r - 9, jj = cc - 9;
        float vv = 0.f;
        if (ii >= 0 && ii < 64 && jj >= 0 && jj < 64) vv = b2f(ip[ii * 64 + jj]);
        tile[s] = vv;
    }
    float wr[49];
    #pragma unroll
    for (int t = 0; t < 49; ++t) wr[t] = w[c * 49 + t];
    float bv = bias[c];
    __syncthreads();

    int jb = tid & 3, row = tid >> 2;     // 16-col strip, one output row
    int j0 = jb * 16;
    float acc[16];
    #pragma unroll
    for (int j = 0; j < 16; ++j) acc[j] = bv;
    #pragma unroll
    for (int di = 0; di < 7; ++di) {
        const float* tp = &tile[(row + 3 * di) * 84 + j0];
        float vv[36];                 // cols j0 .. j0+35 (<= 83, fits row)
        #pragma unroll
        for (int q = 0; q < 9; ++q)
            *(float4*)&vv[q * 4] = *(const float4*)(tp + q * 4);
        #pragma unroll
        for (int dj = 0; dj < 7; ++dj) {
            float wv = wr[di * 7 + dj];
            #pragma unroll
            for (int j = 0; j < 16; ++j)
                acc[j] += wv * vv[3 * dj + j];
        }
    }
    unsigned short* op = out + (size_t)bc * HW_ + row * 64 + j0;
    union { unsigned short h[8]; uint4 u; } pk;
    #pragma unroll
    for (int half = 0; half < 2; ++half) {
        #pragma unroll
        for (int j = 0; j < 8; ++j) pk.h[j] = f2bf(acc[half * 8 + j]);
        *(uint4*)&op[half * 8] = pk.u;
    }
}

// ---------------- K6/K7: 1x1 conv bf16 MFMA GEMM (round-0 structure) --------
// A via global_load_lds from K-tiled W (lane-contiguous); B (CHW, already
// 128B-contiguous per instruction) via register staging.
template<int MODE>
__global__ __launch_bounds__(256) void gemm1x1_mfma(
    const unsigned short* __restrict__ in, const unsigned short* __restrict__ W,
    const float* __restrict__ bias,
    const unsigned short* __restrict__ auxh, const float* __restrict__ auxf,
    const float* __restrict__ ss,
    unsigned short* __restrict__ out_bf, float* __restrict__ out_f)
{
    int blk = blockIdx.x;              // 512
    int b = blk & 7, i = blk >> 3;
    int tid = threadIdx.x;
    int wv = tid >> 6, lane = tid & 63;
    int quad = lane >> 4, l15 = lane & 15;
    __shared__ __align__(16) unsigned short sA[8192];
    __shared__ __align__(16) unsigned short sB[2048];
    int pixS = tid & 63, kqS = tid >> 6;

    const unsigned short* bp = in + ((size_t)b * C_) * HW_ + i * 64 + pixS;

    f32x4 acc[4][4];
    #pragma unroll
    for (int mt = 0; mt < 4; ++mt)
        #pragma unroll
        for (int nt = 0; nt < 4; ++nt) acc[mt][nt] = (f32x4){0.f, 0.f, 0.f, 0.f};

    for (int t = 0; t < 8; ++t) {
        #pragma unroll
        for (int s = 0; s < 4; ++s)
            gl2lds16(W + ((size_t)(t * 4 + s) * 256 + tid) * 8, &sA[(s * 256 + tid) * 8]);
        {
            const unsigned short* p = bp + (size_t)(t * 32 + kqS * 8) * HW_;
            union { unsigned short h[8]; uint4 u; } hb;
            #pragma unroll
            for (int jj = 0; jj < 8; ++jj) hb.h[jj] = p[(size_t)jj * HW_];
            *(uint4*)&sB[(kqS * 64 + pixS) * 8] = hb.u;
        }
        __syncthreads();
        short8 af[4], bf[4];
        #pragma unroll
        for (int mt = 0; mt < 4; ++mt)
            af[mt] = *(const short8*)&sA[(quad * 256 + wv * 64 + mt * 16 + l15) * 8];
        #pragma unroll
        for (int nt = 0; nt < 4; ++nt)
            bf[nt] = *(const short8*)&sB[(quad * 64 + nt * 16 + l15) * 8];
        #pragma unroll
        for (int mt = 0; mt < 4; ++mt)
            #pragma unroll
            for (int nt = 0; nt < 4; ++nt)
                acc[mt][nt] = __builtin_amdgcn_mfma_f32_16x16x32_bf16(
                    af[mt], bf[nt], acc[mt][nt], 0, 0, 0);
        __syncthreads();
    }
    #pragma unroll
    for (int mt = 0; mt < 4; ++mt) {
        #pragma unroll
        for (int r = 0; r < 4; ++r) {
            int co = wv * 64 + mt * 16 + quad * 4 + r;
            float bco = bias[co];
            size_t base = ((size_t)b * C_ + co) * HW_ + i * 64;
            if (MODE == 0) {
                float sc = ss[co], sh = ss[256 + co];
                #pragma unroll
                for (int nt = 0; nt < 4; ++nt) {
                    int col = nt * 16 + l15;
                    float o = acc[mt][nt][r] + bco;
                    float u = silu_f(b2f(auxh[base + col]) * sc + sh);
                    out_bf[base + col] = f2bf(o * u);
                }
            } else {
                #pragma unroll
                for (int nt = 0; nt < 4; ++nt) {
                    int col = nt * 16 + l15;
                    out_f[base + col] = acc[mt][nt][r] + bco + auxf[base + col];
                }
            }
        }
    }
}

// ---------------- launch ----------------------------------------------------
extern "C" void kernel_launch(void* const* d_in, const int* in_sizes, int n_in,
                              void* d_out, int out_size, void* d_ws, size_t ws_size,
                              hipStream_t stream) {
    const float* x     = (const float*)d_in[0];
    const float* p_w   = (const float*)d_in[1];
    const float* p_b   = (const float*)d_in[2];
    const float* ak_w  = (const float*)d_in[3];
    const float* ak_g  = (const float*)d_in[4];
    const float* ak_b  = (const float*)d_in[5];
    const float* l0_w  = (const float*)d_in[6];
    const float* l0_b  = (const float*)d_in[7];
    const float* ls_w  = (const float*)d_in[8];
    const float* ls_b  = (const float*)d_in[9];
    const float* l1_w  = (const float*)d_in[10];
    const float* l1_b  = (const float*)d_in[11];
    const float* cv_w  = (const float*)d_in[12];
    const float* cv_b  = (const float*)d_in[13];
    float* out = (float*)d_out;

    char* w = (char*)d_ws;
    int2*   tbl_off = (int2*)w;                              // 786 KB
    float4* tbl_w   = (float4*)(w + 786432);                 // 1.5 MB
    unsigned short* wak = (unsigned short*)(w + 2359296);    // 384 KB
    unsigned short* wl1 = (unsigned short*)(w + 2752512);    // 128 KB
    unsigned short* wcv = (unsigned short*)(w + 2883584);    // 128 KB
    float* p1 = (float*)(w + 3014656);                       // 512 KB
    float* p2 = (float*)(w + 3538944);                       // 512 KB
    float* ss = (float*)(w + 4063232);                       // 2 KB
    float* pwt = (float*)(w + 4065280);                      // 72 KB
    // time-multiplexed regions:
    float* xt   = (float*)(w + 4194304);                     // 32 MB (dead after gather)
    unsigned short* ybh    = (unsigned short*)(w + 4194304); // 16 MB (ak writes, after gather)
    unsigned short* dw5out = (unsigned short*)(w + 20971520);// 16 MB
    float* part = (float*)(w + 37748736);                    // 6.3 MB (dead after s2)
    unsigned short* attn   = (unsigned short*)(w + 37748736);// 16 MB (dw7 out)
    unsigned short* v      = (unsigned short*)(w + 44040192);// 48 MB (dead after ak)
    unsigned short* g0out  = (unsigned short*)(w + 54525952);// 16 MB (after gemm0)

    prep_kernel<<<1352, 256, 0, stream>>>(ak_w, l1_w, cv_w, p_w, wak, wl1, wcv, pwt);
    offset_s1_kernel<<<4096, 256, 0, stream>>>(x, pwt, part);
    offset_s2_kernel<<<128, 256, 0, stream>>>(part, p_b, tbl_off, tbl_w);
    transpose_kernel<<<1024, 256, 0, stream>>>(x, xt);
    gather_kernel<<<1536, 256, 0, stream>>>(xt, tbl_off, tbl_w, v);
    ak_mfma_kernel<<<512, 256, 0, stream>>>(v, wak, ybh, p1, p2);
    bn_stats_kernel<<<256, 256, 0, stream>>>(p1, p2, ak_g, ak_b, ss);
    dw5_fused_kernel<<<2048, 256, 0, stream>>>(ybh, ss, l0_w, l0_b, dw5out);
    dw7d3_kernel<<<2048, 256, 0, stream>>>(dw5out, ls_w, ls_b, attn);
    gemm1x1_mfma<0><<<512, 256, 0, stream>>>(attn, wl1, l1_b, ybh, nullptr, ss, g0out, nullptr);
    gemm1x1_mfma<1><<<512, 256, 0, stream>>>(g0out, wcv, cv_b, nullptr, x, nullptr, nullptr, out);
}

// Round 6
// 291.877 us; speedup vs baseline: 1.1722x; 1.0198x over previous
//
#include <hip/hip_runtime.h>
#include <math.h>
#include <stdint.h>

#define B_ 8
#define C_ 256
#define HW_ 4096
#define NPIX 32768
#define NELEM (B_*C_*HW_)   // 8388608

typedef __attribute__((ext_vector_type(8))) short short8;
typedef __attribute__((ext_vector_type(4))) float f32x4;

__device__ __forceinline__ unsigned short f2bf(float f) {
    union { float f; uint32_t u; } v; v.f = f;
    uint32_t r = v.u + 0x7FFFu + ((v.u >> 16) & 1u);
    return (unsigned short)(r >> 16);
}
__device__ __forceinline__ float b2f(unsigned short h) {
    union { uint32_t u; float f; } v; v.u = ((uint32_t)h) << 16; return v.f;
}
__device__ __forceinline__ float silu_f(float v) { return v / (1.f + __expf(-v)); }

// unpack 4 bf16 (uint2) -> float4
__device__ __forceinline__ float4 up4(uint2 v) {
    float4 r;
    r.x = b2f((unsigned short)(v.x & 0xffffu));
    r.y = b2f((unsigned short)(v.x >> 16));
    r.z = b2f((unsigned short)(v.y & 0xffffu));
    r.w = b2f((unsigned short)(v.y >> 16));
    return r;
}

// async global->LDS, 16B per lane; LDS dest = wave-uniform base + lane*16.
// Src MUST be lane-contiguous (round-4 lesson: TA request count).
__device__ __forceinline__ void gl2lds16(const void* g, void* l) {
    __builtin_amdgcn_global_load_lds(
        (const __attribute__((address_space(1))) void*)g,
        (__attribute__((address_space(3))) void*)l,
        16, 0, 0);
}

// ---------------- K0: weight conversion (K-TILED layouts) + p_w transpose ---
// Tiled weight layout: Wt[((q)*256 + co)*8 + e] = W[co][k''] with k'' = q*8+e.
// A K-step (32 k) = 4 consecutive q blocks = one contiguous 16 KB chunk.
__global__ __launch_bounds__(256) void prep_kernel(
    const float* __restrict__ akw, const float* __restrict__ l1w,
    const float* __restrict__ cvw, const float* __restrict__ pw,
    unsigned short* __restrict__ wak, unsigned short* __restrict__ wl1,
    unsigned short* __restrict__ wcv, float* __restrict__ pwt)
{
    int gid = blockIdx.x * 256 + threadIdx.x;      // grid=1352
    if (gid < 196608) {
        int e = gid & 7;
        int co = (gid >> 3) & 255;
        int q = gid >> 11;            // 0..95
        int kpp = q * 8 + e;          // k'' = n*256+ci
        int n = kpp >> 8, ci = kpp & 255;
        wak[gid] = f2bf(akw[co * 768 + ci * 3 + n]);
    }
    else if (gid < 262144) {
        int g = gid - 196608;
        int e = g & 7, co = (g >> 3) & 255, q = g >> 11;   // q 0..31
        wl1[g] = f2bf(l1w[co * 256 + q * 8 + e]);
    }
    else if (gid < 327680) {
        int g = gid - 262144;
        int e = g & 7, co = (g >> 3) & 255, q = g >> 11;
        wcv[g] = f2bf(cvw[co * 256 + q * 8 + e]);
    }
    else if (gid < 346112) {
        int idx = gid - 327680;
        int ci = idx / 72, r = idx - ci * 72;
        int tt = r / 12, t9 = r - tt * 12;
        pwt[idx] = (t9 < 9) ? pw[tt * 2304 + ci * 9 + t9] : 0.f;
    }
}

// ---------------- K0b: x CHW -> HWC transpose, bf16 out (XCD-swizzled) ------
__global__ __launch_bounds__(256) void transpose_kernel(
    const float* __restrict__ x, unsigned short* __restrict__ xt)
{
    int blk = blockIdx.x;            // 1024
    int b = blk & 7;
    int rest = blk >> 3;             // 0..127
    int half = rest & 1, i = rest >> 1;
    int bi = b * 64 + i;
    int tid = threadIdx.x;
    __shared__ float tile[64 * 132];

    {
        int ci_l = tid >> 6, jj = tid & 63;
        const float* ip = x + ((size_t)b * C_ + half * 128 + ci_l) * HW_ + i * 64 + jj;
        #pragma unroll 4
        for (int it = 0; it < 32; ++it)
            tile[jj * 132 + ci_l + it * 4] = ip[(size_t)it * 4 * HW_];
    }
    __syncthreads();
    {
        int j = tid >> 2, q = tid & 3;
        unsigned short* op = xt + ((size_t)(bi * 64 + j)) * 256 + half * 128 + q * 32;
        const float* tp = &tile[j * 132 + q * 32];
        #pragma unroll
        for (int f = 0; f < 4; ++f) {
            union { unsigned short h[8]; uint4 u; } pk;
            #pragma unroll
            for (int e = 0; e < 8; ++e) pk.h[e] = f2bf(tp[f * 8 + e]);
            *(uint4*)(op + f * 8) = pk.u;
        }
    }
}

// ---------------- K1a: offset conv stage 1 (v5: register acc, small tree) ---
__global__ __launch_bounds__(256) void offset_s1_kernel(
    const float* __restrict__ x, const float* __restrict__ pwt,
    float* __restrict__ part)          // [bi*8+g][6][64]
{
    int blk = blockIdx.x;              // 4096
    int b = blk & 7;
    int rest = blk >> 3;               // 0..511
    int g = rest & 7, i = rest >> 3;
    int bi = b * 64 + i;
    int tid = threadIdx.x;

    __shared__ float tile[6600];       // x tile [(row*66+col)*33+ci]; aliased as s2[16][387]

    // ---- stage x tile (transposed, halo-padded) ----
    {
        int cs = tid >> 3, r8 = tid & 7;
        const float* xp = x + ((size_t)b * C_ + g * 32 + cs) * HW_;
        #pragma unroll
        for (int t = 0; t < 6; ++t) {
            int idx = r8 * 6 + t;
            int r = idx >> 4, v4 = idx & 15;
            int ii = i + r - 1;
            float4 val = make_float4(0.f, 0.f, 0.f, 0.f);
            if (ii >= 0 && ii < 64)
                val = *(const float4*)(xp + ii * 64 + v4 * 4);
            int base = (r * 66 + 1 + v4 * 4) * 33 + cs;
            tile[base]      = val.x;  tile[base + 33]  = val.y;
            tile[base + 66] = val.z;  tile[base + 99]  = val.w;
        }
        if (tid < 192) {
            int ci = tid / 6, rem = tid - ci * 6;
            int ki = rem >> 1, side = rem & 1;
            tile[(ki * 66 + side * 65) * 33 + ci] = 0.f;
        }
    }
    __syncthreads();

    int sub = tid >> 4;                // 0..15
    int jq  = tid & 15;                // 0..15: pixels jq*4 .. jq*4+3

    float acc[6][4];
    #pragma unroll
    for (int tt = 0; tt < 6; ++tt)
        #pragma unroll
        for (int p = 0; p < 4; ++p) acc[tt][p] = 0.f;

    #pragma unroll
    for (int t = 0; t < 2; ++t) {
        int ci = sub + 16 * t;
        float xv[3][6];                // tile cols jq*4 .. jq*4+5
        #pragma unroll
        for (int ki = 0; ki < 3; ++ki)
            #pragma unroll
            for (int cc = 0; cc < 6; ++cc)
                xv[ki][cc] = tile[(ki * 66 + jq * 4 + cc) * 33 + ci];
        const float* wp = pwt + (g * 32 + ci) * 72;
        #pragma unroll
        for (int tt = 0; tt < 6; ++tt) {
            float w[9];
            *(float4*)&w[0] = *(const float4*)(wp + tt * 12);
            *(float4*)&w[4] = *(const float4*)(wp + tt * 12 + 4);
            w[8] = wp[tt * 12 + 8];
            #pragma unroll
            for (int ki = 0; ki < 3; ++ki)
                #pragma unroll
                for (int kj = 0; kj < 3; ++kj) {
                    float wgt = w[ki * 3 + kj];
                    #pragma unroll
                    for (int p = 0; p < 4; ++p)
                        acc[tt][p] += wgt * xv[ki][kj + p];
                }
        }
    }

    // ---- 16-sub reduction via LDS tree (alias tile as s2, stride 387) ----
    __syncthreads();
    {
        float* s2 = tile + sub * 387;
        #pragma unroll
        for (int tt = 0; tt < 6; ++tt)
            #pragma unroll
            for (int p = 0; p < 4; ++p)
                s2[tt * 64 + jq * 4 + p] = acc[tt][p];
    }
    __syncthreads();
    size_t pslot = (size_t)bi * 8 + g;
    for (int idx = tid; idx < 384; idx += 256) {
        float s = 0.f;
        #pragma unroll
        for (int sb = 0; sb < 16; ++sb)
            s += tile[sb * 387 + idx];
        part[pslot * 384 + idx] = s;
    }
}

// ---------------- K1b: offset stage 2 -> paired gather tables ---------------
__global__ __launch_bounds__(256) void offset_s2_kernel(
    const float* __restrict__ part, const float* __restrict__ pb,
    int2* __restrict__ tbl_off, float4* __restrict__ tbl_w)
{
    int pix = blockIdx.x * 256 + threadIdx.x;   // grid=128
    int b = pix >> 12, rem = pix & 4095, i = rem >> 6, j = rem & 63;
    int bi = b * 64 + i;
    float v[6];
    #pragma unroll
    for (int tt = 0; tt < 6; ++tt) v[tt] = pb[tt];
    for (int g = 0; g < 8; ++g) {
        const float* pp = part + ((size_t)bi * 8 + g) * 384;
        #pragma unroll
        for (int tt = 0; tt < 6; ++tt) v[tt] += pp[tt * 64 + j];
    }
    const float pnx[3] = {0.f, 0.f, 1.f};
    const float pny[3] = {0.f, 1.f, 0.f};
    #pragma unroll
    for (int n = 0; n < 3; ++n) {
        float px_ = (float)i + pnx[n] + v[n];
        float py_ = (float)j + pny[n] + v[n + 3];
        float qx = floorf(px_), qy = floorf(py_);
        float qlx = fminf(fmaxf(qx,       0.f), 63.f);
        float qly = fminf(fmaxf(qy,       0.f), 63.f);
        float qrx = fminf(fmaxf(qx + 1.f, 0.f), 63.f);
        float qry = fminf(fmaxf(qy + 1.f, 0.f), 63.f);
        float pxc = fminf(fmaxf(px_,      0.f), 63.f);
        float pyc = fminf(fmaxf(py_,      0.f), 63.f);
        float glt = (1.f + (qlx - pxc)) * (1.f + (qly - pyc));
        float grb = (1.f - (qrx - pxc)) * (1.f - (qry - pyc));
        float glb = (1.f + (qlx - pxc)) * (1.f - (qry - pyc));
        float grt = (1.f - (qrx - pxc)) * (1.f + (qly - pyc));
        int ilx = (int)qlx, irx = (int)qrx;
        int ily = (int)qly, iry = (int)qry;
        int c0; float a0, a1, b0, b1;
        if (ily == iry) {
            if (ily == 0) { c0 = 0;  a0 = glt + glb; a1 = 0.f; b0 = grt + grb; b1 = 0.f; }
            else          { c0 = 62; a0 = 0.f; a1 = glt + glb; b0 = 0.f; b1 = grt + grb; }
        } else { c0 = ily; a0 = glt; a1 = glb; b0 = grt; b1 = grb; }
        int oi = (b * 3 + n) * HW_ + i * 64 + j;
        tbl_off[oi] = make_int2(ilx * 64 + c0, irx * 64 + c0);
        tbl_w[oi]   = make_float4(a0, a1, b0, b1);
    }
}

// ---------------- K2a: gather — bf16 xt rows, writes v in K-TILED layout ----
// v2[((P*24 + t)*2048) + (kq*64 + pixl)*8 + e]  (shorts), P=pix-block, t=k-chunk.
// bf16 xt halves the L2/L3 service bytes (round-5 finding: gather is
// cache-byte-bound at ~10 TB/s aggregate).
__global__ __launch_bounds__(256) void gather_kernel(
    const unsigned short* __restrict__ xt, const int2* __restrict__ tbl_off,
    const float4* __restrict__ tbl_w, unsigned short* __restrict__ v)
{
    int blk = blockIdx.x;          // 1536
    int b = blk & 7;
    int rest = blk >> 3;           // 0..191
    int n = rest >> 6, i = rest & 63;
    int bi = b * 64 + i;           // = pixel-block P
    int tid = threadIdx.x;
    int lane = tid & 63, wv = tid >> 6;
    int ci4 = lane * 4;
    const unsigned short* xb = xt + (size_t)b * 1048576;

    int tC = (n << 3) + (ci4 >> 5);        // k-chunk (32k) index
    int kq = (ci4 >> 3) & 3;
    int e  = ci4 & 7;
    unsigned short* vb = v + ((size_t)bi * 24 + tC) * 2048 + kq * 512 + e;

    for (int it0 = 0; it0 < 16; it0 += 4) {
        uint2 A8[4], B8[4], C8[4], D8[4];
        float4 w4[4];
        #pragma unroll
        for (int u = 0; u < 4; ++u) {
            int j = wv * 16 + it0 + u;
            int oi = (b * 3 + n) * HW_ + i * 64 + j;
            int2 off = tbl_off[oi];
            w4[u] = tbl_w[oi];
            const unsigned short* p0 = xb + (size_t)off.x * 256 + ci4;
            const unsigned short* p1 = xb + (size_t)off.y * 256 + ci4;
            A8[u] = *(const uint2*)p0;
            B8[u] = *(const uint2*)(p0 + 256);
            C8[u] = *(const uint2*)p1;
            D8[u] = *(const uint2*)(p1 + 256);
        }
        #pragma unroll
        for (int u = 0; u < 4; ++u) {
            int j = wv * 16 + it0 + u;
            float4 A = up4(A8[u]), Bv = up4(B8[u]), Cv = up4(C8[u]), Dv = up4(D8[u]);
            union { unsigned short h[4]; uint2 q; } pk;
            pk.h[0] = f2bf(w4[u].x*A.x + w4[u].y*Bv.x + w4[u].z*Cv.x + w4[u].w*Dv.x);
            pk.h[1] = f2bf(w4[u].x*A.y + w4[u].y*Bv.y + w4[u].z*Cv.y + w4[u].w*Dv.y);
            pk.h[2] = f2bf(w4[u].x*A.z + w4[u].y*Bv.z + w4[u].z*Cv.z + w4[u].w*Dv.z);
            pk.h[3] = f2bf(w4[u].x*A.w + w4[u].y*Bv.w + w4[u].z*Cv.w + w4[u].w*Dv.w);
            *(uint2*)&vb[j * 8] = pk.q;
        }
    }
}

// ---------------- K2b: AK GEMM (bf16 MFMA, round-0 structure) ---------------
// Single-buffer 2-barrier loop; ALL staging via global_load_lds(16B) from
// K-tiled (lane-contiguous) W and v.
__global__ __launch_bounds__(256) void ak_mfma_kernel(
    const unsigned short* __restrict__ v, const unsigned short* __restrict__ W,
    unsigned short* __restrict__ yh, float* __restrict__ p1, float* __restrict__ p2)
{
    int blk = blockIdx.x;              // 512
    int b = blk & 7, i = blk >> 3;
    int P = b * 64 + i;                // pixel-block id in v layout
    int tid = threadIdx.x;
    int wv = tid >> 6, lane = tid & 63;
    int quad = lane >> 4, l15 = lane & 15;
    __shared__ __align__(16) unsigned short sA[8192];
    __shared__ __align__(16) unsigned short sB[2048];

    const unsigned short* vP = v + (size_t)P * 24 * 2048;

    f32x4 acc[4][4];
    #pragma unroll
    for (int mt = 0; mt < 4; ++mt)
        #pragma unroll
        for (int nt = 0; nt < 4; ++nt) acc[mt][nt] = (f32x4){0.f, 0.f, 0.f, 0.f};

    for (int t = 0; t < 24; ++t) {
        #pragma unroll
        for (int s = 0; s < 4; ++s)
            gl2lds16(W + ((size_t)(t * 4 + s) * 256 + tid) * 8, &sA[(s * 256 + tid) * 8]);
        gl2lds16(vP + (size_t)t * 2048 + tid * 8, &sB[tid * 8]);
        __syncthreads();
        short8 af[4], bf[4];
        #pragma unroll
        for (int mt = 0; mt < 4; ++mt)
            af[mt] = *(const short8*)&sA[(quad * 256 + wv * 64 + mt * 16 + l15) * 8];
        #pragma unroll
        for (int nt = 0; nt < 4; ++nt)
            bf[nt] = *(const short8*)&sB[(quad * 64 + nt * 16 + l15) * 8];
        #pragma unroll
        for (int mt = 0; mt < 4; ++mt)
            #pragma unroll
            for (int nt = 0; nt < 4; ++nt)
                acc[mt][nt] = __builtin_amdgcn_mfma_f32_16x16x32_bf16(
                    af[mt], bf[nt], acc[mt][nt], 0, 0, 0);
        __syncthreads();
    }
    #pragma unroll
    for (int mt = 0; mt < 4; ++mt) {
        #pragma unroll
        for (int r = 0; r < 4; ++r) {
            int co = wv * 64 + mt * 16 + quad * 4 + r;
            size_t base = ((size_t)b * C_ + co) * HW_ + i * 64;
            float s1 = 0.f, s2 = 0.f;
            #pragma unroll
            for (int nt = 0; nt < 4; ++nt) {
                float val = acc[mt][nt][r];
                s1 += val; s2 += val * val;
                yh[base + nt * 16 + l15] = f2bf(val);
            }
            #pragma unroll
            for (int m = 1; m < 16; m <<= 1) {
                s1 += __shfl_xor(s1, m); s2 += __shfl_xor(s2, m);
            }
            if (l15 == 0) { p1[co * 512 + blk] = s1; p2[co * 512 + blk] = s2; }
        }
    }
}

// ---------------- K3: BN stats from partials --------------------------------
__global__ __launch_bounds__(256) void bn_stats_kernel(
    const float* __restrict__ p1, const float* __restrict__ p2,
    const float* __restrict__ gamma, const float* __restrict__ beta,
    float* __restrict__ ss)
{
    int co = blockIdx.x, tid = threadIdx.x;     // grid=256
    float a = p1[co * 512 + tid] + p1[co * 512 + 256 + tid];
    float q = p2[co * 512 + tid] + p2[co * 512 + 256 + tid];
    __shared__ float r1[256], r2[256];
    r1[tid] = a; r2[tid] = q; __syncthreads();
    for (int st = 128; st > 0; st >>= 1) {
        if (tid < st) { r1[tid] += r1[tid + st]; r2[tid] += r2[tid + st]; }
        __syncthreads();
    }
    if (tid == 0) {
        const float inv_n = 1.f / (float)NPIX;
        float m = r1[0] * inv_n;
        float var = r2[0] * inv_n - m * m;
        float sc = gamma[co] * rsqrtf(var + 1e-5f);
        ss[co] = sc; ss[256 + co] = beta[co] - m * sc;
    }
}

// ---------------- K4: fused BN+SiLU + 5x5 depthwise (16-wide strips) --------
__global__ __launch_bounds__(256) void dw5_fused_kernel(
    const unsigned short* __restrict__ in, const float* __restrict__ ss,
    const float* __restrict__ w, const float* __restrict__ bias,
    unsigned short* __restrict__ out)
{
    int blkI = blockIdx.x;         // 2048
    int b = blkI & 7, c = blkI >> 3;
    int bc = b * 256 + c;
    int tid = threadIdx.x;
    __shared__ float tile[68 * 68];
    float sc = ss[c], sh = ss[256 + c];
    const unsigned short* ip = in + (size_t)bc * HW_;
    for (int s = tid; s < 68 * 68; s += 256) {
        int r = s / 68, cc = s - r * 68;
        int ii = r - 2, jj = cc - 2;
        float vv = 0.f;
        if (ii >= 0 && ii < 64 && jj >= 0 && jj < 64) {
            float t = b2f(ip[ii * 64 + jj]) * sc + sh;
            vv = silu_f(t);
        }
        tile[s] = vv;
    }
    float wr[25];
    #pragma unroll
    for (int t = 0; t < 25; ++t) wr[t] = w[c * 25 + t];
    float bv = bias[c];
    __syncthreads();

    int jb = tid & 3, row = tid >> 2;     // 16-col strip, one output row
    int j0 = jb * 16;
    float acc[16];
    #pragma unroll
    for (int j = 0; j < 16; ++j) acc[j] = bv;
    #pragma unroll
    for (int di = 0; di < 5; ++di) {
        const float* tp = &tile[(row + di) * 68 + j0];
        float vv[20];
        #pragma unroll
        for (int q = 0; q < 5; ++q)
            *(float4*)&vv[q * 4] = *(const float4*)(tp + q * 4);
        #pragma unroll
        for (int dj = 0; dj < 5; ++dj) {
            float wv = wr[di * 5 + dj];
            #pragma unroll
            for (int j = 0; j < 16; ++j)
                acc[j] += wv * vv[dj + j];
        }
    }
    unsigned short* op = out + (size_t)bc * HW_ + row * 64 + j0;
    union { unsigned short h[8]; uint4 u; } pk;
    #pragma unroll
    for (int half = 0; half < 2; ++half) {
        #pragma unroll
        for (int j = 0; j < 8; ++j) pk.h[j] = f2bf(acc[half * 8 + j]);
        *(uint4*)&op[half * 8] = pk.u;
    }
}

// ---------------- K5: 7x7 dilated(3) depthwise (16-wide strips) -------------
__global__ __launch_bounds__(256) void dw7d3_kernel(
    const unsigned short* __restrict__ in, const float* __restrict__ w,
    const float* __restrict__ bias, unsigned short* __restrict__ out)
{
    int blkI = blockIdx.x;         // 2048
    int b = blkI & 7, c = blkI >> 3;
    int bc = b * 256 + c;
    int tid = threadIdx.x;
    __shared__ float tile[82 * 84];
    const unsigned short* ip = in + (size_t)bc * HW_;
    for (int s = tid; s < 82 * 84; s += 256) {
        int r = s / 84, cc = s - r * 84;
        int ii = r - 9, jj = cc - 9;
        float vv = 0.f;
        if (ii >= 0 && ii < 64 && jj >= 0 && jj < 64) vv = b2f(ip[ii * 64 + jj]);
        tile[s] = vv;
    }
    float wr[49];
    #pragma unroll
    for (int t = 0; t < 49; ++t) wr[t] = w[c * 49 + t];
    float bv = bias[c];
    __syncthreads();

    int jb = tid & 3, row = tid >> 2;     // 16-col strip, one output row
    int j0 = jb * 16;
    float acc[16];
    #pragma unroll
    for (int j = 0; j < 16; ++j) acc[j] = bv;
    #pragma unroll
    for (int di = 0; di < 7; ++di) {
        const float* tp = &tile[(row + 3 * di) * 84 + j0];
        float vv[36];                 // cols j0 .. j0+35 (<= 83, fits row)
        #pragma unroll
        for (int q = 0; q < 9; ++q)
            *(float4*)&vv[q * 4] = *(const float4*)(tp + q * 4);
        #pragma unroll
        for (int dj = 0; dj < 7; ++dj) {
            float wv = wr[di * 7 + dj];
            #pragma unroll
            for (int j = 0; j < 16; ++j)
                acc[j] += wv * vv[3 * dj + j];
        }
    }
    unsigned short* op = out + (size_t)bc * HW_ + row * 64 + j0;
    union { unsigned short h[8]; uint4 u; } pk;
    #pragma unroll
    for (int half = 0; half < 2; ++half) {
        #pragma unroll
        for (int j = 0; j < 8; ++j) pk.h[j] = f2bf(acc[half * 8 + j]);
        *(uint4*)&op[half * 8] = pk.u;
    }
}

// ---------------- K6/K7: 1x1 conv bf16 MFMA GEMM (round-0 structure) --------
template<int MODE>
__global__ __launch_bounds__(256) void gemm1x1_mfma(
    const unsigned short* __restrict__ in, const unsigned short* __restrict__ W,
    const float* __restrict__ bias,
    const unsigned short* __restrict__ auxh, const float* __restrict__ auxf,
    const float* __restrict__ ss,
    unsigned short* __restrict__ out_bf, float* __restrict__ out_f)
{
    int blk = blockIdx.x;              // 512
    int b = blk & 7, i = blk >> 3;
    int tid = threadIdx.x;
    int wv = tid >> 6, lane = tid & 63;
    int quad = lane >> 4, l15 = lane & 15;
    __shared__ __align__(16) unsigned short sA[8192];
    __shared__ __align__(16) unsigned short sB[2048];
    int pixS = tid & 63, kqS = tid >> 6;

    const unsigned short* bp = in + ((size_t)b * C_) * HW_ + i * 64 + pixS;

    f32x4 acc[4][4];
    #pragma unroll
    for (int mt = 0; mt < 4; ++mt)
        #pragma unroll
        for (int nt = 0; nt < 4; ++nt) acc[mt][nt] = (f32x4){0.f, 0.f, 0.f, 0.f};

    for (int t = 0; t < 8; ++t) {
        #pragma unroll
        for (int s = 0; s < 4; ++s)
            gl2lds16(W + ((size_t)(t * 4 + s) * 256 + tid) * 8, &sA[(s * 256 + tid) * 8]);
        {
            const unsigned short* p = bp + (size_t)(t * 32 + kqS * 8) * HW_;
            union { unsigned short h[8]; uint4 u; } hb;
            #pragma unroll
            for (int jj = 0; jj < 8; ++jj) hb.h[jj] = p[(size_t)jj * HW_];
            *(uint4*)&sB[(kqS * 64 + pixS) * 8] = hb.u;
        }
        __syncthreads();
        short8 af[4], bf[4];
        #pragma unroll
        for (int mt = 0; mt < 4; ++mt)
            af[mt] = *(const short8*)&sA[(quad * 256 + wv * 64 + mt * 16 + l15) * 8];
        #pragma unroll
        for (int nt = 0; nt < 4; ++nt)
            bf[nt] = *(const short8*)&sB[(quad * 64 + nt * 16 + l15) * 8];
        #pragma unroll
        for (int mt = 0; mt < 4; ++mt)
            #pragma unroll
            for (int nt = 0; nt < 4; ++nt)
                acc[mt][nt] = __builtin_amdgcn_mfma_f32_16x16x32_bf16(
                    af[mt], bf[nt], acc[mt][nt], 0, 0, 0);
        __syncthreads();
    }
    #pragma unroll
    for (int mt = 0; mt < 4; ++mt) {
        #pragma unroll
        for (int r = 0; r < 4; ++r) {
            int co = wv * 64 + mt * 16 + quad * 4 + r;
            float bco = bias[co];
            size_t base = ((size_t)b * C_ + co) * HW_ + i * 64;
            if (MODE == 0) {
                float sc = ss[co], sh = ss[256 + co];
                #pragma unroll
                for (int nt = 0; nt < 4; ++nt) {
                    int col = nt * 16 + l15;
                    float o = acc[mt][nt][r] + bco;
                    float u = silu_f(b2f(auxh[base + col]) * sc + sh);
                    out_bf[base + col] = f2bf(o * u);
                }
            } else {
                #pragma unroll
                for (int nt = 0; nt < 4; ++nt) {
                    int col = nt * 16 + l15;
                    out_f[base + col] = acc[mt][nt][r] + bco + auxf[base + col];
                }
            }
        }
    }
}

// ---------------- launch ----------------------------------------------------
extern "C" void kernel_launch(void* const* d_in, const int* in_sizes, int n_in,
                              void* d_out, int out_size, void* d_ws, size_t ws_size,
                              hipStream_t stream) {
    const float* x     = (const float*)d_in[0];
    const float* p_w   = (const float*)d_in[1];
    const float* p_b   = (const float*)d_in[2];
    const float* ak_w  = (const float*)d_in[3];
    const float* ak_g  = (const float*)d_in[4];
    const float* ak_b  = (const float*)d_in[5];
    const float* l0_w  = (const float*)d_in[6];
    const float* l0_b  = (const float*)d_in[7];
    const float* ls_w  = (const float*)d_in[8];
    const float* ls_b  = (const float*)d_in[9];
    const float* l1_w  = (const float*)d_in[10];
    const float* l1_b  = (const float*)d_in[11];
    const float* cv_w  = (const float*)d_in[12];
    const float* cv_b  = (const float*)d_in[13];
    float* out = (float*)d_out;

    char* w = (char*)d_ws;
    int2*   tbl_off = (int2*)w;                              // 786 KB
    float4* tbl_w   = (float4*)(w + 786432);                 // 1.5 MB
    unsigned short* wak = (unsigned short*)(w + 2359296);    // 384 KB
    unsigned short* wl1 = (unsigned short*)(w + 2752512);    // 128 KB
    unsigned short* wcv = (unsigned short*)(w + 2883584);    // 128 KB
    float* p1 = (float*)(w + 3014656);                       // 512 KB
    float* p2 = (float*)(w + 3538944);                       // 512 KB
    float* ss = (float*)(w + 4063232);                       // 2 KB
    float* pwt = (float*)(w + 4065280);                      // 72 KB
    // time-multiplexed regions:
    unsigned short* xt = (unsigned short*)(w + 4194304);     // 16 MB bf16 (dead after gather)
    unsigned short* ybh    = (unsigned short*)(w + 4194304); // 16 MB (ak writes, after gather)
    unsigned short* dw5out = (unsigned short*)(w + 20971520);// 16 MB
    float* part = (float*)(w + 37748736);                    // 6.3 MB (dead after s2)
    unsigned short* attn   = (unsigned short*)(w + 37748736);// 16 MB (dw7 out)
    unsigned short* v      = (unsigned short*)(w + 44040192);// 48 MB (dead after ak)
    unsigned short* g0out  = (unsigned short*)(w + 54525952);// 16 MB (after gemm0)

    prep_kernel<<<1352, 256, 0, stream>>>(ak_w, l1_w, cv_w, p_w, wak, wl1, wcv, pwt);
    offset_s1_kernel<<<4096, 256, 0, stream>>>(x, pwt, part);
    offset_s2_kernel<<<128, 256, 0, stream>>>(part, p_b, tbl_off, tbl_w);
    transpose_kernel<<<1024, 256, 0, stream>>>(x, xt);
    gather_kernel<<<1536, 256, 0, stream>>>(xt, tbl_off, tbl_w, v);
    ak_mfma_kernel<<<512, 256, 0, stream>>>(v, wak, ybh, p1, p2);
    bn_stats_kernel<<<256, 256, 0, stream>>>(p1, p2, ak_g, ak_b, ss);
    dw5_fused_kernel<<<2048, 256, 0, stream>>>(ybh, ss, l0_w, l0_b, dw5out);
    dw7d3_kernel<<<2048, 256, 0, stream>>>(dw5out, ls_w, ls_b, attn);
    gemm1x1_mfma<0><<<512, 256, 0, stream>>>(attn, wl1, l1_b, ybh, nullptr, ss, g0out, nullptr);
    gemm1x1_mfma<1><<<512, 256, 0, stream>>>(g0out, wcv, cv_b, nullptr, x, nullptr, nullptr, out);
}

// Round 7
// 278.050 us; speedup vs baseline: 1.2305x; 1.0497x over previous
//
#include <hip/hip_runtime.h>
#include <math.h>
#include <stdint.h>

#define B_ 8
#define C_ 256
#define HW_ 4096
#define NPIX 32768
#define NELEM (B_*C_*HW_)   // 8388608

typedef __attribute__((ext_vector_type(8))) short short8;
typedef __attribute__((ext_vector_type(4))) float f32x4;

__device__ __forceinline__ unsigned short f2bf(float f) {
    union { float f; uint32_t u; } v; v.f = f;
    uint32_t r = v.u + 0x7FFFu + ((v.u >> 16) & 1u);
    return (unsigned short)(r >> 16);
}
__device__ __forceinline__ float b2f(unsigned short h) {
    union { uint32_t u; float f; } v; v.u = ((uint32_t)h) << 16; return v.f;
}
__device__ __forceinline__ float silu_f(float v) { return v / (1.f + __expf(-v)); }

// unpack 4 bf16 (uint2) -> float4
__device__ __forceinline__ float4 up4(uint2 v) {
    float4 r;
    r.x = b2f((unsigned short)(v.x & 0xffffu));
    r.y = b2f((unsigned short)(v.x >> 16));
    r.z = b2f((unsigned short)(v.y & 0xffffu));
    r.w = b2f((unsigned short)(v.y >> 16));
    return r;
}

// async global->LDS, 16B per lane; LDS dest = wave-uniform base + lane*16.
// Src MUST be lane-contiguous (round-4 lesson: TA request count).
__device__ __forceinline__ void gl2lds16(const void* g, void* l) {
    __builtin_amdgcn_global_load_lds(
        (const __attribute__((address_space(1))) void*)g,
        (__attribute__((address_space(3))) void*)l,
        16, 0, 0);
}

// ---------------- K0: weight conversion (K-TILED layouts) + p_w transpose ---
// Tiled weight layout: Wt[((q)*256 + co)*8 + e] = W[co][k''] with k'' = q*8+e.
// A K-step (32 k) = 4 consecutive q blocks = one contiguous 16 KB chunk.
__global__ __launch_bounds__(256) void prep_kernel(
    const float* __restrict__ akw, const float* __restrict__ l1w,
    const float* __restrict__ cvw, const float* __restrict__ pw,
    unsigned short* __restrict__ wak, unsigned short* __restrict__ wl1,
    unsigned short* __restrict__ wcv, float* __restrict__ pwt)
{
    int gid = blockIdx.x * 256 + threadIdx.x;      // grid=1352
    if (gid < 196608) {
        int e = gid & 7;
        int co = (gid >> 3) & 255;
        int q = gid >> 11;            // 0..95
        int kpp = q * 8 + e;          // k'' = n*256+ci
        int n = kpp >> 8, ci = kpp & 255;
        wak[gid] = f2bf(akw[co * 768 + ci * 3 + n]);
    }
    else if (gid < 262144) {
        int g = gid - 196608;
        int e = g & 7, co = (g >> 3) & 255, q = g >> 11;   // q 0..31
        wl1[g] = f2bf(l1w[co * 256 + q * 8 + e]);
    }
    else if (gid < 327680) {
        int g = gid - 262144;
        int e = g & 7, co = (g >> 3) & 255, q = g >> 11;
        wcv[g] = f2bf(cvw[co * 256 + q * 8 + e]);
    }
    else if (gid < 346112) {
        int idx = gid - 327680;
        int ci = idx / 72, r = idx - ci * 72;
        int tt = r / 12, t9 = r - tt * 12;
        pwt[idx] = (t9 < 9) ? pw[tt * 2304 + ci * 9 + t9] : 0.f;
    }
}

// ---------------- K0b: x CHW -> HWC transpose, bf16 out (XCD-swizzled) ------
__global__ __launch_bounds__(256) void transpose_kernel(
    const float* __restrict__ x, unsigned short* __restrict__ xt)
{
    int blk = blockIdx.x;            // 1024
    int b = blk & 7;
    int rest = blk >> 3;             // 0..127
    int half = rest & 1, i = rest >> 1;
    int bi = b * 64 + i;
    int tid = threadIdx.x;
    __shared__ float tile[64 * 132];

    {
        int ci_l = tid >> 6, jj = tid & 63;
        const float* ip = x + ((size_t)b * C_ + half * 128 + ci_l) * HW_ + i * 64 + jj;
        #pragma unroll 4
        for (int it = 0; it < 32; ++it)
            tile[jj * 132 + ci_l + it * 4] = ip[(size_t)it * 4 * HW_];
    }
    __syncthreads();
    {
        int j = tid >> 2, q = tid & 3;
        unsigned short* op = xt + ((size_t)(bi * 64 + j)) * 256 + half * 128 + q * 32;
        const float* tp = &tile[j * 132 + q * 32];
        #pragma unroll
        for (int f = 0; f < 4; ++f) {
            union { unsigned short h[8]; uint4 u; } pk;
            #pragma unroll
            for (int e = 0; e < 8; ++e) pk.h[e] = f2bf(tp[f * 8 + e]);
            *(uint4*)(op + f * 8) = pk.u;
        }
    }
}

// ---------------- K1a: offset conv stage 1 (v5: register acc, small tree) ---
__global__ __launch_bounds__(256) void offset_s1_kernel(
    const float* __restrict__ x, const float* __restrict__ pwt,
    float* __restrict__ part)          // [bi*8+g][6][64]
{
    int blk = blockIdx.x;              // 4096
    int b = blk & 7;
    int rest = blk >> 3;               // 0..511
    int g = rest & 7, i = rest >> 3;
    int bi = b * 64 + i;
    int tid = threadIdx.x;

    __shared__ float tile[6600];       // x tile [(row*66+col)*33+ci]; aliased as s2[16][387]

    // ---- stage x tile (transposed, halo-padded) ----
    {
        int cs = tid >> 3, r8 = tid & 7;
        const float* xp = x + ((size_t)b * C_ + g * 32 + cs) * HW_;
        #pragma unroll
        for (int t = 0; t < 6; ++t) {
            int idx = r8 * 6 + t;
            int r = idx >> 4, v4 = idx & 15;
            int ii = i + r - 1;
            float4 val = make_float4(0.f, 0.f, 0.f, 0.f);
            if (ii >= 0 && ii < 64)
                val = *(const float4*)(xp + ii * 64 + v4 * 4);
            int base = (r * 66 + 1 + v4 * 4) * 33 + cs;
            tile[base]      = val.x;  tile[base + 33]  = val.y;
            tile[base + 66] = val.z;  tile[base + 99]  = val.w;
        }
        if (tid < 192) {
            int ci = tid / 6, rem = tid - ci * 6;
            int ki = rem >> 1, side = rem & 1;
            tile[(ki * 66 + side * 65) * 33 + ci] = 0.f;
        }
    }
    __syncthreads();

    int sub = tid >> 4;                // 0..15
    int jq  = tid & 15;                // 0..15: pixels jq*4 .. jq*4+3

    float acc[6][4];
    #pragma unroll
    for (int tt = 0; tt < 6; ++tt)
        #pragma unroll
        for (int p = 0; p < 4; ++p) acc[tt][p] = 0.f;

    #pragma unroll
    for (int t = 0; t < 2; ++t) {
        int ci = sub + 16 * t;
        float xv[3][6];                // tile cols jq*4 .. jq*4+5
        #pragma unroll
        for (int ki = 0; ki < 3; ++ki)
            #pragma unroll
            for (int cc = 0; cc < 6; ++cc)
                xv[ki][cc] = tile[(ki * 66 + jq * 4 + cc) * 33 + ci];
        const float* wp = pwt + (g * 32 + ci) * 72;
        #pragma unroll
        for (int tt = 0; tt < 6; ++tt) {
            float w[9];
            *(float4*)&w[0] = *(const float4*)(wp + tt * 12);
            *(float4*)&w[4] = *(const float4*)(wp + tt * 12 + 4);
            w[8] = wp[tt * 12 + 8];
            #pragma unroll
            for (int ki = 0; ki < 3; ++ki)
                #pragma unroll
                for (int kj = 0; kj < 3; ++kj) {
                    float wgt = w[ki * 3 + kj];
                    #pragma unroll
                    for (int p = 0; p < 4; ++p)
                        acc[tt][p] += wgt * xv[ki][kj + p];
                }
        }
    }

    // ---- 16-sub reduction via LDS tree (alias tile as s2, stride 387) ----
    __syncthreads();
    {
        float* s2 = tile + sub * 387;
        #pragma unroll
        for (int tt = 0; tt < 6; ++tt)
            #pragma unroll
            for (int p = 0; p < 4; ++p)
                s2[tt * 64 + jq * 4 + p] = acc[tt][p];
    }
    __syncthreads();
    size_t pslot = (size_t)bi * 8 + g;
    for (int idx = tid; idx < 384; idx += 256) {
        float s = 0.f;
        #pragma unroll
        for (int sb = 0; sb < 16; ++sb)
            s += tile[sb * 387 + idx];
        part[pslot * 384 + idx] = s;
    }
}

// ---------------- K1b: offset stage 2 -> paired gather tables ---------------
__global__ __launch_bounds__(256) void offset_s2_kernel(
    const float* __restrict__ part, const float* __restrict__ pb,
    int2* __restrict__ tbl_off, float4* __restrict__ tbl_w)
{
    int pix = blockIdx.x * 256 + threadIdx.x;   // grid=128
    int b = pix >> 12, rem = pix & 4095, i = rem >> 6, j = rem & 63;
    int bi = b * 64 + i;
    float v[6];
    #pragma unroll
    for (int tt = 0; tt < 6; ++tt) v[tt] = pb[tt];
    for (int g = 0; g < 8; ++g) {
        const float* pp = part + ((size_t)bi * 8 + g) * 384;
        #pragma unroll
        for (int tt = 0; tt < 6; ++tt) v[tt] += pp[tt * 64 + j];
    }
    const float pnx[3] = {0.f, 0.f, 1.f};
    const float pny[3] = {0.f, 1.f, 0.f};
    #pragma unroll
    for (int n = 0; n < 3; ++n) {
        float px_ = (float)i + pnx[n] + v[n];
        float py_ = (float)j + pny[n] + v[n + 3];
        float qx = floorf(px_), qy = floorf(py_);
        float qlx = fminf(fmaxf(qx,       0.f), 63.f);
        float qly = fminf(fmaxf(qy,       0.f), 63.f);
        float qrx = fminf(fmaxf(qx + 1.f, 0.f), 63.f);
        float qry = fminf(fmaxf(qy + 1.f, 0.f), 63.f);
        float pxc = fminf(fmaxf(px_,      0.f), 63.f);
        float pyc = fminf(fmaxf(py_,      0.f), 63.f);
        float glt = (1.f + (qlx - pxc)) * (1.f + (qly - pyc));
        float grb = (1.f - (qrx - pxc)) * (1.f - (qry - pyc));
        float glb = (1.f + (qlx - pxc)) * (1.f - (qry - pyc));
        float grt = (1.f - (qrx - pxc)) * (1.f + (qly - pyc));
        int ilx = (int)qlx, irx = (int)qrx;
        int ily = (int)qly, iry = (int)qry;
        int c0; float a0, a1, b0, b1;
        if (ily == iry) {
            if (ily == 0) { c0 = 0;  a0 = glt + glb; a1 = 0.f; b0 = grt + grb; b1 = 0.f; }
            else          { c0 = 62; a0 = 0.f; a1 = glt + glb; b0 = 0.f; b1 = grt + grb; }
        } else { c0 = ily; a0 = glt; a1 = glb; b0 = grt; b1 = grb; }
        int oi = (b * 3 + n) * HW_ + i * 64 + j;
        tbl_off[oi] = make_int2(ilx * 64 + c0, irx * 64 + c0);
        tbl_w[oi]   = make_float4(a0, a1, b0, b1);
    }
}

// ---------------- K2a: gather — bf16 xt, LDS-staged K-tiled writeback -------
// Block covers (b, n, i): produces v chunks tC = n*8 .. n*8+7 for pixel-block
// bi — exactly 32 KB. Scattered per-lane results land in LDS (K-tiled,
// padded strides); writeback is 8 x 4 KB dense lane-contiguous stores ->
// no HBM write-sector amplification (round-6 finding: 195 MB WRITE, 4x).
__global__ __launch_bounds__(256) void gather_kernel(
    const unsigned short* __restrict__ xt, const int2* __restrict__ tbl_off,
    const float4* __restrict__ tbl_w, unsigned short* __restrict__ v)
{
    int blk = blockIdx.x;          // 1536
    int b = blk & 7;
    int rest = blk >> 3;           // 0..191
    int n = rest >> 6, i = rest & 63;
    int bi = b * 64 + i;           // = pixel-block P
    int tid = threadIdx.x;
    int lane = tid & 63, wv = tid >> 6;
    int ci4 = lane * 4;
    const unsigned short* xb = xt + (size_t)b * 1048576;

    // padded K-tiled staging: [tCloc]*2080 + [kq]*520 + [j]*8 + [e] (shorts)
    // kq stride 520 (1040 B, 16B-aligned); <=4-way bank conflict on writes.
    __shared__ unsigned short stile[16640];     // 33.3 KB
    int tCloc = ci4 >> 5;                  // 0..7
    int kq = (ci4 >> 3) & 3;
    int e  = ci4 & 7;                      // 0 or 4
    unsigned short* sl = &stile[tCloc * 2080 + kq * 520 + e];

    for (int it0 = 0; it0 < 16; it0 += 4) {
        uint2 A8[4], B8[4], C8[4], D8[4];
        float4 w4[4];
        #pragma unroll
        for (int u = 0; u < 4; ++u) {
            int j = wv * 16 + it0 + u;
            int oi = (b * 3 + n) * HW_ + i * 64 + j;
            int2 off = tbl_off[oi];
            w4[u] = tbl_w[oi];
            const unsigned short* p0 = xb + (size_t)off.x * 256 + ci4;
            const unsigned short* p1 = xb + (size_t)off.y * 256 + ci4;
            A8[u] = *(const uint2*)p0;
            B8[u] = *(const uint2*)(p0 + 256);
            C8[u] = *(const uint2*)p1;
            D8[u] = *(const uint2*)(p1 + 256);
        }
        #pragma unroll
        for (int u = 0; u < 4; ++u) {
            int j = wv * 16 + it0 + u;
            float4 A = up4(A8[u]), Bv = up4(B8[u]), Cv = up4(C8[u]), Dv = up4(D8[u]);
            union { unsigned short h[4]; uint2 q; } pk;
            pk.h[0] = f2bf(w4[u].x*A.x + w4[u].y*Bv.x + w4[u].z*Cv.x + w4[u].w*Dv.x);
            pk.h[1] = f2bf(w4[u].x*A.y + w4[u].y*Bv.y + w4[u].z*Cv.y + w4[u].w*Dv.y);
            pk.h[2] = f2bf(w4[u].x*A.z + w4[u].y*Bv.z + w4[u].z*Cv.z + w4[u].w*Dv.z);
            pk.h[3] = f2bf(w4[u].x*A.w + w4[u].y*Bv.w + w4[u].z*Cv.w + w4[u].w*Dv.w);
            *(uint2*)&sl[j * 8] = pk.q;
        }
    }
    __syncthreads();
    // dense writeback: 8 chunks x 4 KB, wave writes 1 KB contiguous/instr
    unsigned short* vb = v + ((size_t)bi * 24 + n * 8) * 2048;
    int kqW = tid >> 6, jW = tid & 63;
    #pragma unroll
    for (int tc = 0; tc < 8; ++tc) {
        *(uint4*)&vb[tc * 2048 + kqW * 512 + jW * 8] =
            *(const uint4*)&stile[tc * 2080 + kqW * 520 + jW * 8];
    }
}

// ---------------- K2b: AK GEMM (bf16 MFMA, round-0 structure) ---------------
// Single-buffer 2-barrier loop; ALL staging via global_load_lds(16B) from
// K-tiled (lane-contiguous) W and v.
__global__ __launch_bounds__(256) void ak_mfma_kernel(
    const unsigned short* __restrict__ v, const unsigned short* __restrict__ W,
    unsigned short* __restrict__ yh, float* __restrict__ p1, float* __restrict__ p2)
{
    int blk = blockIdx.x;              // 512
    int b = blk & 7, i = blk >> 3;
    int P = b * 64 + i;                // pixel-block id in v layout
    int tid = threadIdx.x;
    int wv = tid >> 6, lane = tid & 63;
    int quad = lane >> 4, l15 = lane & 15;
    __shared__ __align__(16) unsigned short sA[8192];
    __shared__ __align__(16) unsigned short sB[2048];

    const unsigned short* vP = v + (size_t)P * 24 * 2048;

    f32x4 acc[4][4];
    #pragma unroll
    for (int mt = 0; mt < 4; ++mt)
        #pragma unroll
        for (int nt = 0; nt < 4; ++nt) acc[mt][nt] = (f32x4){0.f, 0.f, 0.f, 0.f};

    for (int t = 0; t < 24; ++t) {
        #pragma unroll
        for (int s = 0; s < 4; ++s)
            gl2lds16(W + ((size_t)(t * 4 + s) * 256 + tid) * 8, &sA[(s * 256 + tid) * 8]);
        gl2lds16(vP + (size_t)t * 2048 + tid * 8, &sB[tid * 8]);
        __syncthreads();
        short8 af[4], bf[4];
        #pragma unroll
        for (int mt = 0; mt < 4; ++mt)
            af[mt] = *(const short8*)&sA[(quad * 256 + wv * 64 + mt * 16 + l15) * 8];
        #pragma unroll
        for (int nt = 0; nt < 4; ++nt)
            bf[nt] = *(const short8*)&sB[(quad * 64 + nt * 16 + l15) * 8];
        #pragma unroll
        for (int mt = 0; mt < 4; ++mt)
            #pragma unroll
            for (int nt = 0; nt < 4; ++nt)
                acc[mt][nt] = __builtin_amdgcn_mfma_f32_16x16x32_bf16(
                    af[mt], bf[nt], acc[mt][nt], 0, 0, 0);
        __syncthreads();
    }
    #pragma unroll
    for (int mt = 0; mt < 4; ++mt) {
        #pragma unroll
        for (int r = 0; r < 4; ++r) {
            int co = wv * 64 + mt * 16 + quad * 4 + r;
            size_t base = ((size_t)b * C_ + co) * HW_ + i * 64;
            float s1 = 0.f, s2 = 0.f;
            #pragma unroll
            for (int nt = 0; nt < 4; ++nt) {
                float val = acc[mt][nt][r];
                s1 += val; s2 += val * val;
                yh[base + nt * 16 + l15] = f2bf(val);
            }
            #pragma unroll
            for (int m = 1; m < 16; m <<= 1) {
                s1 += __shfl_xor(s1, m); s2 += __shfl_xor(s2, m);
            }
            if (l15 == 0) { p1[co * 512 + blk] = s1; p2[co * 512 + blk] = s2; }
        }
    }
}

// ---------------- K3: BN stats from partials --------------------------------
__global__ __launch_bounds__(256) void bn_stats_kernel(
    const float* __restrict__ p1, const float* __restrict__ p2,
    const float* __restrict__ gamma, const float* __restrict__ beta,
    float* __restrict__ ss)
{
    int co = blockIdx.x, tid = threadIdx.x;     // grid=256
    float a = p1[co * 512 + tid] + p1[co * 512 + 256 + tid];
    float q = p2[co * 512 + tid] + p2[co * 512 + 256 + tid];
    __shared__ float r1[256], r2[256];
    r1[tid] = a; r2[tid] = q; __syncthreads();
    for (int st = 128; st > 0; st >>= 1) {
        if (tid < st) { r1[tid] += r1[tid + st]; r2[tid] += r2[tid + st]; }
        __syncthreads();
    }
    if (tid == 0) {
        const float inv_n = 1.f / (float)NPIX;
        float m = r1[0] * inv_n;
        float var = r2[0] * inv_n - m * m;
        float sc = gamma[co] * rsqrtf(var + 1e-5f);
        ss[co] = sc; ss[256 + co] = beta[co] - m * sc;
    }
}

// ---------------- K4: fused BN+SiLU + 5x5 depthwise (16-wide strips) --------
__global__ __launch_bounds__(256) void dw5_fused_kernel(
    const unsigned short* __restrict__ in, const float* __restrict__ ss,
    const float* __restrict__ w, const float* __restrict__ bias,
    unsigned short* __restrict__ out)
{
    int blkI = blockIdx.x;         // 2048
    int b = blkI & 7, c = blkI >> 3;
    int bc = b * 256 + c;
    int tid = threadIdx.x;
    __shared__ float tile[68 * 68];
    float sc = ss[c], sh = ss[256 + c];
    const unsigned short* ip = in + (size_t)bc * HW_;
    for (int s = tid; s < 68 * 68; s += 256) {
        int r = s / 68, cc = s - r * 68;
        int ii = r - 2, jj = cc - 2;
        float vv = 0.f;
        if (ii >= 0 && ii < 64 && jj >= 0 && jj < 64) {
            float t = b2f(ip[ii * 64 + jj]) * sc + sh;
            vv = silu_f(t);
        }
        tile[s] = vv;
    }
    float wr[25];
    #pragma unroll
    for (int t = 0; t < 25; ++t) wr[t] = w[c * 25 + t];
    float bv = bias[c];
    __syncthreads();

    int jb = tid & 3, row = tid >> 2;     // 16-col strip, one output row
    int j0 = jb * 16;
    float acc[16];
    #pragma unroll
    for (int j = 0; j < 16; ++j) acc[j] = bv;
    #pragma unroll
    for (int di = 0; di < 5; ++di) {
        const float* tp = &tile[(row + di) * 68 + j0];
        float vv[20];
        #pragma unroll
        for (int q = 0; q < 5; ++q)
            *(float4*)&vv[q * 4] = *(const float4*)(tp + q * 4);
        #pragma unroll
        for (int dj = 0; dj < 5; ++dj) {
            float wv = wr[di * 5 + dj];
            #pragma unroll
            for (int j = 0; j < 16; ++j)
                acc[j] += wv * vv[dj + j];
        }
    }
    unsigned short* op = out + (size_t)bc * HW_ + row * 64 + j0;
    union { unsigned short h[8]; uint4 u; } pk;
    #pragma unroll
    for (int half = 0; half < 2; ++half) {
        #pragma unroll
        for (int j = 0; j < 8; ++j) pk.h[j] = f2bf(acc[half * 8 + j]);
        *(uint4*)&op[half * 8] = pk.u;
    }
}

// ---------------- K5: 7x7 dilated(3) depthwise (16-wide strips) -------------
__global__ __launch_bounds__(256) void dw7d3_kernel(
    const unsigned short* __restrict__ in, const float* __restrict__ w,
    const float* __restrict__ bias, unsigned short* __restrict__ out)
{
    int blkI = blockIdx.x;         // 2048
    int b = blkI & 7, c = blkI >> 3;
    int bc = b * 256 + c;
    int tid = threadIdx.x;
    __shared__ float tile[82 * 84];
    const unsigned short* ip = in + (size_t)bc * HW_;
    for (int s = tid; s < 82 * 84; s += 256) {
        int r = s / 84, cc = s - r * 84;
        int ii = r - 9, jj = cc - 9;
        float vv = 0.f;
        if (ii >= 0 && ii < 64 && jj >= 0 && jj < 64) vv = b2f(ip[ii * 64 + jj]);
        tile[s] = vv;
    }
    float wr[49];
    #pragma unroll
    for (int t = 0; t < 49; ++t) wr[t] = w[c * 49 + t];
    float bv = bias[c];
    __syncthreads();

    int jb = tid & 3, row = tid >> 2;     // 16-col strip, one output row
    int j0 = jb * 16;
    float acc[16];
    #pragma unroll
    for (int j = 0; j < 16; ++j) acc[j] = bv;
    #pragma unroll
    for (int di = 0; di < 7; ++di) {
        const float* tp = &tile[(row + 3 * di) * 84 + j0];
        float vv[36];                 // cols j0 .. j0+35 (<= 83, fits row)
        #pragma unroll
        for (int q = 0; q < 9; ++q)
            *(float4*)&vv[q * 4] = *(const float4*)(tp + q * 4);
        #pragma unroll
        for (int dj = 0; dj < 7; ++dj) {
            float wv = wr[di * 7 + dj];
            #pragma unroll
            for (int j = 0; j < 16; ++j)
                acc[j] += wv * vv[3 * dj + j];
        }
    }
    unsigned short* op = out + (size_t)bc * HW_ + row * 64 + j0;
    union { unsigned short h[8]; uint4 u; } pk;
    #pragma unroll
    for (int half = 0; half < 2; ++half) {
        #pragma unroll
        for (int j = 0; j < 8; ++j) pk.h[j] = f2bf(acc[half * 8 + j]);
        *(uint4*)&op[half * 8] = pk.u;
    }
}

// ---------------- K6/K7: 1x1 conv bf16 MFMA GEMM (round-0 structure) --------
template<int MODE>
__global__ __launch_bounds__(256) void gemm1x1_mfma(
    const unsigned short* __restrict__ in, const unsigned short* __restrict__ W,
    const float* __restrict__ bias,
    const unsigned short* __restrict__ auxh, const float* __restrict__ auxf,
    const float* __restrict__ ss,
    unsigned short* __restrict__ out_bf, float* __restrict__ out_f)
{
    int blk = blockIdx.x;              // 512
    int b = blk & 7, i = blk >> 3;
    int tid = threadIdx.x;
    int wv = tid >> 6, lane = tid & 63;
    int quad = lane >> 4, l15 = lane & 15;
    __shared__ __align__(16) unsigned short sA[8192];
    __shared__ __align__(16) unsigned short sB[2048];
    int pixS = tid & 63, kqS = tid >> 6;

    const unsigned short* bp = in + ((size_t)b * C_) * HW_ + i * 64 + pixS;

    f32x4 acc[4][4];
    #pragma unroll
    for (int mt = 0; mt < 4; ++mt)
        #pragma unroll
        for (int nt = 0; nt < 4; ++nt) acc[mt][nt] = (f32x4){0.f, 0.f, 0.f, 0.f};

    for (int t = 0; t < 8; ++t) {
        #pragma unroll
        for (int s = 0; s < 4; ++s)
            gl2lds16(W + ((size_t)(t * 4 + s) * 256 + tid) * 8, &sA[(s * 256 + tid) * 8]);
        {
            const unsigned short* p = bp + (size_t)(t * 32 + kqS * 8) * HW_;
            union { unsigned short h[8]; uint4 u; } hb;
            #pragma unroll
            for (int jj = 0; jj < 8; ++jj) hb.h[jj] = p[(size_t)jj * HW_];
            *(uint4*)&sB[(kqS * 64 + pixS) * 8] = hb.u;
        }
        __syncthreads();
        short8 af[4], bf[4];
        #pragma unroll
        for (int mt = 0; mt < 4; ++mt)
            af[mt] = *(const short8*)&sA[(quad * 256 + wv * 64 + mt * 16 + l15) * 8];
        #pragma unroll
        for (int nt = 0; nt < 4; ++nt)
            bf[nt] = *(const short8*)&sB[(quad * 64 + nt * 16 + l15) * 8];
        #pragma unroll
        for (int mt = 0; mt < 4; ++mt)
            #pragma unroll
            for (int nt = 0; nt < 4; ++nt)
                acc[mt][nt] = __builtin_amdgcn_mfma_f32_16x16x32_bf16(
                    af[mt], bf[nt], acc[mt][nt], 0, 0, 0);
        __syncthreads();
    }
    #pragma unroll
    for (int mt = 0; mt < 4; ++mt) {
        #pragma unroll
        for (int r = 0; r < 4; ++r) {
            int co = wv * 64 + mt * 16 + quad * 4 + r;
            float bco = bias[co];
            size_t base = ((size_t)b * C_ + co) * HW_ + i * 64;
            if (MODE == 0) {
                float sc = ss[co], sh = ss[256 + co];
                #pragma unroll
                for (int nt = 0; nt < 4; ++nt) {
                    int col = nt * 16 + l15;
                    float o = acc[mt][nt][r] + bco;
                    float u = silu_f(b2f(auxh[base + col]) * sc + sh);
                    out_bf[base + col] = f2bf(o * u);
                }
            } else {
                #pragma unroll
                for (int nt = 0; nt < 4; ++nt) {
                    int col = nt * 16 + l15;
                    out_f[base + col] = acc[mt][nt][r] + bco + auxf[base + col];
                }
            }
        }
    }
}

// ---------------- launch ----------------------------------------------------
extern "C" void kernel_launch(void* const* d_in, const int* in_sizes, int n_in,
                              void* d_out, int out_size, void* d_ws, size_t ws_size,
                              hipStream_t stream) {
    const float* x     = (const float*)d_in[0];
    const float* p_w   = (const float*)d_in[1];
    const float* p_b   = (const float*)d_in[2];
    const float* ak_w  = (const float*)d_in[3];
    const float* ak_g  = (const float*)d_in[4];
    const float* ak_b  = (const float*)d_in[5];
    const float* l0_w  = (const float*)d_in[6];
    const float* l0_b  = (const float*)d_in[7];
    const float* ls_w  = (const float*)d_in[8];
    const float* ls_b  = (const float*)d_in[9];
    const float* l1_w  = (const float*)d_in[10];
    const float* l1_b  = (const float*)d_in[11];
    const float* cv_w  = (const float*)d_in[12];
    const float* cv_b  = (const float*)d_in[13];
    float* out = (float*)d_out;

    char* w = (char*)d_ws;
    int2*   tbl_off = (int2*)w;                              // 786 KB
    float4* tbl_w   = (float4*)(w + 786432);                 // 1.5 MB
    unsigned short* wak = (unsigned short*)(w + 2359296);    // 384 KB
    unsigned short* wl1 = (unsigned short*)(w + 2752512);    // 128 KB
    unsigned short* wcv = (unsigned short*)(w + 2883584);    // 128 KB
    float* p1 = (float*)(w + 3014656);                       // 512 KB
    float* p2 = (float*)(w + 3538944);                       // 512 KB
    float* ss = (float*)(w + 4063232);                       // 2 KB
    float* pwt = (float*)(w + 4065280);                      // 72 KB
    // time-multiplexed regions:
    unsigned short* xt = (unsigned short*)(w + 4194304);     // 16 MB bf16 (dead after gather)
    unsigned short* ybh    = (unsigned short*)(w + 4194304); // 16 MB (ak writes, after gather)
    unsigned short* dw5out = (unsigned short*)(w + 20971520);// 16 MB
    float* part = (float*)(w + 37748736);                    // 6.3 MB (dead after s2)
    unsigned short* attn   = (unsigned short*)(w + 37748736);// 16 MB (dw7 out)
    unsigned short* v      = (unsigned short*)(w + 44040192);// 48 MB (dead after ak)
    unsigned short* g0out  = (unsigned short*)(w + 54525952);// 16 MB (after gemm0)

    prep_kernel<<<1352, 256, 0, stream>>>(ak_w, l1_w, cv_w, p_w, wak, wl1, wcv, pwt);
    offset_s1_kernel<<<4096, 256, 0, stream>>>(x, pwt, part);
    offset_s2_kernel<<<128, 256, 0, stream>>>(part, p_b, tbl_off, tbl_w);
    transpose_kernel<<<1024, 256, 0, stream>>>(x, xt);
    gather_kernel<<<1536, 256, 0, stream>>>(xt, tbl_off, tbl_w, v);
    ak_mfma_kernel<<<512, 256, 0, stream>>>(v, wak, ybh, p1, p2);
    bn_stats_kernel<<<256, 256, 0, stream>>>(p1, p2, ak_g, ak_b, ss);
    dw5_fused_kernel<<<2048, 256, 0, stream>>>(ybh, ss, l0_w, l0_b, dw5out);
    dw7d3_kernel<<<2048, 256, 0, stream>>>(dw5out, ls_w, ls_b, attn);
    gemm1x1_mfma<0><<<512, 256, 0, stream>>>(attn, wl1, l1_b, ybh, nullptr, ss, g0out, nullptr);
    gemm1x1_mfma<1><<<512, 256, 0, stream>>>(g0out, wcv, cv_b, nullptr, x, nullptr, nullptr, out);
}

// Round 8
// 271.500 us; speedup vs baseline: 1.2602x; 1.0241x over previous
//
#include <hip/hip_runtime.h>
#include <math.h>
#include <stdint.h>

#define B_ 8
#define C_ 256
#define HW_ 4096
#define NPIX 32768
#define NELEM (B_*C_*HW_)   // 8388608

typedef __attribute__((ext_vector_type(8))) short short8;
typedef __attribute__((ext_vector_type(4))) float f32x4;

__device__ __forceinline__ unsigned short f2bf(float f) {
    union { float f; uint32_t u; } v; v.f = f;
    uint32_t r = v.u + 0x7FFFu + ((v.u >> 16) & 1u);
    return (unsigned short)(r >> 16);
}
__device__ __forceinline__ float b2f(unsigned short h) {
    union { uint32_t u; float f; } v; v.u = ((uint32_t)h) << 16; return v.f;
}
__device__ __forceinline__ float silu_f(float v) { return v / (1.f + __expf(-v)); }

// unpack 4 bf16 (uint2) -> float4
__device__ __forceinline__ float4 up4(uint2 v) {
    float4 r;
    r.x = b2f((unsigned short)(v.x & 0xffffu));
    r.y = b2f((unsigned short)(v.x >> 16));
    r.z = b2f((unsigned short)(v.y & 0xffffu));
    r.w = b2f((unsigned short)(v.y >> 16));
    return r;
}

// async global->LDS, 16B per lane; LDS dest = wave-uniform base + lane*16.
// Src MUST be lane-contiguous (round-4 lesson: TA request count).
__device__ __forceinline__ void gl2lds16(const void* g, void* l) {
    __builtin_amdgcn_global_load_lds(
        (const __attribute__((address_space(1))) void*)g,
        (__attribute__((address_space(3))) void*)l,
        16, 0, 0);
}

// ---------------- K0: weight conversion (K-TILED layouts) + p_w transpose ---
__global__ __launch_bounds__(256) void prep_kernel(
    const float* __restrict__ akw, const float* __restrict__ l1w,
    const float* __restrict__ cvw, const float* __restrict__ pw,
    unsigned short* __restrict__ wak, unsigned short* __restrict__ wl1,
    unsigned short* __restrict__ wcv, float* __restrict__ pwt)
{
    int gid = blockIdx.x * 256 + threadIdx.x;      // grid=1352
    if (gid < 196608) {
        int e = gid & 7;
        int co = (gid >> 3) & 255;
        int q = gid >> 11;            // 0..95
        int kpp = q * 8 + e;          // k'' = n*256+ci
        int n = kpp >> 8, ci = kpp & 255;
        wak[gid] = f2bf(akw[co * 768 + ci * 3 + n]);
    }
    else if (gid < 262144) {
        int g = gid - 196608;
        int e = g & 7, co = (g >> 3) & 255, q = g >> 11;   // q 0..31
        wl1[g] = f2bf(l1w[co * 256 + q * 8 + e]);
    }
    else if (gid < 327680) {
        int g = gid - 262144;
        int e = g & 7, co = (g >> 3) & 255, q = g >> 11;
        wcv[g] = f2bf(cvw[co * 256 + q * 8 + e]);
    }
    else if (gid < 346112) {
        int idx = gid - 327680;
        int ci = idx / 72, r = idx - ci * 72;
        int tt = r / 12, t9 = r - tt * 12;
        pwt[idx] = (t9 < 9) ? pw[tt * 2304 + ci * 9 + t9] : 0.f;
    }
}

// ---------------- K0b: x CHW -> HWC transpose, bf16 out (XCD-swizzled) ------
__global__ __launch_bounds__(256) void transpose_kernel(
    const float* __restrict__ x, unsigned short* __restrict__ xt)
{
    int blk = blockIdx.x;            // 1024
    int b = blk & 7;
    int rest = blk >> 3;             // 0..127
    int half = rest & 1, i = rest >> 1;
    int bi = b * 64 + i;
    int tid = threadIdx.x;
    __shared__ float tile[64 * 132];

    {
        int ci_l = tid >> 6, jj = tid & 63;
        const float* ip = x + ((size_t)b * C_ + half * 128 + ci_l) * HW_ + i * 64 + jj;
        #pragma unroll 4
        for (int it = 0; it < 32; ++it)
            tile[jj * 132 + ci_l + it * 4] = ip[(size_t)it * 4 * HW_];
    }
    __syncthreads();
    {
        int j = tid >> 2, q = tid & 3;
        unsigned short* op = xt + ((size_t)(bi * 64 + j)) * 256 + half * 128 + q * 32;
        const float* tp = &tile[j * 132 + q * 32];
        #pragma unroll
        for (int f = 0; f < 4; ++f) {
            union { unsigned short h[8]; uint4 u; } pk;
            #pragma unroll
            for (int e = 0; e < 8; ++e) pk.h[e] = f2bf(tp[f * 8 + e]);
            *(uint4*)(op + f * 8) = pk.u;
        }
    }
}

// ---------------- K1a: offset conv stage 1 (v5: register acc, small tree) ---
__global__ __launch_bounds__(256) void offset_s1_kernel(
    const float* __restrict__ x, const float* __restrict__ pwt,
    float* __restrict__ part)          // [bi*8+g][6][64]
{
    int blk = blockIdx.x;              // 4096
    int b = blk & 7;
    int rest = blk >> 3;               // 0..511
    int g = rest & 7, i = rest >> 3;
    int bi = b * 64 + i;
    int tid = threadIdx.x;

    __shared__ float tile[6600];       // x tile [(row*66+col)*33+ci]; aliased as s2[16][387]

    // ---- stage x tile (transposed, halo-padded) ----
    {
        int cs = tid >> 3, r8 = tid & 7;
        const float* xp = x + ((size_t)b * C_ + g * 32 + cs) * HW_;
        #pragma unroll
        for (int t = 0; t < 6; ++t) {
            int idx = r8 * 6 + t;
            int r = idx >> 4, v4 = idx & 15;
            int ii = i + r - 1;
            float4 val = make_float4(0.f, 0.f, 0.f, 0.f);
            if (ii >= 0 && ii < 64)
                val = *(const float4*)(xp + ii * 64 + v4 * 4);
            int base = (r * 66 + 1 + v4 * 4) * 33 + cs;
            tile[base]      = val.x;  tile[base + 33]  = val.y;
            tile[base + 66] = val.z;  tile[base + 99]  = val.w;
        }
        if (tid < 192) {
            int ci = tid / 6, rem = tid - ci * 6;
            int ki = rem >> 1, side = rem & 1;
            tile[(ki * 66 + side * 65) * 33 + ci] = 0.f;
        }
    }
    __syncthreads();

    int sub = tid >> 4;                // 0..15
    int jq  = tid & 15;                // 0..15: pixels jq*4 .. jq*4+3

    float acc[6][4];
    #pragma unroll
    for (int tt = 0; tt < 6; ++tt)
        #pragma unroll
        for (int p = 0; p < 4; ++p) acc[tt][p] = 0.f;

    #pragma unroll
    for (int t = 0; t < 2; ++t) {
        int ci = sub + 16 * t;
        float xv[3][6];                // tile cols jq*4 .. jq*4+5
        #pragma unroll
        for (int ki = 0; ki < 3; ++ki)
            #pragma unroll
            for (int cc = 0; cc < 6; ++cc)
                xv[ki][cc] = tile[(ki * 66 + jq * 4 + cc) * 33 + ci];
        const float* wp = pwt + (g * 32 + ci) * 72;
        #pragma unroll
        for (int tt = 0; tt < 6; ++tt) {
            float w[9];
            *(float4*)&w[0] = *(const float4*)(wp + tt * 12);
            *(float4*)&w[4] = *(const float4*)(wp + tt * 12 + 4);
            w[8] = wp[tt * 12 + 8];
            #pragma unroll
            for (int ki = 0; ki < 3; ++ki)
                #pragma unroll
                for (int kj = 0; kj < 3; ++kj) {
                    float wgt = w[ki * 3 + kj];
                    #pragma unroll
                    for (int p = 0; p < 4; ++p)
                        acc[tt][p] += wgt * xv[ki][kj + p];
                }
        }
    }

    // ---- 16-sub reduction via LDS tree (alias tile as s2, stride 387) ----
    __syncthreads();
    {
        float* s2 = tile + sub * 387;
        #pragma unroll
        for (int tt = 0; tt < 6; ++tt)
            #pragma unroll
            for (int p = 0; p < 4; ++p)
                s2[tt * 64 + jq * 4 + p] = acc[tt][p];
    }
    __syncthreads();
    size_t pslot = (size_t)bi * 8 + g;
    for (int idx = tid; idx < 384; idx += 256) {
        float s = 0.f;
        #pragma unroll
        for (int sb = 0; sb < 16; ++sb)
            s += tile[sb * 387 + idx];
        part[pslot * 384 + idx] = s;
    }
}

// ---------------- K1b: offset stage 2 -> paired gather tables ---------------
__global__ __launch_bounds__(256) void offset_s2_kernel(
    const float* __restrict__ part, const float* __restrict__ pb,
    int2* __restrict__ tbl_off, float4* __restrict__ tbl_w)
{
    int pix = blockIdx.x * 256 + threadIdx.x;   // grid=128
    int b = pix >> 12, rem = pix & 4095, i = rem >> 6, j = rem & 63;
    int bi = b * 64 + i;
    float v[6];
    #pragma unroll
    for (int tt = 0; tt < 6; ++tt) v[tt] = pb[tt];
    for (int g = 0; g < 8; ++g) {
        const float* pp = part + ((size_t)bi * 8 + g) * 384;
        #pragma unroll
        for (int tt = 0; tt < 6; ++tt) v[tt] += pp[tt * 64 + j];
    }
    const float pnx[3] = {0.f, 0.f, 1.f};
    const float pny[3] = {0.f, 1.f, 0.f};
    #pragma unroll
    for (int n = 0; n < 3; ++n) {
        float px_ = (float)i + pnx[n] + v[n];
        float py_ = (float)j + pny[n] + v[n + 3];
        float qx = floorf(px_), qy = floorf(py_);
        float qlx = fminf(fmaxf(qx,       0.f), 63.f);
        float qly = fminf(fmaxf(qy,       0.f), 63.f);
        float qrx = fminf(fmaxf(qx + 1.f, 0.f), 63.f);
        float qry = fminf(fmaxf(qy + 1.f, 0.f), 63.f);
        float pxc = fminf(fmaxf(px_,      0.f), 63.f);
        float pyc = fminf(fmaxf(py_,      0.f), 63.f);
        float glt = (1.f + (qlx - pxc)) * (1.f + (qly - pyc));
        float grb = (1.f - (qrx - pxc)) * (1.f - (qry - pyc));
        float glb = (1.f + (qlx - pxc)) * (1.f - (qry - pyc));
        float grt = (1.f - (qrx - pxc)) * (1.f + (qly - pyc));
        int ilx = (int)qlx, irx = (int)qrx;
        int ily = (int)qly, iry = (int)qry;
        int c0; float a0, a1, b0, b1;
        if (ily == iry) {
            if (ily == 0) { c0 = 0;  a0 = glt + glb; a1 = 0.f; b0 = grt + grb; b1 = 0.f; }
            else          { c0 = 62; a0 = 0.f; a1 = glt + glb; b0 = 0.f; b1 = grt + grb; }
        } else { c0 = ily; a0 = glt; a1 = glb; b0 = grt; b1 = grb; }
        int oi = (b * 3 + n) * HW_ + i * 64 + j;
        tbl_off[oi] = make_int2(ilx * 64 + c0, irx * 64 + c0);
        tbl_w[oi]   = make_float4(a0, a1, b0, b1);
    }
}

// ---------------- K2a: gather — bf16 xt, LDS-staged K-tiled writeback -------
__global__ __launch_bounds__(256) void gather_kernel(
    const unsigned short* __restrict__ xt, const int2* __restrict__ tbl_off,
    const float4* __restrict__ tbl_w, unsigned short* __restrict__ v)
{
    int blk = blockIdx.x;          // 1536
    int b = blk & 7;
    int rest = blk >> 3;           // 0..191
    int n = rest >> 6, i = rest & 63;
    int bi = b * 64 + i;           // = pixel-block P
    int tid = threadIdx.x;
    int lane = tid & 63, wv = tid >> 6;
    int ci4 = lane * 4;
    const unsigned short* xb = xt + (size_t)b * 1048576;

    __shared__ unsigned short stile[16640];     // 33.3 KB, padded K-tiled
    int tCloc = ci4 >> 5;                  // 0..7
    int kq = (ci4 >> 3) & 3;
    int e  = ci4 & 7;                      // 0 or 4
    unsigned short* sl = &stile[tCloc * 2080 + kq * 520 + e];

    for (int it0 = 0; it0 < 16; it0 += 4) {
        uint2 A8[4], B8[4], C8[4], D8[4];
        float4 w4[4];
        #pragma unroll
        for (int u = 0; u < 4; ++u) {
            int j = wv * 16 + it0 + u;
            int oi = (b * 3 + n) * HW_ + i * 64 + j;
            int2 off = tbl_off[oi];
            w4[u] = tbl_w[oi];
            const unsigned short* p0 = xb + (size_t)off.x * 256 + ci4;
            const unsigned short* p1 = xb + (size_t)off.y * 256 + ci4;
            A8[u] = *(const uint2*)p0;
            B8[u] = *(const uint2*)(p0 + 256);
            C8[u] = *(const uint2*)p1;
            D8[u] = *(const uint2*)(p1 + 256);
        }
        #pragma unroll
        for (int u = 0; u < 4; ++u) {
            int j = wv * 16 + it0 + u;
            float4 A = up4(A8[u]), Bv = up4(B8[u]), Cv = up4(C8[u]), Dv = up4(D8[u]);
            union { unsigned short h[4]; uint2 q; } pk;
            pk.h[0] = f2bf(w4[u].x*A.x + w4[u].y*Bv.x + w4[u].z*Cv.x + w4[u].w*Dv.x);
            pk.h[1] = f2bf(w4[u].x*A.y + w4[u].y*Bv.y + w4[u].z*Cv.y + w4[u].w*Dv.y);
            pk.h[2] = f2bf(w4[u].x*A.z + w4[u].y*Bv.z + w4[u].z*Cv.z + w4[u].w*Dv.z);
            pk.h[3] = f2bf(w4[u].x*A.w + w4[u].y*Bv.w + w4[u].z*Cv.w + w4[u].w*Dv.w);
            *(uint2*)&sl[j * 8] = pk.q;
        }
    }
    __syncthreads();
    // dense writeback: 8 chunks x 4 KB, wave writes 1 KB contiguous/instr
    unsigned short* vb = v + ((size_t)bi * 24 + n * 8) * 2048;
    int kqW = tid >> 6, jW = tid & 63;
    #pragma unroll
    for (int tc = 0; tc < 8; ++tc) {
        *(uint4*)&vb[tc * 2048 + kqW * 512 + jW * 8] =
            *(const uint4*)&stile[tc * 2080 + kqW * 520 + jW * 8];
    }
}

// ---------------- K2b: AK GEMM (bf16 MFMA, round-0 structure) ---------------
__global__ __launch_bounds__(256) void ak_mfma_kernel(
    const unsigned short* __restrict__ v, const unsigned short* __restrict__ W,
    unsigned short* __restrict__ yh, float* __restrict__ p1, float* __restrict__ p2)
{
    int blk = blockIdx.x;              // 512
    int b = blk & 7, i = blk >> 3;
    int P = b * 64 + i;                // pixel-block id in v layout
    int tid = threadIdx.x;
    int wv = tid >> 6, lane = tid & 63;
    int quad = lane >> 4, l15 = lane & 15;
    __shared__ __align__(16) unsigned short sA[8192];
    __shared__ __align__(16) unsigned short sB[2048];

    const unsigned short* vP = v + (size_t)P * 24 * 2048;

    f32x4 acc[4][4];
    #pragma unroll
    for (int mt = 0; mt < 4; ++mt)
        #pragma unroll
        for (int nt = 0; nt < 4; ++nt) acc[mt][nt] = (f32x4){0.f, 0.f, 0.f, 0.f};

    for (int t = 0; t < 24; ++t) {
        #pragma unroll
        for (int s = 0; s < 4; ++s)
            gl2lds16(W + ((size_t)(t * 4 + s) * 256 + tid) * 8, &sA[(s * 256 + tid) * 8]);
        gl2lds16(vP + (size_t)t * 2048 + tid * 8, &sB[tid * 8]);
        __syncthreads();
        short8 af[4], bf[4];
        #pragma unroll
        for (int mt = 0; mt < 4; ++mt)
            af[mt] = *(const short8*)&sA[(quad * 256 + wv * 64 + mt * 16 + l15) * 8];
        #pragma unroll
        for (int nt = 0; nt < 4; ++nt)
            bf[nt] = *(const short8*)&sB[(quad * 64 + nt * 16 + l15) * 8];
        #pragma unroll
        for (int mt = 0; mt < 4; ++mt)
            #pragma unroll
            for (int nt = 0; nt < 4; ++nt)
                acc[mt][nt] = __builtin_amdgcn_mfma_f32_16x16x32_bf16(
                    af[mt], bf[nt], acc[mt][nt], 0, 0, 0);
        __syncthreads();
    }
    #pragma unroll
    for (int mt = 0; mt < 4; ++mt) {
        #pragma unroll
        for (int r = 0; r < 4; ++r) {
            int co = wv * 64 + mt * 16 + quad * 4 + r;
            size_t base = ((size_t)b * C_ + co) * HW_ + i * 64;
            float s1 = 0.f, s2 = 0.f;
            #pragma unroll
            for (int nt = 0; nt < 4; ++nt) {
                float val = acc[mt][nt][r];
                s1 += val; s2 += val * val;
                yh[base + nt * 16 + l15] = f2bf(val);
            }
            #pragma unroll
            for (int m = 1; m < 16; m <<= 1) {
                s1 += __shfl_xor(s1, m); s2 += __shfl_xor(s2, m);
            }
            if (l15 == 0) { p1[co * 512 + blk] = s1; p2[co * 512 + blk] = s2; }
        }
    }
}

// ---------------- K3: BN stats from partials --------------------------------
__global__ __launch_bounds__(256) void bn_stats_kernel(
    const float* __restrict__ p1, const float* __restrict__ p2,
    const float* __restrict__ gamma, const float* __restrict__ beta,
    float* __restrict__ ss)
{
    int co = blockIdx.x, tid = threadIdx.x;     // grid=256
    float a = p1[co * 512 + tid] + p1[co * 512 + 256 + tid];
    float q = p2[co * 512 + tid] + p2[co * 512 + 256 + tid];
    __shared__ float r1[256], r2[256];
    r1[tid] = a; r2[tid] = q; __syncthreads();
    for (int st = 128; st > 0; st >>= 1) {
        if (tid < st) { r1[tid] += r1[tid + st]; r2[tid] += r2[tid + st]; }
        __syncthreads();
    }
    if (tid == 0) {
        const float inv_n = 1.f / (float)NPIX;
        float m = r1[0] * inv_n;
        float var = r2[0] * inv_n - m * m;
        float sc = gamma[co] * rsqrtf(var + 1e-5f);
        ss[co] = sc; ss[256 + co] = beta[co] - m * sc;
    }
}

// ---------------- K4: FUSED BN+SiLU + dw5 + dw7d3 (LDS intermediate) --------
// dw5 output plane == dw7 input plane (same (b,c), zero halo). Compute dw5
// into t2 (82x84, zero-bordered) and run dw7 from LDS: saves the 16 MB
// dw5out write + 16 MB read + one launch.
__global__ __launch_bounds__(256) void dw_fused_kernel(
    const unsigned short* __restrict__ in, const float* __restrict__ ss,
    const float* __restrict__ w5, const float* __restrict__ b5,
    const float* __restrict__ w7, const float* __restrict__ b7,
    unsigned short* __restrict__ out)
{
    int blkI = blockIdx.x;         // 2048
    int b = blkI & 7, c = blkI >> 3;
    int bc = b * 256 + c;
    int tid = threadIdx.x;
    __shared__ float t1[68 * 68];      // dw5 input (BN+SiLU), halo 2
    __shared__ float t2[82 * 84];      // dw7 input = dw5 output, halo 9

    // zero t2 (border must be 0; interior overwritten by dw5)
    for (int s = tid; s < 82 * 84; s += 256) t2[s] = 0.f;

    float sc = ss[c], sh = ss[256 + c];
    const unsigned short* ip = in + (size_t)bc * HW_;
    for (int s = tid; s < 68 * 68; s += 256) {
        int r = s / 68, cc = s - r * 68;
        int ii = r - 2, jj = cc - 2;
        float vv = 0.f;
        if (ii >= 0 && ii < 64 && jj >= 0 && jj < 64) {
            float t = b2f(ip[ii * 64 + jj]) * sc + sh;
            vv = silu_f(t);
        }
        t1[s] = vv;
    }
    __syncthreads();

    int jb = tid & 3, row = tid >> 2;     // 16-col strip, one output row
    int j0 = jb * 16;
    {   // ---- dw5 phase: write into t2 interior at (+9,+9) ----
        float wr[25];
        #pragma unroll
        for (int t = 0; t < 25; ++t) wr[t] = w5[c * 25 + t];
        float bv = b5[c];
        float acc[16];
        #pragma unroll
        for (int j = 0; j < 16; ++j) acc[j] = bv;
        #pragma unroll
        for (int di = 0; di < 5; ++di) {
            const float* tp = &t1[(row + di) * 68 + j0];
            float vv[20];
            #pragma unroll
            for (int q = 0; q < 5; ++q)
                *(float4*)&vv[q * 4] = *(const float4*)(tp + q * 4);
            #pragma unroll
            for (int dj = 0; dj < 5; ++dj) {
                float wv = wr[di * 5 + dj];
                #pragma unroll
                for (int j = 0; j < 16; ++j)
                    acc[j] += wv * vv[dj + j];
            }
        }
        float* t2w = &t2[(row + 9) * 84 + 9 + j0];
        #pragma unroll
        for (int j = 0; j < 16; ++j) t2w[j] = acc[j];   // scalar (base +9 unaligned)
    }
    __syncthreads();
    {   // ---- dw7 phase (dilation 3) from t2 ----
        float wr[49];
        #pragma unroll
        for (int t = 0; t < 49; ++t) wr[t] = w7[c * 49 + t];
        float bv = b7[c];
        float acc[16];
        #pragma unroll
        for (int j = 0; j < 16; ++j) acc[j] = bv;
        #pragma unroll
        for (int di = 0; di < 7; ++di) {
            const float* tp = &t2[(row + 3 * di) * 84 + j0];
            float vv[36];
            #pragma unroll
            for (int q = 0; q < 9; ++q)
                *(float4*)&vv[q * 4] = *(const float4*)(tp + q * 4);
            #pragma unroll
            for (int dj = 0; dj < 7; ++dj) {
                float wv = wr[di * 7 + dj];
                #pragma unroll
                for (int j = 0; j < 16; ++j)
                    acc[j] += wv * vv[3 * dj + j];
            }
        }
        unsigned short* op = out + (size_t)bc * HW_ + row * 64 + j0;
        union { unsigned short h[8]; uint4 u; } pk;
        #pragma unroll
        for (int half = 0; half < 2; ++half) {
            #pragma unroll
            for (int j = 0; j < 8; ++j) pk.h[j] = f2bf(acc[half * 8 + j]);
            *(uint4*)&op[half * 8] = pk.u;
        }
    }
}

// ---------------- K6: FUSED gemm0(silu-gate) + gemm1(+residual) -------------
// Block (b,i) produces all 256 co of gemm0 == gemm1's full B-tile for the
// same pixels. Intermediate lives in LDS in the K-tiled sB fragment layout
// (conflict-free read proven by ak: SQ_LDS_BANK_CONFLICT=0). Phase 2 has
// no B staging. Saves 16 MB write + 16 MB read + one launch.
__global__ __launch_bounds__(256) void gemm_fused_kernel(
    const unsigned short* __restrict__ in,   // attn (CHW bf16)
    const unsigned short* __restrict__ W0, const float* __restrict__ bias0,
    const unsigned short* __restrict__ W1, const float* __restrict__ bias1,
    const unsigned short* __restrict__ auxh, const float* __restrict__ ss,
    const float* __restrict__ auxf, float* __restrict__ out_f)
{
    int blk = blockIdx.x;              // 512
    int b = blk & 7, i = blk >> 3;
    int tid = threadIdx.x;
    int wv = tid >> 6, lane = tid & 63;
    int quad = lane >> 4, l15 = lane & 15;
    __shared__ __align__(16) unsigned short sA[8192];    // 16 KB
    __shared__ __align__(16) unsigned short sB[2048];    //  4 KB
    __shared__ __align__(16) unsigned short mid[16384];  // 32 KB K-tiled interm.
    int pixS = tid & 63, kqS = tid >> 6;

    const unsigned short* bp = in + ((size_t)b * C_) * HW_ + i * 64 + pixS;

    f32x4 acc[4][4];
    #pragma unroll
    for (int mt = 0; mt < 4; ++mt)
        #pragma unroll
        for (int nt = 0; nt < 4; ++nt) acc[mt][nt] = (f32x4){0.f, 0.f, 0.f, 0.f};

    // ---- phase 1: gemm0 (W0=wl1) ----
    for (int t = 0; t < 8; ++t) {
        #pragma unroll
        for (int s = 0; s < 4; ++s)
            gl2lds16(W0 + ((size_t)(t * 4 + s) * 256 + tid) * 8, &sA[(s * 256 + tid) * 8]);
        {
            const unsigned short* p = bp + (size_t)(t * 32 + kqS * 8) * HW_;
            union { unsigned short h[8]; uint4 u; } hb;
            #pragma unroll
            for (int jj = 0; jj < 8; ++jj) hb.h[jj] = p[(size_t)jj * HW_];
            *(uint4*)&sB[(kqS * 64 + pixS) * 8] = hb.u;
        }
        __syncthreads();
        short8 af[4], bf[4];
        #pragma unroll
        for (int mt = 0; mt < 4; ++mt)
            af[mt] = *(const short8*)&sA[(quad * 256 + wv * 64 + mt * 16 + l15) * 8];
        #pragma unroll
        for (int nt = 0; nt < 4; ++nt)
            bf[nt] = *(const short8*)&sB[(quad * 64 + nt * 16 + l15) * 8];
        #pragma unroll
        for (int mt = 0; mt < 4; ++mt)
            #pragma unroll
            for (int nt = 0; nt < 4; ++nt)
                acc[mt][nt] = __builtin_amdgcn_mfma_f32_16x16x32_bf16(
                    af[mt], bf[nt], acc[mt][nt], 0, 0, 0);
        __syncthreads();
    }
    // epilogue 1: silu-gate, write K-tiled into mid (co becomes gemm1's k)
    #pragma unroll
    for (int mt = 0; mt < 4; ++mt) {
        #pragma unroll
        for (int r = 0; r < 4; ++r) {
            int co = wv * 64 + mt * 16 + quad * 4 + r;
            float bco = bias0[co];
            size_t base = ((size_t)b * C_ + co) * HW_ + i * 64;
            float sc = ss[co], sh = ss[256 + co];
            #pragma unroll
            for (int nt = 0; nt < 4; ++nt) {
                int col = nt * 16 + l15;
                float o = acc[mt][nt][r] + bco;
                float u = silu_f(b2f(auxh[base + col]) * sc + sh);
                mid[((co >> 3) * 64 + col) * 8 + (co & 7)] = f2bf(o * u);
            }
        }
    }
    // ---- phase 2: gemm1 (W1=wcv), B from mid, no staging ----
    #pragma unroll
    for (int mt = 0; mt < 4; ++mt)
        #pragma unroll
        for (int nt = 0; nt < 4; ++nt) acc[mt][nt] = (f32x4){0.f, 0.f, 0.f, 0.f};
    for (int t = 0; t < 8; ++t) {
        #pragma unroll
        for (int s = 0; s < 4; ++s)
            gl2lds16(W1 + ((size_t)(t * 4 + s) * 256 + tid) * 8, &sA[(s * 256 + tid) * 8]);
        __syncthreads();   // also makes mid writes visible at t=0
        short8 af[4], bf[4];
        #pragma unroll
        for (int mt = 0; mt < 4; ++mt)
            af[mt] = *(const short8*)&sA[(quad * 256 + wv * 64 + mt * 16 + l15) * 8];
        #pragma unroll
        for (int nt = 0; nt < 4; ++nt)
            bf[nt] = *(const short8*)&mid[((t * 4 + quad) * 64 + nt * 16 + l15) * 8];
        #pragma unroll
        for (int mt = 0; mt < 4; ++mt)
            #pragma unroll
            for (int nt = 0; nt < 4; ++nt)
                acc[mt][nt] = __builtin_amdgcn_mfma_f32_16x16x32_bf16(
                    af[mt], bf[nt], acc[mt][nt], 0, 0, 0);
        __syncthreads();
    }
    #pragma unroll
    for (int mt = 0; mt < 4; ++mt) {
        #pragma unroll
        for (int r = 0; r < 4; ++r) {
            int co = wv * 64 + mt * 16 + quad * 4 + r;
            float bco = bias1[co];
            size_t base = ((size_t)b * C_ + co) * HW_ + i * 64;
            #pragma unroll
            for (int nt = 0; nt < 4; ++nt) {
                int col = nt * 16 + l15;
                out_f[base + col] = acc[mt][nt][r] + bco + auxf[base + col];
            }
        }
    }
}

// ---------------- launch ----------------------------------------------------
extern "C" void kernel_launch(void* const* d_in, const int* in_sizes, int n_in,
                              void* d_out, int out_size, void* d_ws, size_t ws_size,
                              hipStream_t stream) {
    const float* x     = (const float*)d_in[0];
    const float* p_w   = (const float*)d_in[1];
    const float* p_b   = (const float*)d_in[2];
    const float* ak_w  = (const float*)d_in[3];
    const float* ak_g  = (const float*)d_in[4];
    const float* ak_b  = (const float*)d_in[5];
    const float* l0_w  = (const float*)d_in[6];
    const float* l0_b  = (const float*)d_in[7];
    const float* ls_w  = (const float*)d_in[8];
    const float* ls_b  = (const float*)d_in[9];
    const float* l1_w  = (const float*)d_in[10];
    const float* l1_b  = (const float*)d_in[11];
    const float* cv_w  = (const float*)d_in[12];
    const float* cv_b  = (const float*)d_in[13];
    float* out = (float*)d_out;

    char* w = (char*)d_ws;
    int2*   tbl_off = (int2*)w;                              // 786 KB
    float4* tbl_w   = (float4*)(w + 786432);                 // 1.5 MB
    unsigned short* wak = (unsigned short*)(w + 2359296);    // 384 KB
    unsigned short* wl1 = (unsigned short*)(w + 2752512);    // 128 KB
    unsigned short* wcv = (unsigned short*)(w + 2883584);    // 128 KB
    float* p1 = (float*)(w + 3014656);                       // 512 KB
    float* p2 = (float*)(w + 3538944);                       // 512 KB
    float* ss = (float*)(w + 4063232);                       // 2 KB
    float* pwt = (float*)(w + 4065280);                      // 72 KB
    // time-multiplexed regions:
    unsigned short* xt = (unsigned short*)(w + 4194304);     // 16 MB bf16 (dead after gather)
    unsigned short* ybh    = (unsigned short*)(w + 4194304); // 16 MB (ak writes, after gather)
    float* part = (float*)(w + 37748736);                    // 6.3 MB (dead after s2)
    unsigned short* attn   = (unsigned short*)(w + 37748736);// 16 MB (dw_fused out)
    unsigned short* v      = (unsigned short*)(w + 44040192);// 48 MB (dead after ak)

    prep_kernel<<<1352, 256, 0, stream>>>(ak_w, l1_w, cv_w, p_w, wak, wl1, wcv, pwt);
    offset_s1_kernel<<<4096, 256, 0, stream>>>(x, pwt, part);
    offset_s2_kernel<<<128, 256, 0, stream>>>(part, p_b, tbl_off, tbl_w);
    transpose_kernel<<<1024, 256, 0, stream>>>(x, xt);
    gather_kernel<<<1536, 256, 0, stream>>>(xt, tbl_off, tbl_w, v);
    ak_mfma_kernel<<<512, 256, 0, stream>>>(v, wak, ybh, p1, p2);
    bn_stats_kernel<<<256, 256, 0, stream>>>(p1, p2, ak_g, ak_b, ss);
    dw_fused_kernel<<<2048, 256, 0, stream>>>(ybh, ss, l0_w, l0_b, ls_w, ls_b, attn);
    gemm_fused_kernel<<<512, 256, 0, stream>>>(attn, wl1, l1_b, wcv, cv_b, ybh, ss, x, out);
}